// Round 1
// baseline (9779.546 us; speedup 1.0000x reference)
//
#include <hip/hip_runtime.h>
#include <hip/hip_bf16.h>

using bf16 = __hip_bfloat16;

constexpr int Bc = 8, Kc = 64, Mc = 128, Dnc = 256, Dec = 128, Hnc = 512, Hec = 256, Hc = 8;
constexpr float INV_SQRT_DH = 0.17677669529663687f;   // 1/sqrt(32)

// ---------- helpers ----------
__device__ __forceinline__ float waveSum(float v) {
#pragma unroll
  for (int m = 32; m > 0; m >>= 1) v += __shfl_xor(v, m);
  return v;
}
__device__ __forceinline__ float grpSum32(float v) {
#pragma unroll
  for (int m = 16; m > 0; m >>= 1) v += __shfl_xor(v, m);
  return v;
}
__device__ __forceinline__ float grpMax32(float v) {
#pragma unroll
  for (int m = 16; m > 0; m >>= 1) v = fmaxf(v, __shfl_xor(v, m));
  return v;
}
__device__ __forceinline__ float ldf(const float* p) { return *p; }
__device__ __forceinline__ float ldf(const bf16* p)  { return __bfloat162float(*p); }
__device__ __forceinline__ void  stf(float* p, float v) { *p = v; }
__device__ __forceinline__ void  stf(bf16*  p, float v) { *p = __float2bfloat16(v); }

// ---------- LayerNorm over last dim D (one row per block) ----------
template<int D, typename InT, typename OutT>
__global__ __launch_bounds__(D) void ln_kernel(const InT* __restrict__ in, OutT* __restrict__ out) {
  constexpr int NW = D / 64;
  __shared__ float sb[NW];
  size_t row = blockIdx.x;
  int t = threadIdx.x;
  float v = ldf(in + row * D + t);
  float s = waveSum(v);
  if ((t & 63) == 0) sb[t >> 6] = s;
  __syncthreads();
  float tot = 0.f;
#pragma unroll
  for (int i = 0; i < NW; i++) tot += sb[i];
  float mean = tot * (1.0f / D);
  float d = v - mean;
  __syncthreads();
  float s2 = waveSum(d * d);
  if ((t & 63) == 0) sb[t >> 6] = s2;
  __syncthreads();
  float tot2 = 0.f;
#pragma unroll
  for (int i = 0; i < NW; i++) tot2 += sb[i];
  float rstd = rsqrtf(tot2 * (1.0f / D) + 1e-5f);
  stf(out + row * D + t, d * rstd);
}

// ---------- broadcast init (period is a power of 2; mask = period-1) ----------
__global__ void bcast_kernel(const float* __restrict__ s, float* __restrict__ d,
                             unsigned mask, size_t total) {
  size_t i = (size_t)blockIdx.x * blockDim.x + threadIdx.x;
  if (i < total) d[i] = s[i & mask];
}

// ---------- C[R,ND] = A[R,KD] @ W[KD,ND] (8 rows per block; MODE1: +=) ----------
template<int KD, int ND, int MODE>
__global__ __launch_bounds__(ND) void rowmat_kernel(const float* __restrict__ A,
                                                    const float* __restrict__ W,
                                                    float* __restrict__ C) {
  __shared__ float a[8][KD];
  int r0 = blockIdx.x * 8;
  int t = threadIdx.x;
  for (int i = t; i < 8 * KD; i += ND) a[i / KD][i % KD] = A[(size_t)r0 * KD + i];
  __syncthreads();
  float acc[8];
#pragma unroll
  for (int i = 0; i < 8; i++) acc[i] = 0.f;
#pragma unroll 4
  for (int k = 0; k < KD; k++) {
    float w = W[(size_t)k * ND + t];
#pragma unroll
    for (int i = 0; i < 8; i++) acc[i] += a[i][k] * w;
  }
#pragma unroll
  for (int i = 0; i < 8; i++) {
    size_t o = (size_t)(r0 + i) * ND + t;
    if (MODE) C[o] += acc[i]; else C[o] = acc[i];
  }
}

// ---------- cross attention: one block per (b,m), 8 heads x 32 lanes ----------
__global__ __launch_bounds__(256) void cross_attn_kernel(const float* __restrict__ q,
    const float* __restrict__ kk, const float* __restrict__ vv, float* __restrict__ o) {
  __shared__ float sc[Hc][Kc];
  int bm = blockIdx.x; int b = bm >> 7;
  int t = threadIdx.x; int h = t >> 5; int d = t & 31;
  float qv = q[(size_t)bm * Dnc + h * 32 + d] * INV_SQRT_DH;
  for (int k0 = 0; k0 < Kc; k0++) {
    float kv = kk[((size_t)(b * Kc + k0)) * Dnc + h * 32 + d];
    float p = grpSum32(qv * kv);
    if (d == 0) sc[h][k0] = p;
  }
  __syncthreads();
  float s0 = sc[h][d], s1 = sc[h][d + 32];
  float mx = grpMax32(fmaxf(s0, s1));
  float e0 = __expf(s0 - mx), e1 = __expf(s1 - mx);
  float sm = grpSum32(e0 + e1);
  float rs = 1.f / sm;
  sc[h][d] = e0 * rs; sc[h][d + 32] = e1 * rs;
  __syncthreads();
  float acc = 0.f;
  for (int k0 = 0; k0 < Kc; k0++)
    acc += sc[h][k0] * vv[((size_t)(b * Kc + k0)) * Dnc + h * 32 + d];
  o[(size_t)bm * Dnc + h * 32 + d] = acc;
}

// ---------- pair-biased self attention: one block per (b,i) ----------
__global__ __launch_bounds__(256) void self_attn_kernel(const float* __restrict__ q,
    const float* __restrict__ kk, const float* __restrict__ vv,
    const float* __restrict__ bias, float* __restrict__ o) {
  __shared__ float sc[Hc][Mc];
  int bm = blockIdx.x; int b = bm >> 7, i = bm & 127;
  int t = threadIdx.x; int h = t >> 5, d = t & 31;
  float qv = q[(size_t)bm * Dnc + h * 32 + d] * INV_SQRT_DH;
  const float* bs = bias + (((size_t)b * Hc + h) * Mc + i) * Mc;
  for (int j = 0; j < Mc; j++) {
    float kv = kk[((size_t)(b * Mc + j)) * Dnc + h * 32 + d];
    float p = grpSum32(qv * kv);
    if (d == 0) sc[h][j] = p + bs[j];
  }
  __syncthreads();
  float sv[4]; float mx = -1e30f;
#pragma unroll
  for (int u = 0; u < 4; u++) { sv[u] = sc[h][d + 32 * u]; mx = fmaxf(mx, sv[u]); }
  mx = grpMax32(mx);
  float sm = 0.f;
#pragma unroll
  for (int u = 0; u < 4; u++) { sv[u] = __expf(sv[u] - mx); sm += sv[u]; }
  sm = grpSum32(sm);
  float rs = 1.f / sm;
#pragma unroll
  for (int u = 0; u < 4; u++) sc[h][d + 32 * u] = sv[u] * rs;
  __syncthreads();
  float acc = 0.f;
  for (int j = 0; j < Mc; j++)
    acc += sc[h][j] * vv[((size_t)(b * Mc + j)) * Dnc + h * 32 + d];
  o[(size_t)bm * Dnc + h * 32 + d] = acc;
}

// ---------- bias[b,h,i,j] = sum_c En[b,i,j,c] * Wb[c,h] ----------
__global__ __launch_bounds__(128) void bias_kernel(const bf16* __restrict__ En,
    const float* __restrict__ Wb_l, float* __restrict__ bias) {
  __shared__ float sb[2];
  size_t r = blockIdx.x;  // (b*M+i)*M+j
  int t = threadIdx.x;
  float v = __bfloat162float(En[r * Dec + t]);
  int b = (int)(r >> 14); int ij = (int)(r & 16383); int i = ij >> 7; int j = ij & 127;
#pragma unroll
  for (int h = 0; h < Hc; h++) {
    float p = v * Wb_l[t * Hc + h];
    p = waveSum(p);
    if ((t & 63) == 0) sb[t >> 6] = p;
    __syncthreads();
    if (t == 0) bias[(((size_t)b * Hc + h) * Mc + i) * Mc + j] = sb[0] + sb[1];
    __syncthreads();
  }
}

// ---------- node MLP (MODE1: X += relu(Xn@W1)@W2 ; MODE0: out = ...) ----------
template<int MODE>
__global__ __launch_bounds__(256) void node_mlp_kernel(const float* __restrict__ Xn,
    const float* __restrict__ W1, const float* __restrict__ W2, float* __restrict__ dst) {
  __shared__ float a[Dnc];
  __shared__ float hsh[Hnc];
  size_t r = blockIdx.x;
  int t = threadIdx.x;
  a[t] = Xn[r * Dnc + t];
  __syncthreads();
  for (int hh = t; hh < Hnc; hh += 256) {
    float acc = 0.f;
#pragma unroll 4
    for (int k = 0; k < Dnc; k++) acc += a[k] * W1[(size_t)k * Hnc + hh];
    hsh[hh] = fmaxf(acc, 0.f);
  }
  __syncthreads();
  float acc = 0.f;
#pragma unroll 4
  for (int k = 0; k < Hnc; k++) acc += hsh[k] * W2[(size_t)k * Dnc + t];
  if (MODE) dst[r * Dnc + t] += acc; else dst[r * Dnc + t] = acc;
}

// ---------- node_features head: relu(Xn@W1[256x512])@W2[512x16] ----------
__global__ __launch_bounds__(256) void node_feat_kernel(const float* __restrict__ Xn,
    const float* __restrict__ W1, const float* __restrict__ W2, float* __restrict__ out) {
  __shared__ float a[Dnc];
  __shared__ float hsh[Hnc];
  size_t r = blockIdx.x;
  int t = threadIdx.x;
  a[t] = Xn[r * Dnc + t];
  __syncthreads();
  for (int hh = t; hh < Hnc; hh += 256) {
    float acc = 0.f;
#pragma unroll 4
    for (int k = 0; k < Dnc; k++) acc += a[k] * W1[(size_t)k * Hnc + hh];
    hsh[hh] = fmaxf(acc, 0.f);
  }
  __syncthreads();
  if (t < 16) {
    float acc = 0.f;
    for (int k = 0; k < Hnc; k++) acc += hsh[k] * W2[k * 16 + t];
    out[r * 16 + t] = acc;
  }
}

// ---------- row dot (N=1 heads) ----------
template<int D>
__global__ __launch_bounds__(D) void rowdot_kernel(const float* __restrict__ A,
    const float* __restrict__ w, float* __restrict__ out) {
  __shared__ float sb[D / 64];
  size_t r = blockIdx.x; int t = threadIdx.x;
  float v = A[r * D + t] * w[t];
  v = waveSum(v);
  if ((t & 63) == 0) sb[t >> 6] = v;
  __syncthreads();
  if (t == 0) { float s = 0.f; for (int i = 0; i < D / 64; i++) s += sb[i]; out[r] = s; }
}

// ---------- outer sum: E[b,i,j,:] += xi[b,i,:] + xj[b,j,:] ----------
__global__ __launch_bounds__(256) void outer_sum_kernel(float* __restrict__ E,
    const float* __restrict__ xi, const float* __restrict__ xj) {
  size_t idx = (size_t)blockIdx.x * 256 + threadIdx.x;
  int c = (int)(idx & 127); int j = (int)((idx >> 7) & 127);
  int i = (int)((idx >> 14) & 127); int b = (int)(idx >> 21);
  E[idx] += xi[(size_t)(b * Mc + i) * Dec + c] + xj[(size_t)(b * Mc + j) * Dec + c];
}

// ---------- a = sig(En@Wga)*(En@Wa), b = sig(En@Wgb)*(En@Wb2) ; 32 rows/block ----------
__global__ __launch_bounds__(256) void ab_proj_kernel(const bf16* __restrict__ En,
    const float* __restrict__ Wga, const float* __restrict__ Wa,
    const float* __restrict__ Wgb, const float* __restrict__ Wb2,
    bf16* __restrict__ aO, bf16* __restrict__ bO) {
  __shared__ float A[32][Dec];
  size_t r0 = (size_t)blockIdx.x * 32;
  int t = threadIdx.x;
  for (int i = t; i < 32 * Dec; i += 256) A[i >> 7][i & 127] = __bfloat162float(En[r0 * Dec + i]);
  __syncthreads();
  int c = t & 127, rg = (t >> 7) * 16;
  float ag[16], av[16];
#pragma unroll
  for (int i = 0; i < 16; i++) { ag[i] = 0.f; av[i] = 0.f; }
  for (int k = 0; k < Dec; k++) {
    float wg = Wga[k * Dec + c], wv = Wa[k * Dec + c];
#pragma unroll
    for (int i = 0; i < 16; i++) { float x = A[rg + i][k]; ag[i] += x * wg; av[i] += x * wv; }
  }
#pragma unroll
  for (int i = 0; i < 16; i++) {
    float val = av[i] / (1.f + __expf(-ag[i]));
    aO[(r0 + rg + i) * Dec + c] = __float2bfloat16(val);
  }
#pragma unroll
  for (int i = 0; i < 16; i++) { ag[i] = 0.f; av[i] = 0.f; }
  for (int k = 0; k < Dec; k++) {
    float wg = Wgb[k * Dec + c], wv = Wb2[k * Dec + c];
#pragma unroll
    for (int i = 0; i < 16; i++) { float x = A[rg + i][k]; ag[i] += x * wg; av[i] += x * wv; }
  }
#pragma unroll
  for (int i = 0; i < 16; i++) {
    float val = av[i] / (1.f + __expf(-ag[i]));
    bO[(r0 + rg + i) * Dec + c] = __float2bfloat16(val);
  }
}

// ---------- triangle: t[b,i,j,c] = 0.5*(sum_k a[b,i,k,c]*bb[b,j,k,c] + a[b,k,i,c]*bb[b,k,j,c]) ----------
__global__ __launch_bounds__(128) void tri_kernel(const bf16* __restrict__ a,
    const bf16* __restrict__ bb, bf16* __restrict__ tO) {
  int c = threadIdx.x;
  int i0 = blockIdx.x * 4, j0 = blockIdx.y * 4, b = blockIdx.z;
  size_t base = (size_t)b * Mc * Mc * Dec;
  const bf16* ap = a + base; const bf16* bp = bb + base;
  float acc1[4][4] = {}, acc2[4][4] = {};
  for (int k = 0; k < Mc; k++) {
    float a1[4], b1[4], a2[4], b2[4];
#pragma unroll
    for (int r = 0; r < 4; r++) a1[r] = __bfloat162float(ap[(i0 + r) * 16384 + k * 128 + c]);
#pragma unroll
    for (int s = 0; s < 4; s++) b1[s] = __bfloat162float(bp[(j0 + s) * 16384 + k * 128 + c]);
#pragma unroll
    for (int r = 0; r < 4; r++) a2[r] = __bfloat162float(ap[k * 16384 + (i0 + r) * 128 + c]);
#pragma unroll
    for (int s = 0; s < 4; s++) b2[s] = __bfloat162float(bp[k * 16384 + (j0 + s) * 128 + c]);
#pragma unroll
    for (int r = 0; r < 4; r++)
#pragma unroll
      for (int s = 0; s < 4; s++) { acc1[r][s] += a1[r] * b1[s]; acc2[r][s] += a2[r] * b2[s]; }
  }
#pragma unroll
  for (int r = 0; r < 4; r++)
#pragma unroll
    for (int s = 0; s < 4; s++)
      tO[base + (i0 + r) * 16384 + (j0 + s) * 128 + c] =
          __float2bfloat16(0.5f * (acc1[r][s] + acc2[r][s]));
}

// ---------- E += sig(En@Wgp) * (tn@Wp) ; 32 rows/block ----------
__global__ __launch_bounds__(256) void gate_proj_kernel(const bf16* __restrict__ En,
    const bf16* __restrict__ Tn, const float* __restrict__ Wgp,
    const float* __restrict__ Wp, float* __restrict__ E) {
  __shared__ float A[32][Dec];
  __shared__ float T[32][Dec];
  size_t r0 = (size_t)blockIdx.x * 32;
  int t = threadIdx.x;
  for (int i = t; i < 32 * Dec; i += 256) {
    A[i >> 7][i & 127] = __bfloat162float(En[r0 * Dec + i]);
    T[i >> 7][i & 127] = __bfloat162float(Tn[r0 * Dec + i]);
  }
  __syncthreads();
  int c = t & 127, rg = (t >> 7) * 16;
  float ag[16], ap[16];
#pragma unroll
  for (int i = 0; i < 16; i++) { ag[i] = 0.f; ap[i] = 0.f; }
  for (int k = 0; k < Dec; k++) {
    float wg = Wgp[k * Dec + c], wp = Wp[k * Dec + c];
#pragma unroll
    for (int i = 0; i < 16; i++) { ag[i] += A[rg + i][k] * wg; ap[i] += T[rg + i][k] * wp; }
  }
#pragma unroll
  for (int i = 0; i < 16; i++)
    E[(r0 + rg + i) * Dec + c] += ap[i] / (1.f + __expf(-ag[i]));
}

// ---------- E += relu(En@We1[128x256])@We2[256x128] ; 32 rows/block ----------
__global__ __launch_bounds__(256) void edge_mlp_kernel(const bf16* __restrict__ En,
    const float* __restrict__ W1, const float* __restrict__ W2, float* __restrict__ E) {
  __shared__ float A[32][Dec];
  __shared__ float Hh[32][Hec + 1];
  size_t r0 = (size_t)blockIdx.x * 32;
  int t = threadIdx.x;
  for (int i = t; i < 32 * Dec; i += 256) A[i >> 7][i & 127] = __bfloat162float(En[r0 * Dec + i]);
  __syncthreads();
  {
    float acc[32];
#pragma unroll
    for (int i = 0; i < 32; i++) acc[i] = 0.f;
    for (int k = 0; k < Dec; k++) {
      float w = W1[k * Hec + t];
#pragma unroll
      for (int i = 0; i < 32; i++) acc[i] += A[i][k] * w;
    }
#pragma unroll
    for (int i = 0; i < 32; i++) Hh[i][t] = fmaxf(acc[i], 0.f);
  }
  __syncthreads();
  int c = t & 127, rg = (t >> 7) * 16;
  float acc2[16];
#pragma unroll
  for (int i = 0; i < 16; i++) acc2[i] = 0.f;
  for (int k = 0; k < Hec; k++) {
    float w = W2[k * Dec + c];
#pragma unroll
    for (int i = 0; i < 16; i++) acc2[i] += Hh[rg + i][k] * w;
  }
#pragma unroll
  for (int i = 0; i < 16; i++) E[(r0 + rg + i) * Dec + c] += acc2[i];
}

// ---------- edge_features head: relu(Ef@efW1[128x256])@efW2[256x8] ----------
__global__ __launch_bounds__(256) void edge_feat_kernel(const float* __restrict__ Ef,
    const float* __restrict__ W1, const float* __restrict__ W2, float* __restrict__ out) {
  __shared__ float A[32][Dec];
  __shared__ float Hh[32][Hec + 1];
  size_t r0 = (size_t)blockIdx.x * 32;
  int t = threadIdx.x;
  for (int i = t; i < 32 * Dec; i += 256) A[i >> 7][i & 127] = Ef[r0 * Dec + i];
  __syncthreads();
  {
    float acc[32];
#pragma unroll
    for (int i = 0; i < 32; i++) acc[i] = 0.f;
    for (int k = 0; k < Dec; k++) {
      float w = W1[k * Hec + t];
#pragma unroll
      for (int i = 0; i < 32; i++) acc[i] += A[i][k] * w;
    }
#pragma unroll
    for (int i = 0; i < 32; i++) Hh[i][t] = fmaxf(acc[i], 0.f);
  }
  __syncthreads();
  int r = t >> 3, c = t & 7;
  float acc = 0.f;
  for (int k = 0; k < Hec; k++) acc += Hh[r][k] * W2[k * 8 + c];
  out[(r0 + r) * 8 + c] = acc;
}

// ---------- A = Ef@aW (N=1) and edge_labels = Ef@elW (N=8), fused ----------
__global__ __launch_bounds__(128) void edge_heads_kernel(const float* __restrict__ Ef,
    const float* __restrict__ aW, const float* __restrict__ elW,
    float* __restrict__ outA, float* __restrict__ outEl) {
  __shared__ float sb[2];
  size_t r = blockIdx.x; int t = threadIdx.x;
  float v = Ef[r * Dec + t];
  float p = v * aW[t];
  p = waveSum(p);
  if ((t & 63) == 0) sb[t >> 6] = p;
  __syncthreads();
  if (t == 0) outA[r] = sb[0] + sb[1];
#pragma unroll
  for (int h = 0; h < 8; h++) {
    __syncthreads();
    float q = v * elW[t * 8 + h];
    q = waveSum(q);
    if ((t & 63) == 0) sb[t >> 6] = q;
    __syncthreads();
    if (t == 0) outEl[r * 8 + h] = sb[0] + sb[1];
  }
}

extern "C" void kernel_launch(void* const* d_in, const int* in_sizes, int n_in,
                              void* d_out, int out_size, void* d_ws, size_t ws_size,
                              hipStream_t stream) {
  const float* graph = (const float*)d_in[0];
  const float* Xq  = (const float*)d_in[1];
  const float* Eq  = (const float*)d_in[2];
  const float* Wq  = (const float*)d_in[3];
  const float* Wk  = (const float*)d_in[4];
  const float* Wv  = (const float*)d_in[5];
  const float* Wo  = (const float*)d_in[6];
  const float* Sq  = (const float*)d_in[7];
  const float* Sk  = (const float*)d_in[8];
  const float* Sv  = (const float*)d_in[9];
  const float* So  = (const float*)d_in[10];
  const float* Wb  = (const float*)d_in[11];
  const float* Wn1 = (const float*)d_in[12];
  const float* Wn2 = (const float*)d_in[13];
  const float* Woi = (const float*)d_in[14];
  const float* Woj = (const float*)d_in[15];
  const float* Wa  = (const float*)d_in[16];
  const float* Wga = (const float*)d_in[17];
  const float* Wb2 = (const float*)d_in[18];
  const float* Wgb = (const float*)d_in[19];
  const float* Wp  = (const float*)d_in[20];
  const float* Wgp = (const float*)d_in[21];
  const float* We1 = (const float*)d_in[22];
  const float* We2 = (const float*)d_in[23];
  const float* hW  = (const float*)d_in[24];
  const float* neW1 = (const float*)d_in[25];
  const float* neW2 = (const float*)d_in[26];
  const float* nlW  = (const float*)d_in[27];
  const float* nfW1 = (const float*)d_in[28];
  const float* nfW2 = (const float*)d_in[29];
  const float* aW   = (const float*)d_in[30];
  const float* elW  = (const float*)d_in[31];
  const float* efW1 = (const float*)d_in[32];
  const float* efW2 = (const float*)d_in[33];

  char* wsb = (char*)d_ws;
  size_t off = 0;
  auto alloc = [&](size_t bytes) -> char* {
    char* p = wsb + off; off += (bytes + 255) & ~(size_t)255; return p;
  };
  float* X   = (float*)alloc((size_t)262144 * 4);
  float* Xn  = (float*)alloc((size_t)262144 * 4);
  float* src = (float*)alloc((size_t)131072 * 4);
  float* qb  = (float*)alloc((size_t)262144 * 4);
  float* kb  = (float*)alloc((size_t)262144 * 4);
  float* vb  = (float*)alloc((size_t)262144 * 4);
  float* ob  = (float*)alloc((size_t)262144 * 4);
  float* bias = (float*)alloc((size_t)1048576 * 4);
  float* xi  = (float*)alloc((size_t)131072 * 4);
  float* xj  = (float*)alloc((size_t)131072 * 4);
  float* E   = (float*)alloc((size_t)16777216 * 4);
  bf16* En   = (bf16*)alloc((size_t)16777216 * 2);
  bf16* aB   = (bf16*)alloc((size_t)16777216 * 2);
  bf16* bB   = (bf16*)alloc((size_t)16777216 * 2);
  bf16* tB   = (bf16*)alloc((size_t)16777216 * 2);

  float* out = (float*)d_out;
  float* out_ne = out;               // 262144
  float* out_h  = out + 262144;      // 1024
  float* out_nl = out + 263168;      // 32768
  float* out_nf = out + 295936;      // 16384
  float* out_A  = out + 312320;      // 131072
  float* out_el = out + 443392;      // 1048576
  float* out_ef = out + 1491968;     // 1048576

  // init
  bcast_kernel<<<1024, 256, 0, stream>>>(Xq, X, 32767u, (size_t)262144);
  bcast_kernel<<<65536, 256, 0, stream>>>(Eq, E, 2097151u, (size_t)16777216);
  ln_kernel<256, float, float><<<512, 256, 0, stream>>>(graph, src);

  for (int l = 0; l < 4; l++) {
    const float* Wq_l = Wq + l * 65536; const float* Wk_l = Wk + l * 65536;
    const float* Wv_l = Wv + l * 65536; const float* Wo_l = Wo + l * 65536;
    const float* Sq_l = Sq + l * 65536; const float* Sk_l = Sk + l * 65536;
    const float* Sv_l = Sv + l * 65536; const float* So_l = So + l * 65536;
    const float* Wb_l = Wb + l * 1024;
    const float* Wn1_l = Wn1 + l * 131072; const float* Wn2_l = Wn2 + l * 131072;
    const float* Woi_l = Woi + l * 32768; const float* Woj_l = Woj + l * 32768;
    const float* Wa_l = Wa + l * 16384;  const float* Wga_l = Wga + l * 16384;
    const float* Wb2_l = Wb2 + l * 16384; const float* Wgb_l = Wgb + l * 16384;
    const float* Wp_l = Wp + l * 16384;  const float* Wgp_l = Wgp + l * 16384;
    const float* We1_l = We1 + l * 32768; const float* We2_l = We2 + l * 32768;

    // (a) cross attention
    ln_kernel<256, float, float><<<1024, 256, 0, stream>>>(X, Xn);
    rowmat_kernel<256, 256, 0><<<128, 256, 0, stream>>>(Xn, Wq_l, qb);
    rowmat_kernel<256, 256, 0><<<64, 256, 0, stream>>>(src, Wk_l, kb);
    rowmat_kernel<256, 256, 0><<<64, 256, 0, stream>>>(src, Wv_l, vb);
    cross_attn_kernel<<<1024, 256, 0, stream>>>(qb, kb, vb, ob);
    rowmat_kernel<256, 256, 1><<<128, 256, 0, stream>>>(ob, Wo_l, X);

    // (b) pair-biased self attention
    ln_kernel<128, float, bf16><<<131072, 128, 0, stream>>>(E, En);
    bias_kernel<<<131072, 128, 0, stream>>>(En, Wb_l, bias);
    ln_kernel<256, float, float><<<1024, 256, 0, stream>>>(X, Xn);
    rowmat_kernel<256, 256, 0><<<128, 256, 0, stream>>>(Xn, Sq_l, qb);
    rowmat_kernel<256, 256, 0><<<128, 256, 0, stream>>>(Xn, Sk_l, kb);
    rowmat_kernel<256, 256, 0><<<128, 256, 0, stream>>>(Xn, Sv_l, vb);
    self_attn_kernel<<<1024, 256, 0, stream>>>(qb, kb, vb, bias, ob);
    rowmat_kernel<256, 256, 1><<<128, 256, 0, stream>>>(ob, So_l, X);

    // (c) node MLP
    ln_kernel<256, float, float><<<1024, 256, 0, stream>>>(X, Xn);
    node_mlp_kernel<1><<<1024, 256, 0, stream>>>(Xn, Wn1_l, Wn2_l, X);

    // (d) outer sum into E
    ln_kernel<256, float, float><<<1024, 256, 0, stream>>>(X, Xn);
    rowmat_kernel<256, 128, 0><<<128, 128, 0, stream>>>(Xn, Woi_l, xi);
    rowmat_kernel<256, 128, 0><<<128, 128, 0, stream>>>(Xn, Woj_l, xj);
    outer_sum_kernel<<<65536, 256, 0, stream>>>(E, xi, xj);

    // (e) triangle multiplicative update
    ln_kernel<128, float, bf16><<<131072, 128, 0, stream>>>(E, En);
    ab_proj_kernel<<<4096, 256, 0, stream>>>(En, Wga_l, Wa_l, Wgb_l, Wb2_l, aB, bB);
    tri_kernel<<<dim3(32, 32, 8), 128, 0, stream>>>(aB, bB, tB);
    ln_kernel<128, bf16, bf16><<<131072, 128, 0, stream>>>(tB, tB);
    gate_proj_kernel<<<4096, 256, 0, stream>>>(En, tB, Wgp_l, Wp_l, E);

    // (f) edge MLP
    ln_kernel<128, float, bf16><<<131072, 128, 0, stream>>>(E, En);
    edge_mlp_kernel<<<4096, 256, 0, stream>>>(En, We1_l, We2_l, E);
  }

  // final norms
  ln_kernel<256, float, float><<<1024, 256, 0, stream>>>(X, Xn);
  ln_kernel<128, float, float><<<131072, 128, 0, stream>>>(E, E);

  // node heads
  node_mlp_kernel<0><<<1024, 256, 0, stream>>>(Xn, neW1, neW2, out_ne);
  rowdot_kernel<256><<<1024, 256, 0, stream>>>(Xn, hW, out_h);
  rowmat_kernel<256, 32, 0><<<128, 32, 0, stream>>>(Xn, nlW, out_nl);
  node_feat_kernel<<<1024, 256, 0, stream>>>(Xn, nfW1, nfW2, out_nf);

  // edge heads
  edge_heads_kernel<<<131072, 128, 0, stream>>>(E, aW, elW, out_A, out_el);
  edge_feat_kernel<<<4096, 256, 0, stream>>>(E, efW1, efW2, out_ef);
}

// Round 2
// 4979.636 us; speedup vs baseline: 1.9639x; 1.9639x over previous
//
#include <hip/hip_runtime.h>
#include <hip/hip_bf16.h>

using bf16 = __hip_bfloat16;

constexpr int Bc = 8, Kc = 64, Mc = 128, Dnc = 256, Dec = 128, Hnc = 512, Hec = 256, Hc = 8;
constexpr float INV_SQRT_DH = 0.17677669529663687f;   // 1/sqrt(32)

typedef __attribute__((ext_vector_type(8))) short s8v;   // 8 bf16 (4 VGPRs)
typedef __attribute__((ext_vector_type(4))) float f4v;   // 4 fp32
#define MFMA16(a, b, c) __builtin_amdgcn_mfma_f32_16x16x32_bf16(a, b, c, 0, 0, 0)

// ---------- helpers ----------
__device__ __forceinline__ float waveSum(float v) {
#pragma unroll
  for (int m = 32; m > 0; m >>= 1) v += __shfl_xor(v, m);
  return v;
}
__device__ __forceinline__ float grpSum32(float v) {
#pragma unroll
  for (int m = 16; m > 0; m >>= 1) v += __shfl_xor(v, m);
  return v;
}
__device__ __forceinline__ float grpMax32(float v) {
#pragma unroll
  for (int m = 16; m > 0; m >>= 1) v = fmaxf(v, __shfl_xor(v, m));
  return v;
}
__device__ __forceinline__ float ldf(const float* p) { return *p; }
__device__ __forceinline__ float ldf(const bf16* p)  { return __bfloat162float(*p); }
__device__ __forceinline__ void  stf(float* p, float v) { *p = v; }
__device__ __forceinline__ void  stf(bf16*  p, float v) { *p = __float2bfloat16(v); }

// ---------- LayerNorm over last dim D (one row per block; D=256 node-side) ----------
template<int D, typename InT, typename OutT>
__global__ __launch_bounds__(D) void ln_kernel(const InT* __restrict__ in, OutT* __restrict__ out) {
  constexpr int NW = D / 64;
  __shared__ float sb[NW];
  size_t row = blockIdx.x;
  int t = threadIdx.x;
  float v = ldf(in + row * D + t);
  float s = waveSum(v);
  if ((t & 63) == 0) sb[t >> 6] = s;
  __syncthreads();
  float tot = 0.f;
#pragma unroll
  for (int i = 0; i < NW; i++) tot += sb[i];
  float mean = tot * (1.0f / D);
  float d = v - mean;
  __syncthreads();
  float s2 = waveSum(d * d);
  if ((t & 63) == 0) sb[t >> 6] = s2;
  __syncthreads();
  float tot2 = 0.f;
#pragma unroll
  for (int i = 0; i < NW; i++) tot2 += sb[i];
  float rstd = rsqrtf(tot2 * (1.0f / D) + 1e-5f);
  stf(out + row * D + t, d * rstd);
}

// ---------- LayerNorm D=128, one row per WAVE (4 rows / 256-thread block) ----------
template<typename InT, typename OutT>
__global__ __launch_bounds__(256) void ln128w_kernel(const InT* __restrict__ in,
                                                     OutT* __restrict__ out) {
  size_t row = (size_t)blockIdx.x * 4 + (threadIdx.x >> 6);
  int l = threadIdx.x & 63;
  const InT* p = in + row * 128 + l * 2;
  float v0 = ldf(p), v1 = ldf(p + 1);
  float mean = waveSum(v0 + v1) * (1.f / 128.f);
  float d0 = v0 - mean, d1 = v1 - mean;
  float rstd = rsqrtf(waveSum(d0 * d0 + d1 * d1) * (1.f / 128.f) + 1e-5f);
  OutT* q = out + row * 128 + l * 2;
  stf(q, d0 * rstd);
  stf(q + 1, d1 * rstd);
}

// ---------- broadcast init ----------
__global__ void bcast_kernel(const float* __restrict__ s, float* __restrict__ d,
                             unsigned mask, size_t total) {
  size_t i = (size_t)blockIdx.x * blockDim.x + threadIdx.x;
  if (i < total) d[i] = s[i & mask];
}

// ---------- weight transpose+convert: out[n][k] = bf16(in[k][n]); grid (N/32,K/32,L) ----------
__global__ __launch_bounds__(256) void twcvt_kernel(const float* __restrict__ in,
                                                    bf16* __restrict__ out, int K, int N) {
  const float* inp = in + (size_t)blockIdx.z * K * N;
  bf16* outp = out + (size_t)blockIdx.z * K * N;
  __shared__ float tile[32][33];
  int tx = threadIdx.x & 31, ty = threadIdx.x >> 5;
  int k0 = blockIdx.y * 32, n0 = blockIdx.x * 32;
#pragma unroll
  for (int it = 0; it < 4; it++)
    tile[ty + it * 8][tx] = inp[(size_t)(k0 + ty + it * 8) * N + n0 + tx];
  __syncthreads();
#pragma unroll
  for (int it = 0; it < 4; it++)
    outp[(size_t)(n0 + ty + it * 8) * K + k0 + tx] = __float2bfloat16(tile[tx][ty + it * 8]);
}

// ---------- MFMA tile staging with XOR swizzle (rows x 128 bf16 per k-chunk) ----------
template<int ROWS>
__device__ __forceinline__ void stageTile(const bf16* __restrict__ g, int srcLd,
                                          char* lds, int t) {
  constexpr int IT = ROWS * 16 / 256;
#pragma unroll
  for (int it = 0; it < IT; it++) {
    int u = t + it * 256;
    int row = u >> 4, c16 = u & 15;
    uint4 val = *(const uint4*)(g + (size_t)row * srcLd + c16 * 8);
    *(uint4*)(lds + row * 256 + ((c16 ^ (row & 7)) << 4)) = val;
  }
}
__device__ __forceinline__ s8v readFrag(const char* lds, int row, int c16) {
  return *(const s8v*)(lds + row * 256 + ((c16 ^ (row & 7)) << 4));
}

// ---------- MFMA GEMM: 256 rows x 128 cols per block, two weight mats ----------
// EPI 0: out bf16[Rx128] = sigmoid(acc0)*acc1   (gated projection)
// EPI 1: out bf16[Rx256] = relu(acc0) | relu(acc1)  (MLP hidden, two N-halves)
template<int KTOT, int EPI>
__global__ __launch_bounds__(256, 1) void mfma_nw2_kernel(
    const bf16* __restrict__ A, const bf16* __restrict__ W0t, const bf16* __restrict__ W1t,
    bf16* __restrict__ out) {
  __shared__ char Ash[256 * 256];   // 64KB
  __shared__ char W0sh[128 * 256];  // 32KB
  __shared__ char W1sh[128 * 256];  // 32KB
  int t = threadIdx.x, l = t & 63, w = t >> 6;
  size_t r0 = (size_t)blockIdx.x * 256;
  int rb = w * 64;
  f4v acc0[4][8], acc1[4][8];
#pragma unroll
  for (int rf = 0; rf < 4; rf++)
#pragma unroll
    for (int cf = 0; cf < 8; cf++) {
      acc0[rf][cf] = (f4v){0.f, 0.f, 0.f, 0.f};
      acc1[rf][cf] = (f4v){0.f, 0.f, 0.f, 0.f};
    }
#pragma unroll
  for (int kb = 0; kb < KTOT; kb += 128) {
    if (kb) __syncthreads();
    stageTile<256>(A + r0 * KTOT + kb, KTOT, Ash, t);
    stageTile<128>(W0t + kb, KTOT, W0sh, t);
    stageTile<128>(W1t + kb, KTOT, W1sh, t);
    __syncthreads();
#pragma unroll
    for (int kc = 0; kc < 4; kc++) {
      int c16 = kc * 4 + (l >> 4);
      s8v af[4];
#pragma unroll
      for (int rf = 0; rf < 4; rf++) af[rf] = readFrag(Ash, rb + rf * 16 + (l & 15), c16);
#pragma unroll
      for (int cf = 0; cf < 8; cf++) {
        s8v b0 = readFrag(W0sh, cf * 16 + (l & 15), c16);
        s8v b1 = readFrag(W1sh, cf * 16 + (l & 15), c16);
#pragma unroll
        for (int rf = 0; rf < 4; rf++) {
          acc0[rf][cf] = MFMA16(af[rf], b0, acc0[rf][cf]);
          acc1[rf][cf] = MFMA16(af[rf], b1, acc1[rf][cf]);
        }
      }
    }
  }
#pragma unroll
  for (int rf = 0; rf < 4; rf++)
#pragma unroll
    for (int cf = 0; cf < 8; cf++)
#pragma unroll
      for (int i = 0; i < 4; i++) {
        size_t row = r0 + rb + rf * 16 + ((l >> 4) << 2) + i;
        int col = cf * 16 + (l & 15);
        float v0 = acc0[rf][cf][i], v1 = acc1[rf][cf][i];
        if (EPI == 0) {
          out[row * 128 + col] = __float2bfloat16(v1 / (1.f + __expf(-v0)));
        } else {
          out[row * 256 + col]       = __float2bfloat16(fmaxf(v0, 0.f));
          out[row * 256 + 128 + col] = __float2bfloat16(fmaxf(v1, 0.f));
        }
      }
}

// ---------- MFMA GEMM: E[Rx128] += A[Rx256] @ Wt  (edge-MLP second matmul) ----------
__global__ __launch_bounds__(256, 1) void mfma_add_kernel(
    const bf16* __restrict__ A, const bf16* __restrict__ Wt, float* __restrict__ E) {
  __shared__ char Ash[256 * 256];   // 64KB
  __shared__ char Wsh[128 * 256];   // 32KB
  int t = threadIdx.x, l = t & 63, w = t >> 6;
  size_t r0 = (size_t)blockIdx.x * 256;
  int rb = w * 64;
  f4v acc[4][8];
#pragma unroll
  for (int rf = 0; rf < 4; rf++)
#pragma unroll
    for (int cf = 0; cf < 8; cf++) acc[rf][cf] = (f4v){0.f, 0.f, 0.f, 0.f};
#pragma unroll
  for (int kb = 0; kb < 256; kb += 128) {
    if (kb) __syncthreads();
    stageTile<256>(A + r0 * 256 + kb, 256, Ash, t);
    stageTile<128>(Wt + kb, 256, Wsh, t);
    __syncthreads();
#pragma unroll
    for (int kc = 0; kc < 4; kc++) {
      int c16 = kc * 4 + (l >> 4);
      s8v af[4];
#pragma unroll
      for (int rf = 0; rf < 4; rf++) af[rf] = readFrag(Ash, rb + rf * 16 + (l & 15), c16);
#pragma unroll
      for (int cf = 0; cf < 8; cf++) {
        s8v b0 = readFrag(Wsh, cf * 16 + (l & 15), c16);
#pragma unroll
        for (int rf = 0; rf < 4; rf++) acc[rf][cf] = MFMA16(af[rf], b0, acc[rf][cf]);
      }
    }
  }
#pragma unroll
  for (int rf = 0; rf < 4; rf++)
#pragma unroll
    for (int cf = 0; cf < 8; cf++)
#pragma unroll
      for (int i = 0; i < 4; i++) {
        size_t row = r0 + rb + rf * 16 + ((l >> 4) << 2) + i;
        int col = cf * 16 + (l & 15);
        E[row * 128 + col] += acc[rf][cf][i];
      }
}

// ---------- MFMA gated add: E += sigmoid(A1@W0t) * (A2@W1t); 128 rows/block ----------
__global__ __launch_bounds__(256, 1) void mfma_gateadd_kernel(
    const bf16* __restrict__ A1, const bf16* __restrict__ A2,
    const bf16* __restrict__ W0t, const bf16* __restrict__ W1t, float* __restrict__ E) {
  __shared__ char A1sh[128 * 256];
  __shared__ char A2sh[128 * 256];
  __shared__ char W0sh[128 * 256];
  __shared__ char W1sh[128 * 256];   // 128KB total
  int t = threadIdx.x, l = t & 63, w = t >> 6;
  size_t r0 = (size_t)blockIdx.x * 128;
  int rb = w * 32;
  f4v acc0[2][8], acc1[2][8];
#pragma unroll
  for (int rf = 0; rf < 2; rf++)
#pragma unroll
    for (int cf = 0; cf < 8; cf++) {
      acc0[rf][cf] = (f4v){0.f, 0.f, 0.f, 0.f};
      acc1[rf][cf] = (f4v){0.f, 0.f, 0.f, 0.f};
    }
  stageTile<128>(A1 + r0 * 128, 128, A1sh, t);
  stageTile<128>(A2 + r0 * 128, 128, A2sh, t);
  stageTile<128>(W0t, 128, W0sh, t);
  stageTile<128>(W1t, 128, W1sh, t);
  __syncthreads();
#pragma unroll
  for (int kc = 0; kc < 4; kc++) {
    int c16 = kc * 4 + (l >> 4);
    s8v a1f[2], a2f[2];
#pragma unroll
    for (int rf = 0; rf < 2; rf++) {
      a1f[rf] = readFrag(A1sh, rb + rf * 16 + (l & 15), c16);
      a2f[rf] = readFrag(A2sh, rb + rf * 16 + (l & 15), c16);
    }
#pragma unroll
    for (int cf = 0; cf < 8; cf++) {
      s8v b0 = readFrag(W0sh, cf * 16 + (l & 15), c16);
      s8v b1 = readFrag(W1sh, cf * 16 + (l & 15), c16);
#pragma unroll
      for (int rf = 0; rf < 2; rf++) {
        acc0[rf][cf] = MFMA16(a1f[rf], b0, acc0[rf][cf]);
        acc1[rf][cf] = MFMA16(a2f[rf], b1, acc1[rf][cf]);
      }
    }
  }
#pragma unroll
  for (int rf = 0; rf < 2; rf++)
#pragma unroll
    for (int cf = 0; cf < 8; cf++)
#pragma unroll
      for (int i = 0; i < 4; i++) {
        size_t row = r0 + rb + rf * 16 + ((l >> 4) << 2) + i;
        int col = cf * 16 + (l & 15);
        E[row * 128 + col] += acc1[rf][cf][i] / (1.f + __expf(-acc0[rf][cf][i]));
      }
}

// ---------- 8-col head: out[r,h] = sum_k A[r,k]*W[k,h]; optional bias-scatter / A-dot ----------
template<int K, int BIAS, int WITHA>
__global__ __launch_bounds__(256) void head8_kernel(const bf16* __restrict__ A,
    const float* __restrict__ W, float* __restrict__ out,
    const float* __restrict__ aW, float* __restrict__ outA) {
  __shared__ __align__(16) bf16 As[32 * K];
  __shared__ float Ws[K * 8];
  __shared__ float aWs[128];
  size_t r0 = (size_t)blockIdx.x * 32;
  int t = threadIdx.x;
  constexpr int NCH = 32 * K / 8;   // uint4 chunks
#pragma unroll
  for (int it = 0; it < NCH / 256; it++)
    ((uint4*)As)[t + it * 256] = ((const uint4*)(A + r0 * K))[t + it * 256];
  for (int u = t; u < K * 8; u += 256) Ws[u] = W[u];
  if (WITHA) { if (t < 128) aWs[t] = aW[t]; }
  __syncthreads();
  int rr = t >> 3, h = t & 7;
  float acc = 0.f;
#pragma unroll 4
  for (int k = 0; k < K; k++) acc += __bfloat162float(As[rr * K + k]) * Ws[k * 8 + h];
  size_t r = r0 + rr;
  if (BIAS) {
    size_t b = r >> 14, ij = r & 16383;
    out[((b * 8 + h) << 14) + ij] = acc;
  } else {
    out[r * 8 + h] = acc;
  }
  if (WITHA) {
    if (t < 32) {
      float a2 = 0.f;
#pragma unroll 4
      for (int k = 0; k < K; k++) a2 += __bfloat162float(As[t * K + k]) * aWs[k];
      outA[r0 + t] = a2;
    }
  }
}

// ---------- C[R,ND] = A[R,KD] @ W[KD,ND] (8 rows per block; MODE1: +=) node-side ----------
template<int KD, int ND, int MODE>
__global__ __launch_bounds__(ND) void rowmat_kernel(const float* __restrict__ A,
                                                    const float* __restrict__ W,
                                                    float* __restrict__ C) {
  __shared__ float a[8][KD];
  int r0 = blockIdx.x * 8;
  int t = threadIdx.x;
  for (int i = t; i < 8 * KD; i += ND) a[i / KD][i % KD] = A[(size_t)r0 * KD + i];
  __syncthreads();
  float acc[8];
#pragma unroll
  for (int i = 0; i < 8; i++) acc[i] = 0.f;
#pragma unroll 4
  for (int k = 0; k < KD; k++) {
    float w = W[(size_t)k * ND + t];
#pragma unroll
    for (int i = 0; i < 8; i++) acc[i] += a[i][k] * w;
  }
#pragma unroll
  for (int i = 0; i < 8; i++) {
    size_t o = (size_t)(r0 + i) * ND + t;
    if (MODE) C[o] += acc[i]; else C[o] = acc[i];
  }
}

// ---------- cross attention ----------
__global__ __launch_bounds__(256) void cross_attn_kernel(const float* __restrict__ q,
    const float* __restrict__ kk, const float* __restrict__ vv, float* __restrict__ o) {
  __shared__ float sc[Hc][Kc];
  int bm = blockIdx.x; int b = bm >> 7;
  int t = threadIdx.x; int h = t >> 5; int d = t & 31;
  float qv = q[(size_t)bm * Dnc + h * 32 + d] * INV_SQRT_DH;
  for (int k0 = 0; k0 < Kc; k0++) {
    float kv = kk[((size_t)(b * Kc + k0)) * Dnc + h * 32 + d];
    float p = grpSum32(qv * kv);
    if (d == 0) sc[h][k0] = p;
  }
  __syncthreads();
  float s0 = sc[h][d], s1 = sc[h][d + 32];
  float mx = grpMax32(fmaxf(s0, s1));
  float e0 = __expf(s0 - mx), e1 = __expf(s1 - mx);
  float sm = grpSum32(e0 + e1);
  float rs = 1.f / sm;
  sc[h][d] = e0 * rs; sc[h][d + 32] = e1 * rs;
  __syncthreads();
  float acc = 0.f;
  for (int k0 = 0; k0 < Kc; k0++)
    acc += sc[h][k0] * vv[((size_t)(b * Kc + k0)) * Dnc + h * 32 + d];
  o[(size_t)bm * Dnc + h * 32 + d] = acc;
}

// ---------- pair-biased self attention ----------
__global__ __launch_bounds__(256) void self_attn_kernel(const float* __restrict__ q,
    const float* __restrict__ kk, const float* __restrict__ vv,
    const float* __restrict__ bias, float* __restrict__ o) {
  __shared__ float sc[Hc][Mc];
  int bm = blockIdx.x; int b = bm >> 7, i = bm & 127;
  int t = threadIdx.x; int h = t >> 5, d = t & 31;
  float qv = q[(size_t)bm * Dnc + h * 32 + d] * INV_SQRT_DH;
  const float* bs = bias + (((size_t)b * Hc + h) * Mc + i) * Mc;
  for (int j = 0; j < Mc; j++) {
    float kv = kk[((size_t)(b * Mc + j)) * Dnc + h * 32 + d];
    float p = grpSum32(qv * kv);
    if (d == 0) sc[h][j] = p + bs[j];
  }
  __syncthreads();
  float sv[4]; float mx = -1e30f;
#pragma unroll
  for (int u = 0; u < 4; u++) { sv[u] = sc[h][d + 32 * u]; mx = fmaxf(mx, sv[u]); }
  mx = grpMax32(mx);
  float sm = 0.f;
#pragma unroll
  for (int u = 0; u < 4; u++) { sv[u] = __expf(sv[u] - mx); sm += sv[u]; }
  sm = grpSum32(sm);
  float rs = 1.f / sm;
#pragma unroll
  for (int u = 0; u < 4; u++) sc[h][d + 32 * u] = sv[u] * rs;
  __syncthreads();
  float acc = 0.f;
  for (int j = 0; j < Mc; j++)
    acc += sc[h][j] * vv[((size_t)(b * Mc + j)) * Dnc + h * 32 + d];
  o[(size_t)bm * Dnc + h * 32 + d] = acc;
}

// ---------- node MLP ----------
template<int MODE>
__global__ __launch_bounds__(256) void node_mlp_kernel(const float* __restrict__ Xn,
    const float* __restrict__ W1, const float* __restrict__ W2, float* __restrict__ dst) {
  __shared__ float a[Dnc];
  __shared__ float hsh[Hnc];
  size_t r = blockIdx.x;
  int t = threadIdx.x;
  a[t] = Xn[r * Dnc + t];
  __syncthreads();
  for (int hh = t; hh < Hnc; hh += 256) {
    float acc = 0.f;
#pragma unroll 4
    for (int k = 0; k < Dnc; k++) acc += a[k] * W1[(size_t)k * Hnc + hh];
    hsh[hh] = fmaxf(acc, 0.f);
  }
  __syncthreads();
  float acc = 0.f;
#pragma unroll 4
  for (int k = 0; k < Hnc; k++) acc += hsh[k] * W2[(size_t)k * Dnc + t];
  if (MODE) dst[r * Dnc + t] += acc; else dst[r * Dnc + t] = acc;
}

// ---------- node_features head ----------
__global__ __launch_bounds__(256) void node_feat_kernel(const float* __restrict__ Xn,
    const float* __restrict__ W1, const float* __restrict__ W2, float* __restrict__ out) {
  __shared__ float a[Dnc];
  __shared__ float hsh[Hnc];
  size_t r = blockIdx.x;
  int t = threadIdx.x;
  a[t] = Xn[r * Dnc + t];
  __syncthreads();
  for (int hh = t; hh < Hnc; hh += 256) {
    float acc = 0.f;
#pragma unroll 4
    for (int k = 0; k < Dnc; k++) acc += a[k] * W1[(size_t)k * Hnc + hh];
    hsh[hh] = fmaxf(acc, 0.f);
  }
  __syncthreads();
  if (t < 16) {
    float acc = 0.f;
    for (int k = 0; k < Hnc; k++) acc += hsh[k] * W2[k * 16 + t];
    out[r * 16 + t] = acc;
  }
}

// ---------- row dot ----------
template<int D>
__global__ __launch_bounds__(D) void rowdot_kernel(const float* __restrict__ A,
    const float* __restrict__ w, float* __restrict__ out) {
  __shared__ float sb[D / 64];
  size_t r = blockIdx.x; int t = threadIdx.x;
  float v = A[r * D + t] * w[t];
  v = waveSum(v);
  if ((t & 63) == 0) sb[t >> 6] = v;
  __syncthreads();
  if (t == 0) { float s = 0.f; for (int i = 0; i < D / 64; i++) s += sb[i]; out[r] = s; }
}

// ---------- outer sum ----------
__global__ __launch_bounds__(256) void outer_sum_kernel(float* __restrict__ E,
    const float* __restrict__ xi, const float* __restrict__ xj) {
  size_t idx = (size_t)blockIdx.x * 256 + threadIdx.x;
  int c = (int)(idx & 127); int j = (int)((idx >> 7) & 127);
  int i = (int)((idx >> 14) & 127); int b = (int)(idx >> 21);
  E[idx] += xi[(size_t)(b * Mc + i) * Dec + c] + xj[(size_t)(b * Mc + j) * Dec + c];
}

// ---------- triangle (unchanged this round) ----------
__global__ __launch_bounds__(128) void tri_kernel(const bf16* __restrict__ a,
    const bf16* __restrict__ bb, bf16* __restrict__ tO) {
  int c = threadIdx.x;
  int i0 = blockIdx.x * 4, j0 = blockIdx.y * 4, b = blockIdx.z;
  size_t base = (size_t)b * Mc * Mc * Dec;
  const bf16* ap = a + base; const bf16* bp = bb + base;
  float acc1[4][4] = {}, acc2[4][4] = {};
  for (int k = 0; k < Mc; k++) {
    float a1[4], b1[4], a2[4], b2[4];
#pragma unroll
    for (int r = 0; r < 4; r++) a1[r] = __bfloat162float(ap[(i0 + r) * 16384 + k * 128 + c]);
#pragma unroll
    for (int s = 0; s < 4; s++) b1[s] = __bfloat162float(bp[(j0 + s) * 16384 + k * 128 + c]);
#pragma unroll
    for (int r = 0; r < 4; r++) a2[r] = __bfloat162float(ap[k * 16384 + (i0 + r) * 128 + c]);
#pragma unroll
    for (int s = 0; s < 4; s++) b2[s] = __bfloat162float(bp[k * 16384 + (j0 + s) * 128 + c]);
#pragma unroll
    for (int r = 0; r < 4; r++)
#pragma unroll
      for (int s = 0; s < 4; s++) { acc1[r][s] += a1[r] * b1[s]; acc2[r][s] += a2[r] * b2[s]; }
  }
#pragma unroll
  for (int r = 0; r < 4; r++)
#pragma unroll
    for (int s = 0; s < 4; s++)
      tO[base + (i0 + r) * 16384 + (j0 + s) * 128 + c] =
          __float2bfloat16(0.5f * (acc1[r][s] + acc2[r][s]));
}

extern "C" void kernel_launch(void* const* d_in, const int* in_sizes, int n_in,
                              void* d_out, int out_size, void* d_ws, size_t ws_size,
                              hipStream_t stream) {
  const float* graph = (const float*)d_in[0];
  const float* Xq  = (const float*)d_in[1];
  const float* Eq  = (const float*)d_in[2];
  const float* Wq  = (const float*)d_in[3];
  const float* Wk  = (const float*)d_in[4];
  const float* Wv  = (const float*)d_in[5];
  const float* Wo  = (const float*)d_in[6];
  const float* Sq  = (const float*)d_in[7];
  const float* Sk  = (const float*)d_in[8];
  const float* Sv  = (const float*)d_in[9];
  const float* So  = (const float*)d_in[10];
  const float* Wb  = (const float*)d_in[11];
  const float* Wn1 = (const float*)d_in[12];
  const float* Wn2 = (const float*)d_in[13];
  const float* Woi = (const float*)d_in[14];
  const float* Woj = (const float*)d_in[15];
  const float* Wa  = (const float*)d_in[16];
  const float* Wga = (const float*)d_in[17];
  const float* Wb2 = (const float*)d_in[18];
  const float* Wgb = (const float*)d_in[19];
  const float* Wp  = (const float*)d_in[20];
  const float* Wgp = (const float*)d_in[21];
  const float* We1 = (const float*)d_in[22];
  const float* We2 = (const float*)d_in[23];
  const float* hW  = (const float*)d_in[24];
  const float* neW1 = (const float*)d_in[25];
  const float* neW2 = (const float*)d_in[26];
  const float* nlW  = (const float*)d_in[27];
  const float* nfW1 = (const float*)d_in[28];
  const float* nfW2 = (const float*)d_in[29];
  const float* aW   = (const float*)d_in[30];
  const float* elW  = (const float*)d_in[31];
  const float* efW1 = (const float*)d_in[32];
  const float* efW2 = (const float*)d_in[33];

  char* wsb = (char*)d_ws;
  size_t off = 0;
  auto alloc = [&](size_t bytes) -> char* {
    char* p = wsb + off; off += (bytes + 255) & ~(size_t)255; return p;
  };
  float* X   = (float*)alloc((size_t)262144 * 4);
  float* Xn  = (float*)alloc((size_t)262144 * 4);
  float* src = (float*)alloc((size_t)131072 * 4);
  float* qb  = (float*)alloc((size_t)262144 * 4);
  float* kb  = (float*)alloc((size_t)262144 * 4);
  float* vb  = (float*)alloc((size_t)262144 * 4);
  float* ob  = (float*)alloc((size_t)262144 * 4);
  float* bias = (float*)alloc((size_t)1048576 * 4);
  float* xi  = (float*)alloc((size_t)131072 * 4);
  float* xj  = (float*)alloc((size_t)131072 * 4);
  float* E   = (float*)alloc((size_t)16777216 * 4);
  bf16* En   = (bf16*)alloc((size_t)16777216 * 2);
  bf16* aB   = (bf16*)alloc((size_t)16777216 * 2);
  bf16* bB   = (bf16*)alloc((size_t)16777216 * 2);
  bf16* tB   = (bf16*)alloc((size_t)16777216 * 2);
  // transposed bf16 weights
  bf16* WgaT = (bf16*)alloc((size_t)65536 * 2);
  bf16* WaT  = (bf16*)alloc((size_t)65536 * 2);
  bf16* WgbT = (bf16*)alloc((size_t)65536 * 2);
  bf16* Wb2T = (bf16*)alloc((size_t)65536 * 2);
  bf16* WgpT = (bf16*)alloc((size_t)65536 * 2);
  bf16* WpT  = (bf16*)alloc((size_t)65536 * 2);
  bf16* We1T = (bf16*)alloc((size_t)131072 * 2);
  bf16* We2T = (bf16*)alloc((size_t)131072 * 2);
  bf16* efW1T = (bf16*)alloc((size_t)32768 * 2);
  bf16* H = aB;   // alias: aB+bB region (67MB) free when H is live

  float* out = (float*)d_out;
  float* out_ne = out;               // 262144
  float* out_h  = out + 262144;      // 1024
  float* out_nl = out + 263168;      // 32768
  float* out_nf = out + 295936;      // 16384
  float* out_A  = out + 312320;      // 131072
  float* out_el = out + 443392;      // 1048576
  float* out_ef = out + 1491968;     // 1048576

  // ---- weight prep (transpose + bf16) ----
  twcvt_kernel<<<dim3(4, 4, 4), 256, 0, stream>>>(Wga, WgaT, 128, 128);
  twcvt_kernel<<<dim3(4, 4, 4), 256, 0, stream>>>(Wa,  WaT,  128, 128);
  twcvt_kernel<<<dim3(4, 4, 4), 256, 0, stream>>>(Wgb, WgbT, 128, 128);
  twcvt_kernel<<<dim3(4, 4, 4), 256, 0, stream>>>(Wb2, Wb2T, 128, 128);
  twcvt_kernel<<<dim3(4, 4, 4), 256, 0, stream>>>(Wgp, WgpT, 128, 128);
  twcvt_kernel<<<dim3(4, 4, 4), 256, 0, stream>>>(Wp,  WpT,  128, 128);
  twcvt_kernel<<<dim3(8, 4, 4), 256, 0, stream>>>(We1, We1T, 128, 256);
  twcvt_kernel<<<dim3(4, 8, 4), 256, 0, stream>>>(We2, We2T, 256, 128);
  twcvt_kernel<<<dim3(8, 4, 1), 256, 0, stream>>>(efW1, efW1T, 128, 256);

  // ---- init ----
  bcast_kernel<<<1024, 256, 0, stream>>>(Xq, X, 32767u, (size_t)262144);
  bcast_kernel<<<65536, 256, 0, stream>>>(Eq, E, 2097151u, (size_t)16777216);
  ln_kernel<256, float, float><<<512, 256, 0, stream>>>(graph, src);

  for (int l = 0; l < 4; l++) {
    const float* Wq_l = Wq + l * 65536; const float* Wk_l = Wk + l * 65536;
    const float* Wv_l = Wv + l * 65536; const float* Wo_l = Wo + l * 65536;
    const float* Sq_l = Sq + l * 65536; const float* Sk_l = Sk + l * 65536;
    const float* Sv_l = Sv + l * 65536; const float* So_l = So + l * 65536;
    const float* Wb_l = Wb + l * 1024;
    const float* Wn1_l = Wn1 + l * 131072; const float* Wn2_l = Wn2 + l * 131072;
    const float* Woi_l = Woi + l * 32768; const float* Woj_l = Woj + l * 32768;
    const bf16* WgaT_l = WgaT + l * 16384; const bf16* WaT_l  = WaT  + l * 16384;
    const bf16* WgbT_l = WgbT + l * 16384; const bf16* Wb2T_l = Wb2T + l * 16384;
    const bf16* WgpT_l = WgpT + l * 16384; const bf16* WpT_l  = WpT  + l * 16384;
    const bf16* We1T_l = We1T + l * 32768; const bf16* We2T_l = We2T + l * 32768;

    // (a) cross attention
    ln_kernel<256, float, float><<<1024, 256, 0, stream>>>(X, Xn);
    rowmat_kernel<256, 256, 0><<<128, 256, 0, stream>>>(Xn, Wq_l, qb);
    rowmat_kernel<256, 256, 0><<<64, 256, 0, stream>>>(src, Wk_l, kb);
    rowmat_kernel<256, 256, 0><<<64, 256, 0, stream>>>(src, Wv_l, vb);
    cross_attn_kernel<<<1024, 256, 0, stream>>>(qb, kb, vb, ob);
    rowmat_kernel<256, 256, 1><<<128, 256, 0, stream>>>(ob, Wo_l, X);

    // (b) pair-biased self attention
    ln128w_kernel<float, bf16><<<32768, 256, 0, stream>>>(E, En);
    head8_kernel<128, 1, 0><<<4096, 256, 0, stream>>>(En, Wb_l, bias, nullptr, nullptr);
    ln_kernel<256, float, float><<<1024, 256, 0, stream>>>(X, Xn);
    rowmat_kernel<256, 256, 0><<<128, 256, 0, stream>>>(Xn, Sq_l, qb);
    rowmat_kernel<256, 256, 0><<<128, 256, 0, stream>>>(Xn, Sk_l, kb);
    rowmat_kernel<256, 256, 0><<<128, 256, 0, stream>>>(Xn, Sv_l, vb);
    self_attn_kernel<<<1024, 256, 0, stream>>>(qb, kb, vb, bias, ob);
    rowmat_kernel<256, 256, 1><<<128, 256, 0, stream>>>(ob, So_l, X);

    // (c) node MLP
    ln_kernel<256, float, float><<<1024, 256, 0, stream>>>(X, Xn);
    node_mlp_kernel<1><<<1024, 256, 0, stream>>>(Xn, Wn1_l, Wn2_l, X);

    // (d) outer sum into E
    ln_kernel<256, float, float><<<1024, 256, 0, stream>>>(X, Xn);
    rowmat_kernel<256, 128, 0><<<128, 128, 0, stream>>>(Xn, Woi_l, xi);
    rowmat_kernel<256, 128, 0><<<128, 128, 0, stream>>>(Xn, Woj_l, xj);
    outer_sum_kernel<<<65536, 256, 0, stream>>>(E, xi, xj);

    // (e) triangle multiplicative update (MFMA)
    ln128w_kernel<float, bf16><<<32768, 256, 0, stream>>>(E, En);
    mfma_nw2_kernel<128, 0><<<512, 256, 0, stream>>>(En, WgaT_l, WaT_l, aB);
    mfma_nw2_kernel<128, 0><<<512, 256, 0, stream>>>(En, WgbT_l, Wb2T_l, bB);
    tri_kernel<<<dim3(32, 32, 8), 128, 0, stream>>>(aB, bB, tB);
    ln128w_kernel<bf16, bf16><<<32768, 256, 0, stream>>>(tB, tB);
    mfma_gateadd_kernel<<<1024, 256, 0, stream>>>(En, tB, WgpT_l, WpT_l, E);

    // (f) edge MLP (MFMA)
    ln128w_kernel<float, bf16><<<32768, 256, 0, stream>>>(E, En);
    mfma_nw2_kernel<128, 1><<<512, 256, 0, stream>>>(En, We1T_l, We1T_l + 16384, H);
    mfma_add_kernel<<<512, 256, 0, stream>>>(H, We2T_l, E);
  }

  // final norms
  ln_kernel<256, float, float><<<1024, 256, 0, stream>>>(X, Xn);
  ln128w_kernel<float, bf16><<<32768, 256, 0, stream>>>(E, En);   // Enf

  // node heads
  node_mlp_kernel<0><<<1024, 256, 0, stream>>>(Xn, neW1, neW2, out_ne);
  rowdot_kernel<256><<<1024, 256, 0, stream>>>(Xn, hW, out_h);
  rowmat_kernel<256, 32, 0><<<128, 32, 0, stream>>>(Xn, nlW, out_nl);
  node_feat_kernel<<<1024, 256, 0, stream>>>(Xn, nfW1, nfW2, out_nf);

  // edge heads (from bf16 Enf)
  head8_kernel<128, 0, 1><<<4096, 256, 0, stream>>>(En, elW, out_el, aW, out_A);
  mfma_nw2_kernel<128, 1><<<512, 256, 0, stream>>>(En, efW1T, efW1T + 16384, H);
  head8_kernel<256, 0, 0><<<4096, 256, 0, stream>>>(H, efW2, out_ef, nullptr, nullptr);
}

// Round 4
// 3973.127 us; speedup vs baseline: 2.4614x; 1.2533x over previous
//
#include <hip/hip_runtime.h>
#include <hip/hip_bf16.h>

using bf16 = __hip_bfloat16;

constexpr int Bc = 8, Kc = 64, Mc = 128, Dnc = 256, Dec = 128, Hnc = 512, Hec = 256, Hc = 8;
constexpr float INV_SQRT_DH = 0.17677669529663687f;   // 1/sqrt(32)

typedef __attribute__((ext_vector_type(8))) short s8v;   // 8 bf16 (4 VGPRs)
typedef __attribute__((ext_vector_type(4))) float f4v;   // 4 fp32
#define MFMA16(a, b, c) __builtin_amdgcn_mfma_f32_16x16x32_bf16(a, b, c, 0, 0, 0)

// ---------- helpers ----------
__device__ __forceinline__ float waveSum(float v) {
#pragma unroll
  for (int m = 32; m > 0; m >>= 1) v += __shfl_xor(v, m);
  return v;
}
__device__ __forceinline__ float grpSum32(float v) {
#pragma unroll
  for (int m = 16; m > 0; m >>= 1) v += __shfl_xor(v, m);
  return v;
}
__device__ __forceinline__ float grpMax32(float v) {
#pragma unroll
  for (int m = 16; m > 0; m >>= 1) v = fmaxf(v, __shfl_xor(v, m));
  return v;
}
__device__ __forceinline__ float b2f(unsigned short u) {
  union { unsigned x; float f; } v; v.x = (unsigned)u << 16; return v.f;
}
__device__ __forceinline__ unsigned short f2bu(float f) {
  bf16 h = __float2bfloat16(f); return *reinterpret_cast<unsigned short*>(&h);
}
__device__ __forceinline__ float ldf(const float* p) { return *p; }
__device__ __forceinline__ float ldf(const bf16* p)  { return __bfloat162float(*p); }
__device__ __forceinline__ void  stf(float* p, float v) { *p = v; }
__device__ __forceinline__ void  stf(bf16*  p, float v) { *p = __float2bfloat16(v); }

// ---------- LayerNorm over last dim D (one row per block; node-side) ----------
template<int D, typename InT, typename OutT>
__global__ __launch_bounds__(D) void ln_kernel(const InT* __restrict__ in, OutT* __restrict__ out) {
  constexpr int NW = D / 64;
  __shared__ float sb[NW];
  size_t row = blockIdx.x;
  int t = threadIdx.x;
  float v = ldf(in + row * D + t);
  float s = waveSum(v);
  if ((t & 63) == 0) sb[t >> 6] = s;
  __syncthreads();
  float tot = 0.f;
#pragma unroll
  for (int i = 0; i < NW; i++) tot += sb[i];
  float mean = tot * (1.0f / D);
  float d = v - mean;
  __syncthreads();
  float s2 = waveSum(d * d);
  if ((t & 63) == 0) sb[t >> 6] = s2;
  __syncthreads();
  float tot2 = 0.f;
#pragma unroll
  for (int i = 0; i < NW; i++) tot2 += sb[i];
  float rstd = rsqrtf(tot2 * (1.0f / D) + 1e-5f);
  stf(out + row * D + t, d * rstd);
}

// ---------- LayerNorm D=128, one row per WAVE (pre-loop E->En) ----------
template<typename InT, typename OutT>
__global__ __launch_bounds__(256) void ln128w_kernel(const InT* __restrict__ in,
                                                     OutT* __restrict__ out) {
  size_t row = (size_t)blockIdx.x * 4 + (threadIdx.x >> 6);
  int l = threadIdx.x & 63;
  const InT* p = in + row * 128 + l * 2;
  float v0 = ldf(p), v1 = ldf(p + 1);
  float mean = waveSum(v0 + v1) * (1.f / 128.f);
  float d0 = v0 - mean, d1 = v1 - mean;
  float rstd = rsqrtf(waveSum(d0 * d0 + d1 * d1) * (1.f / 128.f) + 1e-5f);
  OutT* q = out + row * 128 + l * 2;
  stf(q, d0 * rstd);
  stf(q + 1, d1 * rstd);
}

// ---------- broadcast init ----------
__global__ void bcast_kernel(const float* __restrict__ s, float* __restrict__ d,
                             unsigned mask, size_t total) {
  size_t i = (size_t)blockIdx.x * blockDim.x + threadIdx.x;
  if (i < total) d[i] = s[i & mask];
}

// ---------- weight transpose+convert: out[n][k] = bf16(in[k][n]) ----------
__global__ __launch_bounds__(256) void twcvt_kernel(const float* __restrict__ in,
                                                    bf16* __restrict__ out, int K, int N) {
  const float* inp = in + (size_t)blockIdx.z * K * N;
  bf16* outp = out + (size_t)blockIdx.z * K * N;
  __shared__ float tile[32][33];
  int tx = threadIdx.x & 31, ty = threadIdx.x >> 5;
  int k0 = blockIdx.y * 32, n0 = blockIdx.x * 32;
#pragma unroll
  for (int it = 0; it < 4; it++)
    tile[ty + it * 8][tx] = inp[(size_t)(k0 + ty + it * 8) * N + n0 + tx];
  __syncthreads();
#pragma unroll
  for (int it = 0; it < 4; it++)
    outp[(size_t)(n0 + ty + it * 8) * K + k0 + tx] = __float2bfloat16(tile[tx][ty + it * 8]);
}

// ---------- MFMA tile staging with XOR swizzle (rows x 128 bf16 per k-chunk) ----------
template<int ROWS>
__device__ __forceinline__ void stageTile(const bf16* __restrict__ g, int srcLd,
                                          char* lds, int t) {
  constexpr int IT = ROWS * 16 / 256;
#pragma unroll
  for (int it = 0; it < IT; it++) {
    int u = t + it * 256;
    int row = u >> 4, c16 = u & 15;
    uint4 val = *(const uint4*)(g + (size_t)row * srcLd + c16 * 8);
    *(uint4*)(lds + row * 256 + ((c16 ^ (row & 7)) << 4)) = val;
  }
}
__device__ __forceinline__ s8v readFrag(const char* lds, int row, int c16) {
  return *(const s8v*)(lds + row * 256 + ((c16 ^ (row & 7)) << 4));
}

// ---------- MFMA GEMM, 256 rows x 128 cols, two weight mats, K=128 ----------
// EPI 1: out bf16[Rx256] = relu(acc0) | relu(acc1)   (MLP hidden)
// EPI 2: gated sigmoid(acc0)*acc1, written TRANSPOSED as out[b][c][ik]
template<int EPI>
__global__ __launch_bounds__(256, 1) void mfma_nw2_kernel(
    const bf16* __restrict__ A, const bf16* __restrict__ W0t, const bf16* __restrict__ W1t,
    bf16* __restrict__ out) {
  __shared__ char lds[131072];
  char* Ash = lds; char* W0sh = lds + 65536; char* W1sh = lds + 98304;
  int t = threadIdx.x, l = t & 63, w = t >> 6;
  size_t r0 = (size_t)blockIdx.x * 256;
  int rb = w * 64;
  stageTile<256>(A + r0 * 128, 128, Ash, t);
  stageTile<128>(W0t, 128, W0sh, t);
  stageTile<128>(W1t, 128, W1sh, t);
  __syncthreads();
  f4v acc0[4][8], acc1[4][8];
#pragma unroll
  for (int rf = 0; rf < 4; rf++)
#pragma unroll
    for (int cf = 0; cf < 8; cf++) {
      acc0[rf][cf] = (f4v){0.f, 0.f, 0.f, 0.f};
      acc1[rf][cf] = (f4v){0.f, 0.f, 0.f, 0.f};
    }
#pragma unroll
  for (int kc = 0; kc < 4; kc++) {
    int c16 = kc * 4 + (l >> 4);
    s8v af[4];
#pragma unroll
    for (int rf = 0; rf < 4; rf++) af[rf] = readFrag(Ash, rb + rf * 16 + (l & 15), c16);
#pragma unroll
    for (int cf = 0; cf < 8; cf++) {
      s8v b0 = readFrag(W0sh, cf * 16 + (l & 15), c16);
      s8v b1 = readFrag(W1sh, cf * 16 + (l & 15), c16);
#pragma unroll
      for (int rf = 0; rf < 4; rf++) {
        acc0[rf][cf] = MFMA16(af[rf], b0, acc0[rf][cf]);
        acc1[rf][cf] = MFMA16(af[rf], b1, acc1[rf][cf]);
      }
    }
  }
  if (EPI == 1) {
#pragma unroll
    for (int rf = 0; rf < 4; rf++)
#pragma unroll
      for (int cf = 0; cf < 8; cf++)
#pragma unroll
        for (int i = 0; i < 4; i++) {
          size_t row = r0 + rb + rf * 16 + ((l >> 4) << 2) + i;
          int col = cf * 16 + (l & 15);
          out[row * 256 + col]       = __float2bfloat16(fmaxf(acc0[rf][cf][i], 0.f));
          out[row * 256 + 128 + col] = __float2bfloat16(fmaxf(acc1[rf][cf][i], 0.f));
        }
  } else {
    __syncthreads();
    char* tb = lds;   // 128c x 560B rows = 71.7KB, overlaps Ash/W0sh (dead)
#pragma unroll
    for (int rf = 0; rf < 4; rf++)
#pragma unroll
      for (int cf = 0; cf < 8; cf++) {
        int c = cf * 16 + (l & 15);
        int u0 = rb + rf * 16 + ((l >> 4) << 2);
        uint2 pv;
        pv.x = (unsigned)f2bu(acc1[rf][cf][0] / (1.f + __expf(-acc0[rf][cf][0]))) |
               ((unsigned)f2bu(acc1[rf][cf][1] / (1.f + __expf(-acc0[rf][cf][1]))) << 16);
        pv.y = (unsigned)f2bu(acc1[rf][cf][2] / (1.f + __expf(-acc0[rf][cf][2]))) |
               ((unsigned)f2bu(acc1[rf][cf][3] / (1.f + __expf(-acc0[rf][cf][3]))) << 16);
        *(uint2*)(tb + c * 560 + u0 * 2) = pv;
      }
    __syncthreads();
    int b_ = (int)(r0 >> 14); int ik0 = (int)(r0 & 16383);
    bf16* op = out + (size_t)b_ * 2097152 + ik0;
    int c2 = t >> 1, hf = t & 1;
#pragma unroll
    for (int q = 0; q < 16; q++) {
      int u = hf * 128 + q * 8;
      *(uint4*)(op + (size_t)c2 * 16384 + u) = *(const uint4*)(tb + c2 * 560 + u * 2);
    }
  }
}

// ---------- G = sigmoid(En @ Wt); 128 rows/block, K=128 ----------
__global__ __launch_bounds__(256) void mfma_sig_kernel(
    const bf16* __restrict__ A, const bf16* __restrict__ Wt, bf16* __restrict__ out) {
  __shared__ char lds[65536];
  char* Ash = lds; char* Wsh = lds + 32768;
  int t = threadIdx.x, l = t & 63, w = t >> 6;
  size_t r0 = (size_t)blockIdx.x * 128;
  int rb = w * 32;
  stageTile<128>(A + r0 * 128, 128, Ash, t);
  stageTile<128>(Wt, 128, Wsh, t);
  __syncthreads();
  f4v acc[2][8];
#pragma unroll
  for (int rf = 0; rf < 2; rf++)
#pragma unroll
    for (int cf = 0; cf < 8; cf++) acc[rf][cf] = (f4v){0.f, 0.f, 0.f, 0.f};
#pragma unroll
  for (int kc = 0; kc < 4; kc++) {
    int c16 = kc * 4 + (l >> 4);
    s8v af[2];
#pragma unroll
    for (int rf = 0; rf < 2; rf++) af[rf] = readFrag(Ash, rb + rf * 16 + (l & 15), c16);
#pragma unroll
    for (int cf = 0; cf < 8; cf++) {
      s8v b0 = readFrag(Wsh, cf * 16 + (l & 15), c16);
#pragma unroll
      for (int rf = 0; rf < 2; rf++) acc[rf][cf] = MFMA16(af[rf], b0, acc[rf][cf]);
    }
  }
#pragma unroll
  for (int rf = 0; rf < 2; rf++)
#pragma unroll
    for (int cf = 0; cf < 8; cf++)
#pragma unroll
      for (int i = 0; i < 4; i++) {
        size_t row = r0 + rb + rf * 16 + ((l >> 4) << 2) + i;
        int col = cf * 16 + (l & 15);
        out[row * 128 + col] = __float2bfloat16(1.f / (1.f + __expf(-acc[rf][cf][i])));
      }
}

// ---------- E += G * (Tn@Wt); then En = LN(E) fused; 128 rows/block, K=128 ----------
__global__ __launch_bounds__(256) void mfma_gmul_add_ln_kernel(
    const bf16* __restrict__ A, const bf16* __restrict__ Wt, const bf16* __restrict__ G,
    float* __restrict__ E, bf16* __restrict__ En) {
  __shared__ char lds[65536];
  char* Ash = lds; char* Wsh = lds + 32768;
  int t = threadIdx.x, l = t & 63, w = t >> 6;
  size_t r0 = (size_t)blockIdx.x * 128;
  int rb = w * 32;
  stageTile<128>(A + r0 * 128, 128, Ash, t);
  stageTile<128>(Wt, 128, Wsh, t);
  __syncthreads();
  f4v acc[2][8];
#pragma unroll
  for (int rf = 0; rf < 2; rf++)
#pragma unroll
    for (int cf = 0; cf < 8; cf++) acc[rf][cf] = (f4v){0.f, 0.f, 0.f, 0.f};
#pragma unroll
  for (int kc = 0; kc < 4; kc++) {
    int c16 = kc * 4 + (l >> 4);
    s8v af[2];
#pragma unroll
    for (int rf = 0; rf < 2; rf++) af[rf] = readFrag(Ash, rb + rf * 16 + (l & 15), c16);
#pragma unroll
    for (int cf = 0; cf < 8; cf++) {
      s8v b0 = readFrag(Wsh, cf * 16 + (l & 15), c16);
#pragma unroll
      for (int rf = 0; rf < 2; rf++) acc[rf][cf] = MFMA16(af[rf], b0, acc[rf][cf]);
    }
  }
  float vv[2][8][4];
#pragma unroll
  for (int rf = 0; rf < 2; rf++)
#pragma unroll
    for (int cf = 0; cf < 8; cf++)
#pragma unroll
      for (int i = 0; i < 4; i++) {
        size_t row = r0 + rb + rf * 16 + ((l >> 4) << 2) + i;
        size_t o = row * 128 + cf * 16 + (l & 15);
        float e = E[o] + __bfloat162float(G[o]) * acc[rf][cf][i];
        E[o] = e; vv[rf][cf][i] = e;
      }
#pragma unroll
  for (int rf = 0; rf < 2; rf++)
#pragma unroll
    for (int i = 0; i < 4; i++) {
      float s = 0.f, s2 = 0.f;
#pragma unroll
      for (int cf = 0; cf < 8; cf++) { float x = vv[rf][cf][i]; s += x; s2 += x * x; }
#pragma unroll
      for (int m = 1; m < 16; m <<= 1) { s += __shfl_xor(s, m); s2 += __shfl_xor(s2, m); }
      float mean = s * 0.0078125f;
      float rstd = rsqrtf(s2 * 0.0078125f - mean * mean + 1e-5f);
      size_t row = r0 + rb + rf * 16 + ((l >> 4) << 2) + i;
#pragma unroll
      for (int cf = 0; cf < 8; cf++)
        En[row * 128 + cf * 16 + (l & 15)] = __float2bfloat16((vv[rf][cf][i] - mean) * rstd);
    }
}

// ---------- E += H @ Wt (K=256); then En = LN(E) fused; 128 rows/block ----------
__global__ __launch_bounds__(256) void mfma_add_ln_kernel(
    const bf16* __restrict__ A, const bf16* __restrict__ Wt,
    float* __restrict__ E, bf16* __restrict__ En) {
  __shared__ char lds[65536];
  char* Ash = lds; char* Wsh = lds + 32768;
  int t = threadIdx.x, l = t & 63, w = t >> 6;
  size_t r0 = (size_t)blockIdx.x * 128;
  int rb = w * 32;
  f4v acc[2][8];
#pragma unroll
  for (int rf = 0; rf < 2; rf++)
#pragma unroll
    for (int cf = 0; cf < 8; cf++) acc[rf][cf] = (f4v){0.f, 0.f, 0.f, 0.f};
#pragma unroll
  for (int kb = 0; kb < 2; kb++) {
    if (kb) __syncthreads();
    stageTile<128>(A + r0 * 256 + kb * 128, 256, Ash, t);
    stageTile<128>(Wt + kb * 128, 256, Wsh, t);
    __syncthreads();
#pragma unroll
    for (int kc = 0; kc < 4; kc++) {
      int c16 = kc * 4 + (l >> 4);
      s8v af[2];
#pragma unroll
      for (int rf = 0; rf < 2; rf++) af[rf] = readFrag(Ash, rb + rf * 16 + (l & 15), c16);
#pragma unroll
      for (int cf = 0; cf < 8; cf++) {
        s8v b0 = readFrag(Wsh, cf * 16 + (l & 15), c16);
#pragma unroll
        for (int rf = 0; rf < 2; rf++) acc[rf][cf] = MFMA16(af[rf], b0, acc[rf][cf]);
      }
    }
  }
  float vv[2][8][4];
#pragma unroll
  for (int rf = 0; rf < 2; rf++)
#pragma unroll
    for (int cf = 0; cf < 8; cf++)
#pragma unroll
      for (int i = 0; i < 4; i++) {
        size_t row = r0 + rb + rf * 16 + ((l >> 4) << 2) + i;
        size_t o = row * 128 + cf * 16 + (l & 15);
        float e = E[o] + acc[rf][cf][i];
        E[o] = e; vv[rf][cf][i] = e;
      }
#pragma unroll
  for (int rf = 0; rf < 2; rf++)
#pragma unroll
    for (int i = 0; i < 4; i++) {
      float s = 0.f, s2 = 0.f;
#pragma unroll
      for (int cf = 0; cf < 8; cf++) { float x = vv[rf][cf][i]; s += x; s2 += x * x; }
#pragma unroll
      for (int m = 1; m < 16; m <<= 1) { s += __shfl_xor(s, m); s2 += __shfl_xor(s2, m); }
      float mean = s * 0.0078125f;
      float rstd = rsqrtf(s2 * 0.0078125f - mean * mean + 1e-5f);
      size_t row = r0 + rb + rf * 16 + ((l >> 4) << 2) + i;
#pragma unroll
      for (int cf = 0; cf < 8; cf++)
        En[row * 128 + cf * 16 + (l & 15)] = __float2bfloat16((vv[rf][cf][i] - mean) * rstd);
    }
}

// ---------- triangle via MFMA: one block per (b,c); both terms; out [b][c][j][i] ----------
__global__ __launch_bounds__(256, 1) void tri_mfma_kernel(
    const bf16* __restrict__ aT, const bf16* __restrict__ bT, bf16* __restrict__ Tcm) {
  __shared__ char lds[131072];
  char* P1 = lds; char* Q1 = lds + 32768; char* P2 = lds + 65536; char* Q2 = lds + 98304;
  int t = threadIdx.x, l = t & 63, w = t >> 6;
  int bc = blockIdx.x;
  stageTile<128>(aT + (size_t)bc * 16384, 128, P1, t);
  stageTile<128>(bT + (size_t)bc * 16384, 128, Q1, t);
  __syncthreads();
  // in-LDS transpose P1->P2, Q1->Q2 (8x8 tiles, conflict-free lane mapping)
#pragma unroll 8
  for (int it = 0; it < 64; it++) {
    int tile_ = w * 64 + it;
    int k0 = (tile_ & 15) * 8, r0 = (tile_ >> 4) * 8;
    int k = k0 + (l & 7), r = r0 + (l >> 3);
    int ra = r * 256 + ((((k >> 3) ^ (r & 7)) << 4)) + (k & 7) * 2;
    int wa = k * 256 + ((((r >> 3) ^ (k & 7)) << 4)) + (r & 7) * 2;
    *(unsigned short*)(P2 + wa) = *(const unsigned short*)(P1 + ra);
    *(unsigned short*)(Q2 + wa) = *(const unsigned short*)(Q1 + ra);
  }
  __syncthreads();
  int rb = w * 32;
  f4v acc1[2][8], acc2[2][8];
#pragma unroll
  for (int rf = 0; rf < 2; rf++)
#pragma unroll
    for (int cf = 0; cf < 8; cf++) {
      acc1[rf][cf] = (f4v){0.f, 0.f, 0.f, 0.f};
      acc2[rf][cf] = (f4v){0.f, 0.f, 0.f, 0.f};
    }
#pragma unroll
  for (int kc = 0; kc < 4; kc++) {
    int c16 = kc * 4 + (l >> 4);
    s8v a1[2], a2[2];
#pragma unroll
    for (int rf = 0; rf < 2; rf++) {
      a1[rf] = readFrag(P1, rb + rf * 16 + (l & 15), c16);
      a2[rf] = readFrag(P2, rb + rf * 16 + (l & 15), c16);
    }
#pragma unroll
    for (int cf = 0; cf < 8; cf++) {
      s8v b1 = readFrag(Q1, cf * 16 + (l & 15), c16);
      s8v b2 = readFrag(Q2, cf * 16 + (l & 15), c16);
#pragma unroll
      for (int rf = 0; rf < 2; rf++) {
        acc1[rf][cf] = MFMA16(a1[rf], b1, acc1[rf][cf]);
        acc2[rf][cf] = MFMA16(a2[rf], b2, acc2[rf][cf]);
      }
    }
  }
  __syncthreads();
  char* tb = lds;   // [j][i] 128 x 560B = 71.7KB (overlaps P1/Q1/P2, dead)
#pragma unroll
  for (int rf = 0; rf < 2; rf++)
#pragma unroll
    for (int cf = 0; cf < 8; cf++) {
      int j = cf * 16 + (l & 15);
      int i0 = rb + rf * 16 + ((l >> 4) << 2);
      uint2 pv;
      pv.x = (unsigned)f2bu(0.5f * (acc1[rf][cf][0] + acc2[rf][cf][0])) |
             ((unsigned)f2bu(0.5f * (acc1[rf][cf][1] + acc2[rf][cf][1])) << 16);
      pv.y = (unsigned)f2bu(0.5f * (acc1[rf][cf][2] + acc2[rf][cf][2])) |
             ((unsigned)f2bu(0.5f * (acc1[rf][cf][3] + acc2[rf][cf][3])) << 16);
      *(uint2*)(tb + j * 560 + i0 * 2) = pv;
    }
  __syncthreads();
  bf16* op = Tcm + (size_t)bc * 16384;
#pragma unroll
  for (int q = 0; q < 8; q++) {
    int ci = q * 256 + t;
    *(uint4*)(op + ci * 8) = *(const uint4*)(tb + (ci >> 4) * 560 + (ci & 15) * 16);
  }
}

// ---------- permute + LN: Tcm[b][c][j][i] -> Tn[(b,i,j)][c] with LN over c ----------
__global__ __launch_bounds__(256) void permln_kernel(const bf16* __restrict__ Tcm,
                                                     bf16* __restrict__ Tn) {
  __shared__ float tile[128][77];
  __shared__ float ps[4][64], ps2[4][64], mst[64], rst[64];
  int b = blockIdx.z, j = blockIdx.y, i0 = blockIdx.x * 64;
  int t = threadIdx.x;
  const bf16* src = Tcm + (size_t)b * 2097152 + j * 128 + i0;
#pragma unroll
  for (int q = 0; q < 4; q++) {
    int ci = q * 256 + t; int c = ci >> 3, ch = ci & 7;
    uint4 v = *(const uint4*)(src + (size_t)c * 16384 + ch * 8);
    const unsigned short* u = (const unsigned short*)&v;
#pragma unroll
    for (int e = 0; e < 8; e++) tile[c][ch * 8 + e] = b2f(u[e]);
  }
  __syncthreads();
  {
    int i_ = t & 63, part = t >> 6;
    float s = 0.f, s2 = 0.f;
    for (int c = part * 32; c < part * 32 + 32; c++) { float x = tile[c][i_]; s += x; s2 += x * x; }
    ps[part][i_] = s; ps2[part][i_] = s2;
  }
  __syncthreads();
  if (t < 64) {
    float s = ps[0][t] + ps[1][t] + ps[2][t] + ps[3][t];
    float q2 = ps2[0][t] + ps2[1][t] + ps2[2][t] + ps2[3][t];
    float mean = s * 0.0078125f;
    float var = q2 * 0.0078125f - mean * mean;
    mst[t] = mean; rst[t] = rsqrtf(var + 1e-5f);
  }
  __syncthreads();
  {
    int i2 = t & 63, c0 = (t >> 6) * 32;
    float mean = mst[i2], rstd = rst[i2];
    bf16* dst = Tn + ((size_t)b * 16384 + (size_t)(i0 + i2) * 128 + j) * 128 + c0;
#pragma unroll
    for (int qq = 0; qq < 4; qq++) {
      unsigned short pk[8];
#pragma unroll
      for (int e = 0; e < 8; e++)
        pk[e] = f2bu((tile[c0 + qq * 8 + e][i2] - mean) * rstd);
      *(uint4*)(dst + qq * 8) = *(uint4*)pk;
    }
  }
}

// ---------- E += outer(xi,xj); En = LN(E) fused; 2 rows/block ----------
__global__ __launch_bounds__(256) void outer_ln_kernel(float* __restrict__ E,
    const float* __restrict__ xi, const float* __restrict__ xj, bf16* __restrict__ En) {
  __shared__ float sb[8];
  size_t r = (size_t)blockIdx.x * 2 + (threadIdx.x >> 7);
  int t = threadIdx.x & 127;
  int b = (int)(r >> 14), i = (int)((r >> 7) & 127), j = (int)(r & 127);
  size_t o = r * 128 + t;
  float e = E[o] + xi[(size_t)(b * 128 + i) * 128 + t] + xj[(size_t)(b * 128 + j) * 128 + t];
  E[o] = e;
  int wg = threadIdx.x >> 6, rh = threadIdx.x >> 7;
  float s = waveSum(e);
  if ((threadIdx.x & 63) == 0) sb[wg] = s;
  __syncthreads();
  float mean = (sb[rh * 2] + sb[rh * 2 + 1]) * (1.f / 128.f);
  float d = e - mean;
  float s2 = waveSum(d * d);
  if ((threadIdx.x & 63) == 0) sb[4 + wg] = s2;
  __syncthreads();
  float rstd = rsqrtf((sb[4 + rh * 2] + sb[4 + rh * 2 + 1]) * (1.f / 128.f) + 1e-5f);
  En[o] = __float2bfloat16(d * rstd);
}

// ---------- 8-col head: out[r,h] = sum_k A[r,k]*W[k,h]; BIAS scatter / A-dot ----------
template<int K, int BIAS, int WITHA>
__global__ __launch_bounds__(256) void head8_kernel(const bf16* __restrict__ A,
    const float* __restrict__ W, float* __restrict__ out,
    const float* __restrict__ aW, float* __restrict__ outA) {
  __shared__ __align__(16) bf16 As[32 * K];
  __shared__ float Ws[K * 8];
  __shared__ float aWs[128];
  size_t r0 = (size_t)blockIdx.x * 32;
  int t = threadIdx.x;
  constexpr int NCH = 32 * K / 8;
#pragma unroll
  for (int it = 0; it < NCH / 256; it++)
    ((uint4*)As)[t + it * 256] = ((const uint4*)(A + r0 * K))[t + it * 256];
  for (int u = t; u < K * 8; u += 256) Ws[u] = W[u];
  if (WITHA) { if (t < 128) aWs[t] = aW[t]; }
  __syncthreads();
  int rr = t >> 3, h = t & 7;
  float acc = 0.f;
#pragma unroll 4
  for (int k = 0; k < K; k++) acc += __bfloat162float(As[rr * K + k]) * Ws[k * 8 + h];
  size_t r = r0 + rr;
  if (BIAS) {
    size_t b = r >> 14, ij = r & 16383;
    out[((b * 8 + h) << 14) + ij] = acc;
  } else {
    out[r * 8 + h] = acc;
  }
  if (WITHA) {
    if (t < 32) {
      float a2 = 0.f;
#pragma unroll 4
      for (int k = 0; k < K; k++) a2 += __bfloat162float(As[t * K + k]) * aWs[k];
      outA[r0 + t] = a2;
    }
  }
}

// ---------- node-side C[R,ND] = A[R,KD] @ W[KD,ND] (8 rows/block; MODE1: +=) ----------
template<int KD, int ND, int MODE>
__global__ __launch_bounds__(ND) void rowmat_kernel(const float* __restrict__ A,
                                                    const float* __restrict__ W,
                                                    float* __restrict__ C) {
  __shared__ float a[8][KD];
  int r0 = blockIdx.x * 8;
  int t = threadIdx.x;
  for (int i = t; i < 8 * KD; i += ND) a[i / KD][i % KD] = A[(size_t)r0 * KD + i];
  __syncthreads();
  float acc[8];
#pragma unroll
  for (int i = 0; i < 8; i++) acc[i] = 0.f;
#pragma unroll 4
  for (int k = 0; k < KD; k++) {
    float w = W[(size_t)k * ND + t];
#pragma unroll
    for (int i = 0; i < 8; i++) acc[i] += a[i][k] * w;
  }
#pragma unroll
  for (int i = 0; i < 8; i++) {
    size_t o = (size_t)(r0 + i) * ND + t;
    if (MODE) C[o] += acc[i]; else C[o] = acc[i];
  }
}

// ---------- cross attention ----------
__global__ __launch_bounds__(256) void cross_attn_kernel(const float* __restrict__ q,
    const float* __restrict__ kk, const float* __restrict__ vv, float* __restrict__ o) {
  __shared__ float sc[Hc][Kc];
  int bm = blockIdx.x; int b = bm >> 7;
  int t = threadIdx.x; int h = t >> 5; int d = t & 31;
  float qv = q[(size_t)bm * Dnc + h * 32 + d] * INV_SQRT_DH;
  for (int k0 = 0; k0 < Kc; k0++) {
    float kv = kk[((size_t)(b * Kc + k0)) * Dnc + h * 32 + d];
    float p = grpSum32(qv * kv);
    if (d == 0) sc[h][k0] = p;
  }
  __syncthreads();
  float s0 = sc[h][d], s1 = sc[h][d + 32];
  float mx = grpMax32(fmaxf(s0, s1));
  float e0 = __expf(s0 - mx), e1 = __expf(s1 - mx);
  float sm = grpSum32(e0 + e1);
  float rs = 1.f / sm;
  sc[h][d] = e0 * rs; sc[h][d + 32] = e1 * rs;
  __syncthreads();
  float acc = 0.f;
  for (int k0 = 0; k0 < Kc; k0++)
    acc += sc[h][k0] * vv[((size_t)(b * Kc + k0)) * Dnc + h * 32 + d];
  o[(size_t)bm * Dnc + h * 32 + d] = acc;
}

// ---------- pair-biased self attention ----------
__global__ __launch_bounds__(256) void self_attn_kernel(const float* __restrict__ q,
    const float* __restrict__ kk, const float* __restrict__ vv,
    const float* __restrict__ bias, float* __restrict__ o) {
  __shared__ float sc[Hc][Mc];
  int bm = blockIdx.x; int b = bm >> 7, i = bm & 127;
  int t = threadIdx.x; int h = t >> 5, d = t & 31;
  float qv = q[(size_t)bm * Dnc + h * 32 + d] * INV_SQRT_DH;
  const float* bs = bias + (((size_t)b * Hc + h) * Mc + i) * Mc;
  for (int j = 0; j < Mc; j++) {
    float kv = kk[((size_t)(b * Mc + j)) * Dnc + h * 32 + d];
    float p = grpSum32(qv * kv);
    if (d == 0) sc[h][j] = p + bs[j];
  }
  __syncthreads();
  float sv[4]; float mx = -1e30f;
#pragma unroll
  for (int u = 0; u < 4; u++) { sv[u] = sc[h][d + 32 * u]; mx = fmaxf(mx, sv[u]); }
  mx = grpMax32(mx);
  float sm = 0.f;
#pragma unroll
  for (int u = 0; u < 4; u++) { sv[u] = __expf(sv[u] - mx); sm += sv[u]; }
  sm = grpSum32(sm);
  float rs = 1.f / sm;
#pragma unroll
  for (int u = 0; u < 4; u++) sc[h][d + 32 * u] = sv[u] * rs;
  __syncthreads();
  float acc = 0.f;
  for (int j = 0; j < Mc; j++)
    acc += sc[h][j] * vv[((size_t)(b * Mc + j)) * Dnc + h * 32 + d];
  o[(size_t)bm * Dnc + h * 32 + d] = acc;
}

// ---------- node MLP ----------
template<int MODE>
__global__ __launch_bounds__(256) void node_mlp_kernel(const float* __restrict__ Xn,
    const float* __restrict__ W1, const float* __restrict__ W2, float* __restrict__ dst) {
  __shared__ float a[Dnc];
  __shared__ float hsh[Hnc];
  size_t r = blockIdx.x;
  int t = threadIdx.x;
  a[t] = Xn[r * Dnc + t];
  __syncthreads();
  for (int hh = t; hh < Hnc; hh += 256) {
    float acc = 0.f;
#pragma unroll 4
    for (int k = 0; k < Dnc; k++) acc += a[k] * W1[(size_t)k * Hnc + hh];
    hsh[hh] = fmaxf(acc, 0.f);
  }
  __syncthreads();
  float acc = 0.f;
#pragma unroll 4
  for (int k = 0; k < Hnc; k++) acc += hsh[k] * W2[(size_t)k * Dnc + t];
  if (MODE) dst[r * Dnc + t] += acc; else dst[r * Dnc + t] = acc;
}

// ---------- node_features head ----------
__global__ __launch_bounds__(256) void node_feat_kernel(const float* __restrict__ Xn,
    const float* __restrict__ W1, const float* __restrict__ W2, float* __restrict__ out) {
  __shared__ float a[Dnc];
  __shared__ float hsh[Hnc];
  size_t r = blockIdx.x;
  int t = threadIdx.x;
  a[t] = Xn[r * Dnc + t];
  __syncthreads();
  for (int hh = t; hh < Hnc; hh += 256) {
    float acc = 0.f;
#pragma unroll 4
    for (int k = 0; k < Dnc; k++) acc += a[k] * W1[(size_t)k * Hnc + hh];
    hsh[hh] = fmaxf(acc, 0.f);
  }
  __syncthreads();
  if (t < 16) {
    float acc = 0.f;
    for (int k = 0; k < Hnc; k++) acc += hsh[k] * W2[k * 16 + t];
    out[r * 16 + t] = acc;
  }
}

// ---------- row dot ----------
template<int D>
__global__ __launch_bounds__(D) void rowdot_kernel(const float* __restrict__ A,
    const float* __restrict__ w, float* __restrict__ out) {
  __shared__ float sb[D / 64];
  size_t r = blockIdx.x; int t = threadIdx.x;
  float v = A[r * D + t] * w[t];
  v = waveSum(v);
  if ((t & 63) == 0) sb[t >> 6] = v;
  __syncthreads();
  if (t == 0) { float s = 0.f; for (int i = 0; i < D / 64; i++) s += sb[i]; out[r] = s; }
}

extern "C" void kernel_launch(void* const* d_in, const int* in_sizes, int n_in,
                              void* d_out, int out_size, void* d_ws, size_t ws_size,
                              hipStream_t stream) {
  const float* graph = (const float*)d_in[0];
  const float* Xq  = (const float*)d_in[1];
  const float* Eq  = (const float*)d_in[2];
  const float* Wq  = (const float*)d_in[3];
  const float* Wk  = (const float*)d_in[4];
  const float* Wv  = (const float*)d_in[5];
  const float* Wo  = (const float*)d_in[6];
  const float* Sq  = (const float*)d_in[7];
  const float* Sk  = (const float*)d_in[8];
  const float* Sv  = (const float*)d_in[9];
  const float* So  = (const float*)d_in[10];
  const float* Wb  = (const float*)d_in[11];
  const float* Wn1 = (const float*)d_in[12];
  const float* Wn2 = (const float*)d_in[13];
  const float* Woi = (const float*)d_in[14];
  const float* Woj = (const float*)d_in[15];
  const float* Wa  = (const float*)d_in[16];
  const float* Wga = (const float*)d_in[17];
  const float* Wb2 = (const float*)d_in[18];
  const float* Wgb = (const float*)d_in[19];
  const float* Wp  = (const float*)d_in[20];
  const float* Wgp = (const float*)d_in[21];
  const float* We1 = (const float*)d_in[22];
  const float* We2 = (const float*)d_in[23];
  const float* hW  = (const float*)d_in[24];
  const float* neW1 = (const float*)d_in[25];
  const float* neW2 = (const float*)d_in[26];
  const float* nlW  = (const float*)d_in[27];
  const float* nfW1 = (const float*)d_in[28];
  const float* nfW2 = (const float*)d_in[29];
  const float* aW   = (const float*)d_in[30];
  const float* elW  = (const float*)d_in[31];
  const float* efW1 = (const float*)d_in[32];
  const float* efW2 = (const float*)d_in[33];

  char* wsb = (char*)d_ws;
  size_t off = 0;
  auto alloc = [&](size_t bytes) -> char* {
    char* p = wsb + off; off += (bytes + 255) & ~(size_t)255; return p;
  };
  float* X   = (float*)alloc((size_t)262144 * 4);
  float* Xn  = (float*)alloc((size_t)262144 * 4);
  float* src = (float*)alloc((size_t)131072 * 4);
  float* qb  = (float*)alloc((size_t)262144 * 4);
  float* kb  = (float*)alloc((size_t)262144 * 4);
  float* vb  = (float*)alloc((size_t)262144 * 4);
  float* ob  = (float*)alloc((size_t)262144 * 4);
  float* bias = (float*)alloc((size_t)1048576 * 4);
  float* xi  = (float*)alloc((size_t)131072 * 4);
  float* xj  = (float*)alloc((size_t)131072 * 4);
  float* E   = (float*)alloc((size_t)16777216 * 4);
  bf16* En   = (bf16*)alloc((size_t)16777216 * 2);
  bf16* aT1  = (bf16*)alloc((size_t)16777216 * 2);   // [b][c][i][k]
  bf16* bT1  = (bf16*)alloc((size_t)16777216 * 2);   // [b][c][j][k]
  bf16* Tcm  = (bf16*)alloc((size_t)16777216 * 2);   // [b][c][j][i]
  bf16* G    = (bf16*)alloc((size_t)16777216 * 2);   // sigmoid(En@Wgp)
  bf16* Tn   = aT1;      // alias: aT1 dead after tri
  bf16* H    = aT1;      // alias: spans aT1+bT1 (contiguous, 67MB)
  // transposed bf16 weights
  bf16* WgaT = (bf16*)alloc((size_t)65536 * 2);
  bf16* WaT  = (bf16*)alloc((size_t)65536 * 2);
  bf16* WgbT = (bf16*)alloc((size_t)65536 * 2);
  bf16* Wb2T = (bf16*)alloc((size_t)65536 * 2);
  bf16* WgpT = (bf16*)alloc((size_t)65536 * 2);
  bf16* WpT  = (bf16*)alloc((size_t)65536 * 2);
  bf16* We1T = (bf16*)alloc((size_t)131072 * 2);
  bf16* We2T = (bf16*)alloc((size_t)131072 * 2);
  bf16* efW1T = (bf16*)alloc((size_t)32768 * 2);

  float* out = (float*)d_out;
  float* out_ne = out;               // 262144
  float* out_h  = out + 262144;      // 1024
  float* out_nl = out + 263168;      // 32768
  float* out_nf = out + 295936;      // 16384
  float* out_A  = out + 312320;      // 131072
  float* out_el = out + 443392;      // 1048576
  float* out_ef = out + 1491968;     // 1048576

  // ---- weight prep ----
  twcvt_kernel<<<dim3(4, 4, 4), 256, 0, stream>>>(Wga, WgaT, 128, 128);
  twcvt_kernel<<<dim3(4, 4, 4), 256, 0, stream>>>(Wa,  WaT,  128, 128);
  twcvt_kernel<<<dim3(4, 4, 4), 256, 0, stream>>>(Wgb, WgbT, 128, 128);
  twcvt_kernel<<<dim3(4, 4, 4), 256, 0, stream>>>(Wb2, Wb2T, 128, 128);
  twcvt_kernel<<<dim3(4, 4, 4), 256, 0, stream>>>(Wgp, WgpT, 128, 128);
  twcvt_kernel<<<dim3(4, 4, 4), 256, 0, stream>>>(Wp,  WpT,  128, 128);
  twcvt_kernel<<<dim3(8, 4, 4), 256, 0, stream>>>(We1, We1T, 128, 256);
  twcvt_kernel<<<dim3(4, 8, 4), 256, 0, stream>>>(We2, We2T, 256, 128);
  twcvt_kernel<<<dim3(8, 4, 1), 256, 0, stream>>>(efW1, efW1T, 128, 256);

  // ---- init ----
  bcast_kernel<<<1024, 256, 0, stream>>>(Xq, X, 32767u, (size_t)262144);
  bcast_kernel<<<65536, 256, 0, stream>>>(Eq, E, 2097151u, (size_t)16777216);
  ln_kernel<256, float, float><<<512, 256, 0, stream>>>(graph, src);
  ln128w_kernel<float, bf16><<<32768, 256, 0, stream>>>(E, En);   // initial En

  for (int l = 0; l < 4; l++) {
    const float* Wq_l = Wq + l * 65536; const float* Wk_l = Wk + l * 65536;
    const float* Wv_l = Wv + l * 65536; const float* Wo_l = Wo + l * 65536;
    const float* Sq_l = Sq + l * 65536; const float* Sk_l = Sk + l * 65536;
    const float* Sv_l = Sv + l * 65536; const float* So_l = So + l * 65536;
    const float* Wb_l = Wb + l * 1024;
    const float* Wn1_l = Wn1 + l * 131072; const float* Wn2_l = Wn2 + l * 131072;
    const float* Woi_l = Woi + l * 32768; const float* Woj_l = Woj + l * 32768;
    const bf16* WgaT_l = WgaT + l * 16384; const bf16* WaT_l  = WaT  + l * 16384;
    const bf16* WgbT_l = WgbT + l * 16384; const bf16* Wb2T_l = Wb2T + l * 16384;
    const bf16* WgpT_l = WgpT + l * 16384; const bf16* WpT_l  = WpT  + l * 16384;
    const bf16* We1T_l = We1T + l * 32768; const bf16* We2T_l = We2T + l * 32768;

    // (a) cross attention
    ln_kernel<256, float, float><<<1024, 256, 0, stream>>>(X, Xn);
    rowmat_kernel<256, 256, 0><<<128, 256, 0, stream>>>(Xn, Wq_l, qb);
    rowmat_kernel<256, 256, 0><<<64, 256, 0, stream>>>(src, Wk_l, kb);
    rowmat_kernel<256, 256, 0><<<64, 256, 0, stream>>>(src, Wv_l, vb);
    cross_attn_kernel<<<1024, 256, 0, stream>>>(qb, kb, vb, ob);
    rowmat_kernel<256, 256, 1><<<128, 256, 0, stream>>>(ob, Wo_l, X);

    // (b) pair-biased self attention (bias from En of layer start)
    head8_kernel<128, 1, 0><<<4096, 256, 0, stream>>>(En, Wb_l, bias, nullptr, nullptr);
    ln_kernel<256, float, float><<<1024, 256, 0, stream>>>(X, Xn);
    rowmat_kernel<256, 256, 0><<<128, 256, 0, stream>>>(Xn, Sq_l, qb);
    rowmat_kernel<256, 256, 0><<<128, 256, 0, stream>>>(Xn, Sk_l, kb);
    rowmat_kernel<256, 256, 0><<<128, 256, 0, stream>>>(Xn, Sv_l, vb);
    self_attn_kernel<<<1024, 256, 0, stream>>>(qb, kb, vb, bias, ob);
    rowmat_kernel<256, 256, 1><<<128, 256, 0, stream>>>(ob, So_l, X);

    // (c) node MLP
    ln_kernel<256, float, float><<<1024, 256, 0, stream>>>(X, Xn);
    node_mlp_kernel<1><<<1024, 256, 0, stream>>>(Xn, Wn1_l, Wn2_l, X);

    // (d) outer sum into E, fused with En = ln(E)
    ln_kernel<256, float, float><<<1024, 256, 0, stream>>>(X, Xn);
    rowmat_kernel<256, 128, 0><<<128, 128, 0, stream>>>(Xn, Woi_l, xi);
    rowmat_kernel<256, 128, 0><<<128, 128, 0, stream>>>(Xn, Woj_l, xj);
    outer_ln_kernel<<<65536, 256, 0, stream>>>(E, xi, xj, En);

    // (e) triangle multiplicative update (all-MFMA)
    mfma_nw2_kernel<2><<<512, 256, 0, stream>>>(En, WgaT_l, WaT_l, aT1);
    mfma_nw2_kernel<2><<<512, 256, 0, stream>>>(En, WgbT_l, Wb2T_l, bT1);
    mfma_sig_kernel<<<1024, 256, 0, stream>>>(En, WgpT_l, G);
    tri_mfma_kernel<<<1024, 256, 0, stream>>>(aT1, bT1, Tcm);
    permln_kernel<<<dim3(2, 128, 8), 256, 0, stream>>>(Tcm, Tn);
    mfma_gmul_add_ln_kernel<<<1024, 256, 0, stream>>>(Tn, WpT_l, G, E, En);

    // (f) edge MLP (En produced for next layer / final heads)
    mfma_nw2_kernel<1><<<512, 256, 0, stream>>>(En, We1T_l, We1T_l + 16384, H);
    mfma_add_ln_kernel<<<1024, 256, 0, stream>>>(H, We2T_l, E, En);
  }

  // final node norm + heads
  ln_kernel<256, float, float><<<1024, 256, 0, stream>>>(X, Xn);
  node_mlp_kernel<0><<<1024, 256, 0, stream>>>(Xn, neW1, neW2, out_ne);
  rowdot_kernel<256><<<1024, 256, 0, stream>>>(Xn, hW, out_h);
  rowmat_kernel<256, 32, 0><<<128, 32, 0, stream>>>(Xn, nlW, out_nl);
  node_feat_kernel<<<1024, 256, 0, stream>>>(Xn, nfW1, nfW2, out_nf);

  // edge heads (En = ln(final E) from last mfma_add_ln)
  head8_kernel<128, 0, 1><<<4096, 256, 0, stream>>>(En, elW, out_el, aW, out_A);
  mfma_nw2_kernel<1><<<512, 256, 0, stream>>>(En, efW1T, efW1T + 16384, H);
  head8_kernel<256, 0, 0><<<4096, 256, 0, stream>>>(H, efW2, out_ef, nullptr, nullptr);
}

// Round 5
// 2596.316 us; speedup vs baseline: 3.7667x; 1.5303x over previous
//
#include <hip/hip_runtime.h>
#include <hip/hip_bf16.h>

using bf16 = __hip_bfloat16;

constexpr int Bc = 8, Kc = 64, Mc = 128, Dnc = 256, Dec = 128, Hnc = 512, Hec = 256, Hc = 8;
constexpr float INV_SQRT_DH = 0.17677669529663687f;   // 1/sqrt(32)

typedef __attribute__((ext_vector_type(8))) short s8v;   // 8 bf16 (4 VGPRs)
typedef __attribute__((ext_vector_type(4))) float f4v;   // 4 fp32
#define MFMA16(a, b, c) __builtin_amdgcn_mfma_f32_16x16x32_bf16(a, b, c, 0, 0, 0)

// ---------- helpers ----------
__device__ __forceinline__ float waveSum(float v) {
#pragma unroll
  for (int m = 32; m > 0; m >>= 1) v += __shfl_xor(v, m);
  return v;
}
__device__ __forceinline__ float grpSum32(float v) {
#pragma unroll
  for (int m = 16; m > 0; m >>= 1) v += __shfl_xor(v, m);
  return v;
}
__device__ __forceinline__ float grpMax32(float v) {
#pragma unroll
  for (int m = 16; m > 0; m >>= 1) v = fmaxf(v, __shfl_xor(v, m));
  return v;
}
__device__ __forceinline__ float b2f(unsigned short u) {
  union { unsigned x; float f; } v; v.x = (unsigned)u << 16; return v.f;
}
__device__ __forceinline__ unsigned short f2bu(float f) {
  bf16 h = __float2bfloat16(f); return *reinterpret_cast<unsigned short*>(&h);
}
__device__ __forceinline__ float ldf(const float* p) { return *p; }
__device__ __forceinline__ float ldf(const bf16* p)  { return __bfloat162float(*p); }
__device__ __forceinline__ void  stf(float* p, float v) { *p = v; }
__device__ __forceinline__ void  stf(bf16*  p, float v) { *p = __float2bfloat16(v); }

// ---------- LayerNorm over last dim D (one row per block) ----------
template<int D, typename InT, typename OutT>
__global__ __launch_bounds__(D) void ln_kernel(const InT* __restrict__ in, OutT* __restrict__ out) {
  constexpr int NW = D / 64;
  __shared__ float sb[NW];
  size_t row = blockIdx.x;
  int t = threadIdx.x;
  float v = ldf(in + row * D + t);
  float s = waveSum(v);
  if ((t & 63) == 0) sb[t >> 6] = s;
  __syncthreads();
  float tot = 0.f;
#pragma unroll
  for (int i = 0; i < NW; i++) tot += sb[i];
  float mean = tot * (1.0f / D);
  float d = v - mean;
  __syncthreads();
  float s2 = waveSum(d * d);
  if ((t & 63) == 0) sb[t >> 6] = s2;
  __syncthreads();
  float tot2 = 0.f;
#pragma unroll
  for (int i = 0; i < NW; i++) tot2 += sb[i];
  float rstd = rsqrtf(tot2 * (1.0f / D) + 1e-5f);
  stf(out + row * D + t, d * rstd);
}

// ---------- LayerNorm D=128, one row per WAVE ----------
template<typename InT, typename OutT>
__global__ __launch_bounds__(256) void ln128w_kernel(const InT* __restrict__ in,
                                                     OutT* __restrict__ out) {
  size_t row = (size_t)blockIdx.x * 4 + (threadIdx.x >> 6);
  int l = threadIdx.x & 63;
  const InT* p = in + row * 128 + l * 2;
  float v0 = ldf(p), v1 = ldf(p + 1);
  float mean = waveSum(v0 + v1) * (1.f / 128.f);
  float d0 = v0 - mean, d1 = v1 - mean;
  float rstd = rsqrtf(waveSum(d0 * d0 + d1 * d1) * (1.f / 128.f) + 1e-5f);
  OutT* q = out + row * 128 + l * 2;
  stf(q, d0 * rstd);
  stf(q + 1, d1 * rstd);
}

// ---------- broadcast init ----------
__global__ void bcast_kernel(const float* __restrict__ s, float* __restrict__ d,
                             unsigned mask, size_t total) {
  size_t i = (size_t)blockIdx.x * blockDim.x + threadIdx.x;
  if (i < total) d[i] = s[i & mask];
}

// ---------- weight transpose+convert: out[n][k] = bf16(in[k][n]); separate z-strides ----------
__global__ __launch_bounds__(256) void twcvt_kernel(const float* __restrict__ in,
                                                    bf16* __restrict__ out, int K, int N,
                                                    int inZ, int outZ) {
  const float* inp = in + (size_t)blockIdx.z * inZ;
  bf16* outp = out + (size_t)blockIdx.z * outZ;
  __shared__ float tile[32][33];
  int tx = threadIdx.x & 31, ty = threadIdx.x >> 5;
  int k0 = blockIdx.y * 32, n0 = blockIdx.x * 32;
#pragma unroll
  for (int it = 0; it < 4; it++)
    tile[ty + it * 8][tx] = inp[(size_t)(k0 + ty + it * 8) * N + n0 + tx];
  __syncthreads();
#pragma unroll
  for (int it = 0; it < 4; it++)
    outp[(size_t)(n0 + ty + it * 8) * K + k0 + tx] = __float2bfloat16(tile[tx][ty + it * 8]);
}

// ---------- MFMA tile staging with XOR swizzle ----------
template<int ROWS>
__device__ __forceinline__ void stageTile(const bf16* __restrict__ g, int srcLd,
                                          char* lds, int t) {
  constexpr int IT = ROWS * 16 / 256;
#pragma unroll
  for (int it = 0; it < IT; it++) {
    int u = t + it * 256;
    int row = u >> 4, c16 = u & 15;
    uint4 val = *(const uint4*)(g + (size_t)row * srcLd + c16 * 8);
    *(uint4*)(lds + row * 256 + ((c16 ^ (row & 7)) << 4)) = val;
  }
}
__device__ __forceinline__ s8v readFrag(const char* lds, int row, int c16) {
  return *(const s8v*)(lds + row * 256 + ((c16 ^ (row & 7)) << 4));
}

// ---------- generic node MFMA GEMM: C[M x N] = A[M x KTOT] @ Wt^T ----------
// grid (M/256, N/128). EPI 0: f32 store; EPI 1: relu -> bf16 store.
template<int KTOT, int EPI>
__global__ __launch_bounds__(256) void ngemm_kernel(
    const bf16* __restrict__ A, const bf16* __restrict__ Wt, void* __restrict__ outv, int N) {
  __shared__ char Ash[65536];
  __shared__ char Wsh[32768];
  int t = threadIdx.x, l = t & 63, w = t >> 6;
  size_t r0 = (size_t)blockIdx.x * 256;
  int c0 = blockIdx.y * 128;
  int rb = w * 64;
  f4v acc[4][8];
#pragma unroll
  for (int rf = 0; rf < 4; rf++)
#pragma unroll
    for (int cf = 0; cf < 8; cf++) acc[rf][cf] = (f4v){0.f, 0.f, 0.f, 0.f};
#pragma unroll
  for (int kb = 0; kb < KTOT; kb += 128) {
    if (kb) __syncthreads();
    stageTile<256>(A + r0 * KTOT + kb, KTOT, Ash, t);
    stageTile<128>(Wt + (size_t)c0 * KTOT + kb, KTOT, Wsh, t);
    __syncthreads();
#pragma unroll
    for (int kc = 0; kc < 4; kc++) {
      int c16 = kc * 4 + (l >> 4);
      s8v af[4];
#pragma unroll
      for (int rf = 0; rf < 4; rf++) af[rf] = readFrag(Ash, rb + rf * 16 + (l & 15), c16);
#pragma unroll
      for (int cf = 0; cf < 8; cf++) {
        s8v b0 = readFrag(Wsh, cf * 16 + (l & 15), c16);
#pragma unroll
        for (int rf = 0; rf < 4; rf++) acc[rf][cf] = MFMA16(af[rf], b0, acc[rf][cf]);
      }
    }
  }
#pragma unroll
  for (int rf = 0; rf < 4; rf++)
#pragma unroll
    for (int cf = 0; cf < 8; cf++)
#pragma unroll
      for (int i = 0; i < 4; i++) {
        size_t row = r0 + rb + rf * 16 + ((l >> 4) << 2) + i;
        int col = c0 + cf * 16 + (l & 15);
        if (EPI == 0) ((float*)outv)[row * N + col] = acc[rf][cf][i];
        else ((bf16*)outv)[row * N + col] = __float2bfloat16(fmaxf(acc[rf][cf][i], 0.f));
      }
}

// ---------- node residual+LN: X[128rows x 256] += A@Wt; Xnb = ln(X) fused ----------
template<int KTOT>
__global__ __launch_bounds__(256) void mfma_addx_ln_kernel(
    const bf16* __restrict__ A, const bf16* __restrict__ Wt,
    float* __restrict__ X, bf16* __restrict__ Xnb) {
  __shared__ char Ash[32768];
  __shared__ char Wsh[65536];
  int t = threadIdx.x, l = t & 63, w = t >> 6;
  size_t r0 = (size_t)blockIdx.x * 128;
  int rb = w * 32;
  f4v acc[2][16];
#pragma unroll
  for (int rf = 0; rf < 2; rf++)
#pragma unroll
    for (int cf = 0; cf < 16; cf++) acc[rf][cf] = (f4v){0.f, 0.f, 0.f, 0.f};
#pragma unroll
  for (int kb = 0; kb < KTOT; kb += 128) {
    if (kb) __syncthreads();
    stageTile<128>(A + r0 * KTOT + kb, KTOT, Ash, t);
    stageTile<256>(Wt + kb, KTOT, Wsh, t);
    __syncthreads();
#pragma unroll
    for (int kc = 0; kc < 4; kc++) {
      int c16 = kc * 4 + (l >> 4);
      s8v af[2];
#pragma unroll
      for (int rf = 0; rf < 2; rf++) af[rf] = readFrag(Ash, rb + rf * 16 + (l & 15), c16);
#pragma unroll
      for (int cf = 0; cf < 16; cf++) {
        s8v b0 = readFrag(Wsh, cf * 16 + (l & 15), c16);
#pragma unroll
        for (int rf = 0; rf < 2; rf++) acc[rf][cf] = MFMA16(af[rf], b0, acc[rf][cf]);
      }
    }
  }
  // residual add (in place into acc) then row-LN over 256 (16 lanes x 16 cf)
#pragma unroll
  for (int rf = 0; rf < 2; rf++)
#pragma unroll
    for (int cf = 0; cf < 16; cf++)
#pragma unroll
      for (int i = 0; i < 4; i++) {
        size_t row = r0 + rb + rf * 16 + ((l >> 4) << 2) + i;
        size_t o = row * 256 + cf * 16 + (l & 15);
        float e = X[o] + acc[rf][cf][i];
        X[o] = e; acc[rf][cf][i] = e;
      }
#pragma unroll
  for (int rf = 0; rf < 2; rf++)
#pragma unroll
    for (int i = 0; i < 4; i++) {
      float s = 0.f, s2 = 0.f;
#pragma unroll
      for (int cf = 0; cf < 16; cf++) { float x = acc[rf][cf][i]; s += x; s2 += x * x; }
#pragma unroll
      for (int m = 1; m < 16; m <<= 1) { s += __shfl_xor(s, m); s2 += __shfl_xor(s2, m); }
      float mean = s * 0.00390625f;
      float rstd = rsqrtf(s2 * 0.00390625f - mean * mean + 1e-5f);
      size_t row = r0 + rb + rf * 16 + ((l >> 4) << 2) + i;
#pragma unroll
      for (int cf = 0; cf < 16; cf++)
        Xnb[row * 256 + cf * 16 + (l & 15)] =
            __float2bfloat16((acc[rf][cf][i] - mean) * rstd);
    }
}

// ---------- MFMA GEMM edge, 256 rows x 128 cols, two weight mats, K=128 ----------
template<int EPI>
__global__ __launch_bounds__(256, 1) void mfma_nw2_kernel(
    const bf16* __restrict__ A, const bf16* __restrict__ W0t, const bf16* __restrict__ W1t,
    bf16* __restrict__ out) {
  __shared__ char lds[131072];
  char* Ash = lds; char* W0sh = lds + 65536; char* W1sh = lds + 98304;
  int t = threadIdx.x, l = t & 63, w = t >> 6;
  size_t r0 = (size_t)blockIdx.x * 256;
  int rb = w * 64;
  stageTile<256>(A + r0 * 128, 128, Ash, t);
  stageTile<128>(W0t, 128, W0sh, t);
  stageTile<128>(W1t, 128, W1sh, t);
  __syncthreads();
  f4v acc0[4][8], acc1[4][8];
#pragma unroll
  for (int rf = 0; rf < 4; rf++)
#pragma unroll
    for (int cf = 0; cf < 8; cf++) {
      acc0[rf][cf] = (f4v){0.f, 0.f, 0.f, 0.f};
      acc1[rf][cf] = (f4v){0.f, 0.f, 0.f, 0.f};
    }
#pragma unroll
  for (int kc = 0; kc < 4; kc++) {
    int c16 = kc * 4 + (l >> 4);
    s8v af[4];
#pragma unroll
    for (int rf = 0; rf < 4; rf++) af[rf] = readFrag(Ash, rb + rf * 16 + (l & 15), c16);
#pragma unroll
    for (int cf = 0; cf < 8; cf++) {
      s8v b0 = readFrag(W0sh, cf * 16 + (l & 15), c16);
      s8v b1 = readFrag(W1sh, cf * 16 + (l & 15), c16);
#pragma unroll
      for (int rf = 0; rf < 4; rf++) {
        acc0[rf][cf] = MFMA16(af[rf], b0, acc0[rf][cf]);
        acc1[rf][cf] = MFMA16(af[rf], b1, acc1[rf][cf]);
      }
    }
  }
  if (EPI == 1) {
#pragma unroll
    for (int rf = 0; rf < 4; rf++)
#pragma unroll
      for (int cf = 0; cf < 8; cf++)
#pragma unroll
        for (int i = 0; i < 4; i++) {
          size_t row = r0 + rb + rf * 16 + ((l >> 4) << 2) + i;
          int col = cf * 16 + (l & 15);
          out[row * 256 + col]       = __float2bfloat16(fmaxf(acc0[rf][cf][i], 0.f));
          out[row * 256 + 128 + col] = __float2bfloat16(fmaxf(acc1[rf][cf][i], 0.f));
        }
  } else {
    __syncthreads();
    char* tb = lds;
#pragma unroll
    for (int rf = 0; rf < 4; rf++)
#pragma unroll
      for (int cf = 0; cf < 8; cf++) {
        int c = cf * 16 + (l & 15);
        int u0 = rb + rf * 16 + ((l >> 4) << 2);
        uint2 pv;
        pv.x = (unsigned)f2bu(acc1[rf][cf][0] / (1.f + __expf(-acc0[rf][cf][0]))) |
               ((unsigned)f2bu(acc1[rf][cf][1] / (1.f + __expf(-acc0[rf][cf][1]))) << 16);
        pv.y = (unsigned)f2bu(acc1[rf][cf][2] / (1.f + __expf(-acc0[rf][cf][2]))) |
               ((unsigned)f2bu(acc1[rf][cf][3] / (1.f + __expf(-acc0[rf][cf][3]))) << 16);
        *(uint2*)(tb + c * 560 + u0 * 2) = pv;
      }
    __syncthreads();
    int b_ = (int)(r0 >> 14); int ik0 = (int)(r0 & 16383);
    bf16* op = out + (size_t)b_ * 2097152 + ik0;
    int c2 = t >> 1, hf = t & 1;
#pragma unroll
    for (int q = 0; q < 16; q++) {
      int u = hf * 128 + q * 8;
      *(uint4*)(op + (size_t)c2 * 16384 + u) = *(const uint4*)(tb + c2 * 560 + u * 2);
    }
  }
}

// ---------- G = sigmoid(En @ Wt) ----------
__global__ __launch_bounds__(256) void mfma_sig_kernel(
    const bf16* __restrict__ A, const bf16* __restrict__ Wt, bf16* __restrict__ out) {
  __shared__ char lds[65536];
  char* Ash = lds; char* Wsh = lds + 32768;
  int t = threadIdx.x, l = t & 63, w = t >> 6;
  size_t r0 = (size_t)blockIdx.x * 128;
  int rb = w * 32;
  stageTile<128>(A + r0 * 128, 128, Ash, t);
  stageTile<128>(Wt, 128, Wsh, t);
  __syncthreads();
  f4v acc[2][8];
#pragma unroll
  for (int rf = 0; rf < 2; rf++)
#pragma unroll
    for (int cf = 0; cf < 8; cf++) acc[rf][cf] = (f4v){0.f, 0.f, 0.f, 0.f};
#pragma unroll
  for (int kc = 0; kc < 4; kc++) {
    int c16 = kc * 4 + (l >> 4);
    s8v af[2];
#pragma unroll
    for (int rf = 0; rf < 2; rf++) af[rf] = readFrag(Ash, rb + rf * 16 + (l & 15), c16);
#pragma unroll
    for (int cf = 0; cf < 8; cf++) {
      s8v b0 = readFrag(Wsh, cf * 16 + (l & 15), c16);
#pragma unroll
      for (int rf = 0; rf < 2; rf++) acc[rf][cf] = MFMA16(af[rf], b0, acc[rf][cf]);
    }
  }
#pragma unroll
  for (int rf = 0; rf < 2; rf++)
#pragma unroll
    for (int cf = 0; cf < 8; cf++)
#pragma unroll
      for (int i = 0; i < 4; i++) {
        size_t row = r0 + rb + rf * 16 + ((l >> 4) << 2) + i;
        int col = cf * 16 + (l & 15);
        out[row * 128 + col] = __float2bfloat16(1.f / (1.f + __expf(-acc[rf][cf][i])));
      }
}

// ---------- E += G * (Tn@Wt); En = LN(E) fused ----------
__global__ __launch_bounds__(256) void mfma_gmul_add_ln_kernel(
    const bf16* __restrict__ A, const bf16* __restrict__ Wt, const bf16* __restrict__ G,
    float* __restrict__ E, bf16* __restrict__ En) {
  __shared__ char lds[65536];
  char* Ash = lds; char* Wsh = lds + 32768;
  int t = threadIdx.x, l = t & 63, w = t >> 6;
  size_t r0 = (size_t)blockIdx.x * 128;
  int rb = w * 32;
  stageTile<128>(A + r0 * 128, 128, Ash, t);
  stageTile<128>(Wt, 128, Wsh, t);
  __syncthreads();
  f4v acc[2][8];
#pragma unroll
  for (int rf = 0; rf < 2; rf++)
#pragma unroll
    for (int cf = 0; cf < 8; cf++) acc[rf][cf] = (f4v){0.f, 0.f, 0.f, 0.f};
#pragma unroll
  for (int kc = 0; kc < 4; kc++) {
    int c16 = kc * 4 + (l >> 4);
    s8v af[2];
#pragma unroll
    for (int rf = 0; rf < 2; rf++) af[rf] = readFrag(Ash, rb + rf * 16 + (l & 15), c16);
#pragma unroll
    for (int cf = 0; cf < 8; cf++) {
      s8v b0 = readFrag(Wsh, cf * 16 + (l & 15), c16);
#pragma unroll
      for (int rf = 0; rf < 2; rf++) acc[rf][cf] = MFMA16(af[rf], b0, acc[rf][cf]);
    }
  }
  float vv[2][8][4];
#pragma unroll
  for (int rf = 0; rf < 2; rf++)
#pragma unroll
    for (int cf = 0; cf < 8; cf++)
#pragma unroll
      for (int i = 0; i < 4; i++) {
        size_t row = r0 + rb + rf * 16 + ((l >> 4) << 2) + i;
        size_t o = row * 128 + cf * 16 + (l & 15);
        float e = E[o] + __bfloat162float(G[o]) * acc[rf][cf][i];
        E[o] = e; vv[rf][cf][i] = e;
      }
#pragma unroll
  for (int rf = 0; rf < 2; rf++)
#pragma unroll
    for (int i = 0; i < 4; i++) {
      float s = 0.f, s2 = 0.f;
#pragma unroll
      for (int cf = 0; cf < 8; cf++) { float x = vv[rf][cf][i]; s += x; s2 += x * x; }
#pragma unroll
      for (int m = 1; m < 16; m <<= 1) { s += __shfl_xor(s, m); s2 += __shfl_xor(s2, m); }
      float mean = s * 0.0078125f;
      float rstd = rsqrtf(s2 * 0.0078125f - mean * mean + 1e-5f);
      size_t row = r0 + rb + rf * 16 + ((l >> 4) << 2) + i;
#pragma unroll
      for (int cf = 0; cf < 8; cf++)
        En[row * 128 + cf * 16 + (l & 15)] = __float2bfloat16((vv[rf][cf][i] - mean) * rstd);
    }
}

// ---------- E += H @ Wt (K=256); En = LN(E) fused ----------
__global__ __launch_bounds__(256) void mfma_add_ln_kernel(
    const bf16* __restrict__ A, const bf16* __restrict__ Wt,
    float* __restrict__ E, bf16* __restrict__ En) {
  __shared__ char lds[65536];
  char* Ash = lds; char* Wsh = lds + 32768;
  int t = threadIdx.x, l = t & 63, w = t >> 6;
  size_t r0 = (size_t)blockIdx.x * 128;
  int rb = w * 32;
  f4v acc[2][8];
#pragma unroll
  for (int rf = 0; rf < 2; rf++)
#pragma unroll
    for (int cf = 0; cf < 8; cf++) acc[rf][cf] = (f4v){0.f, 0.f, 0.f, 0.f};
#pragma unroll
  for (int kb = 0; kb < 2; kb++) {
    if (kb) __syncthreads();
    stageTile<128>(A + r0 * 256 + kb * 128, 256, Ash, t);
    stageTile<128>(Wt + kb * 128, 256, Wsh, t);
    __syncthreads();
#pragma unroll
    for (int kc = 0; kc < 4; kc++) {
      int c16 = kc * 4 + (l >> 4);
      s8v af[2];
#pragma unroll
      for (int rf = 0; rf < 2; rf++) af[rf] = readFrag(Ash, rb + rf * 16 + (l & 15), c16);
#pragma unroll
      for (int cf = 0; cf < 8; cf++) {
        s8v b0 = readFrag(Wsh, cf * 16 + (l & 15), c16);
#pragma unroll
        for (int rf = 0; rf < 2; rf++) acc[rf][cf] = MFMA16(af[rf], b0, acc[rf][cf]);
      }
    }
  }
  float vv[2][8][4];
#pragma unroll
  for (int rf = 0; rf < 2; rf++)
#pragma unroll
    for (int cf = 0; cf < 8; cf++)
#pragma unroll
      for (int i = 0; i < 4; i++) {
        size_t row = r0 + rb + rf * 16 + ((l >> 4) << 2) + i;
        size_t o = row * 128 + cf * 16 + (l & 15);
        float e = E[o] + acc[rf][cf][i];
        E[o] = e; vv[rf][cf][i] = e;
      }
#pragma unroll
  for (int rf = 0; rf < 2; rf++)
#pragma unroll
    for (int i = 0; i < 4; i++) {
      float s = 0.f, s2 = 0.f;
#pragma unroll
      for (int cf = 0; cf < 8; cf++) { float x = vv[rf][cf][i]; s += x; s2 += x * x; }
#pragma unroll
      for (int m = 1; m < 16; m <<= 1) { s += __shfl_xor(s, m); s2 += __shfl_xor(s2, m); }
      float mean = s * 0.0078125f;
      float rstd = rsqrtf(s2 * 0.0078125f - mean * mean + 1e-5f);
      size_t row = r0 + rb + rf * 16 + ((l >> 4) << 2) + i;
#pragma unroll
      for (int cf = 0; cf < 8; cf++)
        En[row * 128 + cf * 16 + (l & 15)] = __float2bfloat16((vv[rf][cf][i] - mean) * rstd);
    }
}

// ---------- triangle via MFMA: one block per (b,c) ----------
__global__ __launch_bounds__(256, 1) void tri_mfma_kernel(
    const bf16* __restrict__ aT, const bf16* __restrict__ bT, bf16* __restrict__ Tcm) {
  __shared__ char lds[131072];
  char* P1 = lds; char* Q1 = lds + 32768; char* P2 = lds + 65536; char* Q2 = lds + 98304;
  int t = threadIdx.x, l = t & 63, w = t >> 6;
  int bc = blockIdx.x;
  stageTile<128>(aT + (size_t)bc * 16384, 128, P1, t);
  stageTile<128>(bT + (size_t)bc * 16384, 128, Q1, t);
  __syncthreads();
#pragma unroll 8
  for (int it = 0; it < 64; it++) {
    int tile_ = w * 64 + it;
    int k0 = (tile_ & 15) * 8, r0 = (tile_ >> 4) * 8;
    int k = k0 + (l & 7), r = r0 + (l >> 3);
    int ra = r * 256 + ((((k >> 3) ^ (r & 7)) << 4)) + (k & 7) * 2;
    int wa = k * 256 + ((((r >> 3) ^ (k & 7)) << 4)) + (r & 7) * 2;
    *(unsigned short*)(P2 + wa) = *(const unsigned short*)(P1 + ra);
    *(unsigned short*)(Q2 + wa) = *(const unsigned short*)(Q1 + ra);
  }
  __syncthreads();
  int rb = w * 32;
  f4v acc1[2][8], acc2[2][8];
#pragma unroll
  for (int rf = 0; rf < 2; rf++)
#pragma unroll
    for (int cf = 0; cf < 8; cf++) {
      acc1[rf][cf] = (f4v){0.f, 0.f, 0.f, 0.f};
      acc2[rf][cf] = (f4v){0.f, 0.f, 0.f, 0.f};
    }
#pragma unroll
  for (int kc = 0; kc < 4; kc++) {
    int c16 = kc * 4 + (l >> 4);
    s8v a1[2], a2[2];
#pragma unroll
    for (int rf = 0; rf < 2; rf++) {
      a1[rf] = readFrag(P1, rb + rf * 16 + (l & 15), c16);
      a2[rf] = readFrag(P2, rb + rf * 16 + (l & 15), c16);
    }
#pragma unroll
    for (int cf = 0; cf < 8; cf++) {
      s8v b1 = readFrag(Q1, cf * 16 + (l & 15), c16);
      s8v b2 = readFrag(Q2, cf * 16 + (l & 15), c16);
#pragma unroll
      for (int rf = 0; rf < 2; rf++) {
        acc1[rf][cf] = MFMA16(a1[rf], b1, acc1[rf][cf]);
        acc2[rf][cf] = MFMA16(a2[rf], b2, acc2[rf][cf]);
      }
    }
  }
  __syncthreads();
  char* tb = lds;
#pragma unroll
  for (int rf = 0; rf < 2; rf++)
#pragma unroll
    for (int cf = 0; cf < 8; cf++) {
      int j = cf * 16 + (l & 15);
      int i0 = rb + rf * 16 + ((l >> 4) << 2);
      uint2 pv;
      pv.x = (unsigned)f2bu(0.5f * (acc1[rf][cf][0] + acc2[rf][cf][0])) |
             ((unsigned)f2bu(0.5f * (acc1[rf][cf][1] + acc2[rf][cf][1])) << 16);
      pv.y = (unsigned)f2bu(0.5f * (acc1[rf][cf][2] + acc2[rf][cf][2])) |
             ((unsigned)f2bu(0.5f * (acc1[rf][cf][3] + acc2[rf][cf][3])) << 16);
      *(uint2*)(tb + j * 560 + i0 * 2) = pv;
    }
  __syncthreads();
  bf16* op = Tcm + (size_t)bc * 16384;
#pragma unroll
  for (int q = 0; q < 8; q++) {
    int ci = q * 256 + t;
    *(uint4*)(op + ci * 8) = *(const uint4*)(tb + (ci >> 4) * 560 + (ci & 15) * 16);
  }
}

// ---------- permute + LN: Tcm[b][c][j][i] -> Tn[(b,i,j)][c] with LN over c ----------
__global__ __launch_bounds__(256) void permln_kernel(const bf16* __restrict__ Tcm,
                                                     bf16* __restrict__ Tn) {
  __shared__ float tile[128][77];
  __shared__ float ps[4][64], ps2[4][64], mst[64], rst[64];
  int b = blockIdx.z, j = blockIdx.y, i0 = blockIdx.x * 64;
  int t = threadIdx.x;
  const bf16* src = Tcm + (size_t)b * 2097152 + j * 128 + i0;
#pragma unroll
  for (int q = 0; q < 4; q++) {
    int ci = q * 256 + t; int c = ci >> 3, ch = ci & 7;
    uint4 v = *(const uint4*)(src + (size_t)c * 16384 + ch * 8);
    const unsigned short* u = (const unsigned short*)&v;
#pragma unroll
    for (int e = 0; e < 8; e++) tile[c][ch * 8 + e] = b2f(u[e]);
  }
  __syncthreads();
  {
    int i_ = t & 63, part = t >> 6;
    float s = 0.f, s2 = 0.f;
    for (int c = part * 32; c < part * 32 + 32; c++) { float x = tile[c][i_]; s += x; s2 += x * x; }
    ps[part][i_] = s; ps2[part][i_] = s2;
  }
  __syncthreads();
  if (t < 64) {
    float s = ps[0][t] + ps[1][t] + ps[2][t] + ps[3][t];
    float q2 = ps2[0][t] + ps2[1][t] + ps2[2][t] + ps2[3][t];
    float mean = s * 0.0078125f;
    float var = q2 * 0.0078125f - mean * mean;
    mst[t] = mean; rst[t] = rsqrtf(var + 1e-5f);
  }
  __syncthreads();
  {
    int i2 = t & 63, c0 = (t >> 6) * 32;
    float mean = mst[i2], rstd = rst[i2];
    bf16* dst = Tn + ((size_t)b * 16384 + (size_t)(i0 + i2) * 128 + j) * 128 + c0;
#pragma unroll
    for (int qq = 0; qq < 4; qq++) {
      unsigned short pk[8];
#pragma unroll
      for (int e = 0; e < 8; e++)
        pk[e] = f2bu((tile[c0 + qq * 8 + e][i2] - mean) * rstd);
      *(uint4*)(dst + qq * 8) = *(uint4*)pk;
    }
  }
}

// ---------- E += outer(xi,xj) [packed xixj ld=256]; En = LN(E) fused ----------
__global__ __launch_bounds__(256) void outer_ln_kernel(float* __restrict__ E,
    const float* __restrict__ xixj, bf16* __restrict__ En) {
  __shared__ float sb[8];
  size_t r = (size_t)blockIdx.x * 2 + (threadIdx.x >> 7);
  int t = threadIdx.x & 127;
  int b = (int)(r >> 14), i = (int)((r >> 7) & 127), j = (int)(r & 127);
  size_t o = r * 128 + t;
  float e = E[o] + xixj[(size_t)(b * 128 + i) * 256 + t]
                 + xixj[(size_t)(b * 128 + j) * 256 + 128 + t];
  E[o] = e;
  int wg = threadIdx.x >> 6, rh = threadIdx.x >> 7;
  float s = waveSum(e);
  if ((threadIdx.x & 63) == 0) sb[wg] = s;
  __syncthreads();
  float mean = (sb[rh * 2] + sb[rh * 2 + 1]) * (1.f / 128.f);
  float d = e - mean;
  float s2 = waveSum(d * d);
  if ((threadIdx.x & 63) == 0) sb[4 + wg] = s2;
  __syncthreads();
  float rstd = rsqrtf((sb[4 + rh * 2] + sb[4 + rh * 2 + 1]) * (1.f / 128.f) + 1e-5f);
  En[o] = __float2bfloat16(d * rstd);
}

// ---------- 8-col head: out[r,h] = sum_k A[r,k]*W[k,h]; BIAS scatter / A-dot ----------
template<int K, int BIAS, int WITHA>
__global__ __launch_bounds__(256) void head8_kernel(const bf16* __restrict__ A,
    const float* __restrict__ W, float* __restrict__ out,
    const float* __restrict__ aW, float* __restrict__ outA) {
  __shared__ __align__(16) bf16 As[32 * K];
  __shared__ float Ws[K * 8];
  __shared__ float aWs[128];
  size_t r0 = (size_t)blockIdx.x * 32;
  int t = threadIdx.x;
  constexpr int NCH = 32 * K / 8;
#pragma unroll
  for (int it = 0; it < NCH / 256; it++)
    ((uint4*)As)[t + it * 256] = ((const uint4*)(A + r0 * K))[t + it * 256];
  for (int u = t; u < K * 8; u += 256) Ws[u] = W[u];
  if (WITHA) { if (t < 128) aWs[t] = aW[t]; }
  __syncthreads();
  int rr = t >> 3, h = t & 7;
  float acc = 0.f;
#pragma unroll 4
  for (int k = 0; k < K; k++) acc += __bfloat162float(As[rr * K + k]) * Ws[k * 8 + h];
  size_t r = r0 + rr;
  if (BIAS) {
    size_t b = r >> 14, ij = r & 16383;
    out[((b * 8 + h) << 14) + ij] = acc;
  } else {
    out[r * 8 + h] = acc;
  }
  if (WITHA) {
    if (t < 32) {
      float a2 = 0.f;
#pragma unroll 4
      for (int k = 0; k < K; k++) a2 += __bfloat162float(As[t * K + k]) * aWs[k];
      outA[r0 + t] = a2;
    }
  }
}

// ---------- generic narrow head: out[r,h] = sum_k A[r,k]*W[k,h], N cols ----------
template<int K, int N>
__global__ __launch_bounds__(256) void headN_kernel(const bf16* __restrict__ A,
    const float* __restrict__ W, float* __restrict__ out) {
  constexpr int R = 256 / N;
  __shared__ __align__(16) bf16 As[R * K];
  __shared__ float Ws[K * N];
  size_t r0 = (size_t)blockIdx.x * R;
  int t = threadIdx.x;
  constexpr int NCH = R * K / 8;
#pragma unroll
  for (int it = 0; it < NCH / 256; it++)
    ((uint4*)As)[t + it * 256] = ((const uint4*)(A + r0 * K))[t + it * 256];
  for (int u = t; u < K * N; u += 256) Ws[u] = W[u];
  __syncthreads();
  int rr = t / N, h = t % N;
  float acc = 0.f;
#pragma unroll 4
  for (int k = 0; k < K; k++) acc += __bfloat162float(As[rr * K + k]) * Ws[k * N + h];
  out[(r0 + rr) * N + h] = acc;
}

// ---------- cross attention: q ld256 f32, kv packed ld512, out bf16 ----------
__global__ __launch_bounds__(256) void cross_attn_kernel(const float* __restrict__ q,
    const float* __restrict__ kv, bf16* __restrict__ o) {
  __shared__ float sc[Hc][Kc];
  int bm = blockIdx.x; int b = bm >> 7;
  int t = threadIdx.x; int h = t >> 5; int d = t & 31;
  float qv = q[(size_t)bm * 256 + h * 32 + d] * INV_SQRT_DH;
  for (int k0 = 0; k0 < Kc; k0++) {
    float kvv = kv[((size_t)(b * Kc + k0)) * 512 + h * 32 + d];
    float p = grpSum32(qv * kvv);
    if (d == 0) sc[h][k0] = p;
  }
  __syncthreads();
  float s0 = sc[h][d], s1 = sc[h][d + 32];
  float mx = grpMax32(fmaxf(s0, s1));
  float e0 = __expf(s0 - mx), e1 = __expf(s1 - mx);
  float sm = grpSum32(e0 + e1);
  float rs = 1.f / sm;
  sc[h][d] = e0 * rs; sc[h][d + 32] = e1 * rs;
  __syncthreads();
  float acc = 0.f;
  for (int k0 = 0; k0 < Kc; k0++)
    acc += sc[h][k0] * kv[((size_t)(b * Kc + k0)) * 512 + 256 + h * 32 + d];
  o[(size_t)bm * 256 + h * 32 + d] = __float2bfloat16(acc);
}

// ---------- pair-biased self attention: qkv packed ld768 f32, out bf16 ----------
__global__ __launch_bounds__(256) void self_attn_kernel(const float* __restrict__ qkv,
    const float* __restrict__ bias, bf16* __restrict__ o) {
  __shared__ float sc[Hc][Mc];
  int bm = blockIdx.x; int b = bm >> 7, i = bm & 127;
  int t = threadIdx.x; int h = t >> 5, d = t & 31;
  float qv = qkv[(size_t)bm * 768 + h * 32 + d] * INV_SQRT_DH;
  const float* bs = bias + (((size_t)b * Hc + h) * Mc + i) * Mc;
  for (int j = 0; j < Mc; j++) {
    float kvv = qkv[((size_t)(b * Mc + j)) * 768 + 256 + h * 32 + d];
    float p = grpSum32(qv * kvv);
    if (d == 0) sc[h][j] = p + bs[j];
  }
  __syncthreads();
  float sv[4]; float mx = -1e30f;
#pragma unroll
  for (int u = 0; u < 4; u++) { sv[u] = sc[h][d + 32 * u]; mx = fmaxf(mx, sv[u]); }
  mx = grpMax32(mx);
  float sm = 0.f;
#pragma unroll
  for (int u = 0; u < 4; u++) { sv[u] = __expf(sv[u] - mx); sm += sv[u]; }
  sm = grpSum32(sm);
  float rs = 1.f / sm;
#pragma unroll
  for (int u = 0; u < 4; u++) sc[h][d + 32 * u] = sv[u] * rs;
  __syncthreads();
  float acc = 0.f;
  for (int j = 0; j < Mc; j++)
    acc += sc[h][j] * qkv[((size_t)(b * Mc + j)) * 768 + 512 + h * 32 + d];
  o[(size_t)bm * 256 + h * 32 + d] = __float2bfloat16(acc);
}

// ---------- row dot ----------
template<int D, typename InT>
__global__ __launch_bounds__(D) void rowdot_kernel(const InT* __restrict__ A,
    const float* __restrict__ w, float* __restrict__ out) {
  __shared__ float sb[D / 64];
  size_t r = blockIdx.x; int t = threadIdx.x;
  float v = ldf(A + r * D + t) * w[t];
  v = waveSum(v);
  if ((t & 63) == 0) sb[t >> 6] = v;
  __syncthreads();
  if (t == 0) { float s = 0.f; for (int i = 0; i < D / 64; i++) s += sb[i]; out[r] = s; }
}

extern "C" void kernel_launch(void* const* d_in, const int* in_sizes, int n_in,
                              void* d_out, int out_size, void* d_ws, size_t ws_size,
                              hipStream_t stream) {
  const float* graph = (const float*)d_in[0];
  const float* Xq  = (const float*)d_in[1];
  const float* Eq  = (const float*)d_in[2];
  const float* Wq  = (const float*)d_in[3];
  const float* Wk  = (const float*)d_in[4];
  const float* Wv  = (const float*)d_in[5];
  const float* Wo  = (const float*)d_in[6];
  const float* Sq  = (const float*)d_in[7];
  const float* Sk  = (const float*)d_in[8];
  const float* Sv  = (const float*)d_in[9];
  const float* So  = (const float*)d_in[10];
  const float* Wb  = (const float*)d_in[11];
  const float* Wn1 = (const float*)d_in[12];
  const float* Wn2 = (const float*)d_in[13];
  const float* Woi = (const float*)d_in[14];
  const float* Woj = (const float*)d_in[15];
  const float* Wa  = (const float*)d_in[16];
  const float* Wga = (const float*)d_in[17];
  const float* Wb2 = (const float*)d_in[18];
  const float* Wgb = (const float*)d_in[19];
  const float* Wp  = (const float*)d_in[20];
  const float* Wgp = (const float*)d_in[21];
  const float* We1 = (const float*)d_in[22];
  const float* We2 = (const float*)d_in[23];
  const float* hW  = (const float*)d_in[24];
  const float* neW1 = (const float*)d_in[25];
  const float* neW2 = (const float*)d_in[26];
  const float* nlW  = (const float*)d_in[27];
  const float* nfW1 = (const float*)d_in[28];
  const float* nfW2 = (const float*)d_in[29];
  const float* aW   = (const float*)d_in[30];
  const float* elW  = (const float*)d_in[31];
  const float* efW1 = (const float*)d_in[32];
  const float* efW2 = (const float*)d_in[33];

  char* wsb = (char*)d_ws;
  size_t off = 0;
  auto alloc = [&](size_t bytes) -> char* {
    char* p = wsb + off; off += (bytes + 255) & ~(size_t)255; return p;
  };
  float* X    = (float*)alloc((size_t)262144 * 4);
  bf16*  Xnb  = (bf16*)alloc((size_t)262144 * 2);
  bf16*  srcb = (bf16*)alloc((size_t)131072 * 2);
  float* qf   = (float*)alloc((size_t)262144 * 4);
  float* kvf  = (float*)alloc((size_t)262144 * 4);
  float* qkvf = (float*)alloc((size_t)786432 * 4);
  bf16*  obB  = (bf16*)alloc((size_t)262144 * 2);
  bf16*  H1   = (bf16*)alloc((size_t)524288 * 2);
  float* xixj = (float*)alloc((size_t)262144 * 4);
  float* bias = (float*)alloc((size_t)1048576 * 4);
  float* E   = (float*)alloc((size_t)16777216 * 4);
  bf16* En   = (bf16*)alloc((size_t)16777216 * 2);
  bf16* aT1  = (bf16*)alloc((size_t)16777216 * 2);   // [b][c][i][k]
  bf16* bT1  = (bf16*)alloc((size_t)16777216 * 2);   // [b][c][j][k]
  bf16* Tcm  = (bf16*)alloc((size_t)16777216 * 2);   // [b][c][j][i]
  bf16* G    = (bf16*)alloc((size_t)16777216 * 2);   // sigmoid(En@Wgp)
  bf16* Tn   = aT1;      // alias: aT1 dead after tri
  bf16* H    = aT1;      // alias: spans aT1+bT1 (contiguous)
  // transposed bf16 edge weights
  bf16* WgaT = (bf16*)alloc((size_t)65536 * 2);
  bf16* WaT  = (bf16*)alloc((size_t)65536 * 2);
  bf16* WgbT = (bf16*)alloc((size_t)65536 * 2);
  bf16* Wb2T = (bf16*)alloc((size_t)65536 * 2);
  bf16* WgpT = (bf16*)alloc((size_t)65536 * 2);
  bf16* WpT  = (bf16*)alloc((size_t)65536 * 2);
  bf16* We1T = (bf16*)alloc((size_t)131072 * 2);
  bf16* We2T = (bf16*)alloc((size_t)131072 * 2);
  bf16* efW1T = (bf16*)alloc((size_t)32768 * 2);
  // transposed bf16 node weights
  bf16* WqT   = (bf16*)alloc((size_t)262144 * 2);    // 4 x [256][256]
  bf16* WkvT  = (bf16*)alloc((size_t)524288 * 2);    // 4 x [512][256]
  bf16* SqkvT = (bf16*)alloc((size_t)786432 * 2);    // 4 x [768][256]
  bf16* WoT   = (bf16*)alloc((size_t)262144 * 2);
  bf16* SoT   = (bf16*)alloc((size_t)262144 * 2);
  bf16* Wn1T  = (bf16*)alloc((size_t)524288 * 2);    // 4 x [512][256]
  bf16* Wn2T  = (bf16*)alloc((size_t)524288 * 2);    // 4 x [256][512]
  bf16* WoijT = (bf16*)alloc((size_t)262144 * 2);    // 4 x [256][256]
  bf16* neW1T = (bf16*)alloc((size_t)131072 * 2);    // [512][256]
  bf16* neW2T = (bf16*)alloc((size_t)131072 * 2);    // [256][512]
  bf16* nfW1T = (bf16*)alloc((size_t)131072 * 2);    // [512][256]

  float* out = (float*)d_out;
  float* out_ne = out;               // 262144
  float* out_h  = out + 262144;      // 1024
  float* out_nl = out + 263168;      // 32768
  float* out_nf = out + 295936;      // 16384
  float* out_A  = out + 312320;      // 131072
  float* out_el = out + 443392;      // 1048576
  float* out_ef = out + 1491968;     // 1048576

  // ---- weight prep (edge) ----
  twcvt_kernel<<<dim3(4, 4, 4), 256, 0, stream>>>(Wga, WgaT, 128, 128, 16384, 16384);
  twcvt_kernel<<<dim3(4, 4, 4), 256, 0, stream>>>(Wa,  WaT,  128, 128, 16384, 16384);
  twcvt_kernel<<<dim3(4, 4, 4), 256, 0, stream>>>(Wgb, WgbT, 128, 128, 16384, 16384);
  twcvt_kernel<<<dim3(4, 4, 4), 256, 0, stream>>>(Wb2, Wb2T, 128, 128, 16384, 16384);
  twcvt_kernel<<<dim3(4, 4, 4), 256, 0, stream>>>(Wgp, WgpT, 128, 128, 16384, 16384);
  twcvt_kernel<<<dim3(4, 4, 4), 256, 0, stream>>>(Wp,  WpT,  128, 128, 16384, 16384);
  twcvt_kernel<<<dim3(8, 4, 4), 256, 0, stream>>>(We1, We1T, 128, 256, 32768, 32768);
  twcvt_kernel<<<dim3(4, 8, 4), 256, 0, stream>>>(We2, We2T, 256, 128, 32768, 32768);
  twcvt_kernel<<<dim3(8, 4, 1), 256, 0, stream>>>(efW1, efW1T, 128, 256, 32768, 32768);
  // ---- weight prep (node) ----
  twcvt_kernel<<<dim3(8, 8, 4), 256, 0, stream>>>(Wq, WqT, 256, 256, 65536, 65536);
  twcvt_kernel<<<dim3(8, 8, 4), 256, 0, stream>>>(Wk, WkvT, 256, 256, 65536, 131072);
  twcvt_kernel<<<dim3(8, 8, 4), 256, 0, stream>>>(Wv, WkvT + 65536, 256, 256, 65536, 131072);
  twcvt_kernel<<<dim3(8, 8, 4), 256, 0, stream>>>(Sq, SqkvT, 256, 256, 65536, 196608);
  twcvt_kernel<<<dim3(8, 8, 4), 256, 0, stream>>>(Sk, SqkvT + 65536, 256, 256, 65536, 196608);
  twcvt_kernel<<<dim3(8, 8, 4), 256, 0, stream>>>(Sv, SqkvT + 131072, 256, 256, 65536, 196608);
  twcvt_kernel<<<dim3(8, 8, 4), 256, 0, stream>>>(Wo, WoT, 256, 256, 65536, 65536);
  twcvt_kernel<<<dim3(8, 8, 4), 256, 0, stream>>>(So, SoT, 256, 256, 65536, 65536);
  twcvt_kernel<<<dim3(16, 8, 4), 256, 0, stream>>>(Wn1, Wn1T, 256, 512, 131072, 131072);
  twcvt_kernel<<<dim3(8, 16, 4), 256, 0, stream>>>(Wn2, Wn2T, 512, 256, 131072, 131072);
  twcvt_kernel<<<dim3(4, 8, 4), 256, 0, stream>>>(Woi, WoijT, 256, 128, 32768, 65536);
  twcvt_kernel<<<dim3(4, 8, 4), 256, 0, stream>>>(Woj, WoijT + 32768, 256, 128, 32768, 65536);
  twcvt_kernel<<<dim3(16, 8, 1), 256, 0, stream>>>(neW1, neW1T, 256, 512, 131072, 131072);
  twcvt_kernel<<<dim3(8, 16, 1), 256, 0, stream>>>(neW2, neW2T, 512, 256, 131072, 131072);
  twcvt_kernel<<<dim3(16, 8, 1), 256, 0, stream>>>(nfW1, nfW1T, 256, 512, 131072, 131072);

  // ---- init ----
  bcast_kernel<<<1024, 256, 0, stream>>>(Xq, X, 32767u, (size_t)262144);
  bcast_kernel<<<65536, 256, 0, stream>>>(Eq, E, 2097151u, (size_t)16777216);
  ln_kernel<256, float, bf16><<<1024, 256, 0, stream>>>(X, Xnb);
  ln_kernel<256, float, bf16><<<512, 256, 0, stream>>>(graph, srcb);
  ln128w_kernel<float, bf16><<<32768, 256, 0, stream>>>(E, En);

  for (int l = 0; l < 4; l++) {
    const bf16* WqT_l   = WqT   + l * 65536;
    const bf16* WkvT_l  = WkvT  + l * 131072;
    const bf16* SqkvT_l = SqkvT + l * 196608;
    const bf16* WoT_l   = WoT   + l * 65536;
    const bf16* SoT_l   = SoT   + l * 65536;
    const bf16* Wn1T_l  = Wn1T  + l * 131072;
    const bf16* Wn2T_l  = Wn2T  + l * 131072;
    const bf16* WoijT_l = WoijT + l * 65536;
    const float* Wb_l = Wb + l * 1024;
    const bf16* WgaT_l = WgaT + l * 16384; const bf16* WaT_l  = WaT  + l * 16384;
    const bf16* WgbT_l = WgbT + l * 16384; const bf16* Wb2T_l = Wb2T + l * 16384;
    const bf16* WgpT_l = WgpT + l * 16384; const bf16* WpT_l  = WpT  + l * 16384;
    const bf16* We1T_l = We1T + l * 32768; const bf16* We2T_l = We2T + l * 32768;

    // (a) cross attention
    ngemm_kernel<256, 0><<<dim3(4, 2), 256, 0, stream>>>(Xnb, WqT_l, qf, 256);
    ngemm_kernel<256, 0><<<dim3(2, 4), 256, 0, stream>>>(srcb, WkvT_l, kvf, 512);
    cross_attn_kernel<<<1024, 256, 0, stream>>>(qf, kvf, obB);
    mfma_addx_ln_kernel<256><<<8, 256, 0, stream>>>(obB, WoT_l, X, Xnb);

    // (b) pair-biased self attention
    head8_kernel<128, 1, 0><<<4096, 256, 0, stream>>>(En, Wb_l, bias, nullptr, nullptr);
    ngemm_kernel<256, 0><<<dim3(4, 6), 256, 0, stream>>>(Xnb, SqkvT_l, qkvf, 768);
    self_attn_kernel<<<1024, 256, 0, stream>>>(qkvf, bias, obB);
    mfma_addx_ln_kernel<256><<<8, 256, 0, stream>>>(obB, SoT_l, X, Xnb);

    // (c) node MLP
    ngemm_kernel<256, 1><<<dim3(4, 4), 256, 0, stream>>>(Xnb, Wn1T_l, H1, 512);
    mfma_addx_ln_kernel<512><<<8, 256, 0, stream>>>(H1, Wn2T_l, X, Xnb);

    // (d) outer sum into E + fused En = ln(E)
    ngemm_kernel<256, 0><<<dim3(4, 2), 256, 0, stream>>>(Xnb, WoijT_l, xixj, 256);
    outer_ln_kernel<<<65536, 256, 0, stream>>>(E, xixj, En);

    // (e) triangle multiplicative update (all-MFMA)
    mfma_nw2_kernel<2><<<512, 256, 0, stream>>>(En, WgaT_l, WaT_l, aT1);
    mfma_nw2_kernel<2><<<512, 256, 0, stream>>>(En, WgbT_l, Wb2T_l, bT1);
    mfma_sig_kernel<<<1024, 256, 0, stream>>>(En, WgpT_l, G);
    tri_mfma_kernel<<<1024, 256, 0, stream>>>(aT1, bT1, Tcm);
    permln_kernel<<<dim3(2, 128, 8), 256, 0, stream>>>(Tcm, Tn);
    mfma_gmul_add_ln_kernel<<<1024, 256, 0, stream>>>(Tn, WpT_l, G, E, En);

    // (f) edge MLP
    mfma_nw2_kernel<1><<<512, 256, 0, stream>>>(En, We1T_l, We1T_l + 16384, H);
    mfma_add_ln_kernel<<<1024, 256, 0, stream>>>(H, We2T_l, E, En);
  }

  // node heads (Xnb = ln(final X) from last addx_ln; X unchanged since)
  ngemm_kernel<256, 1><<<dim3(4, 4), 256, 0, stream>>>(Xnb, neW1T, H1, 512);
  ngemm_kernel<512, 0><<<dim3(4, 2), 256, 0, stream>>>(H1, neW2T, out_ne, 256);
  rowdot_kernel<256, bf16><<<1024, 256, 0, stream>>>(Xnb, hW, out_h);
  headN_kernel<256, 32><<<128, 256, 0, stream>>>(Xnb, nlW, out_nl);
  ngemm_kernel<256, 1><<<dim3(4, 4), 256, 0, stream>>>(Xnb, nfW1T, H1, 512);
  headN_kernel<512, 16><<<64, 256, 0, stream>>>(H1, nfW2, out_nf);

  // edge heads (En = ln(final E) from last mfma_add_ln)
  head8_kernel<128, 0, 1><<<4096, 256, 0, stream>>>(En, elW, out_el, aW, out_A);
  mfma_nw2_kernel<1><<<512, 256, 0, stream>>>(En, efW1T, efW1T + 16384, H);
  head8_kernel<256, 0, 0><<<4096, 256, 0, stream>>>(H, efW2, out_ef, nullptr, nullptr);
}

// Round 6
// 2031.673 us; speedup vs baseline: 4.8135x; 1.2779x over previous
//
#include <hip/hip_runtime.h>
#include <hip/hip_bf16.h>

using bf16 = __hip_bfloat16;

constexpr int Bc = 8, Kc = 64, Mc = 128, Dnc = 256, Dec = 128, Hnc = 512, Hec = 256, Hc = 8;
constexpr float INV_SQRT_DH = 0.17677669529663687f;   // 1/sqrt(32)

typedef __attribute__((ext_vector_type(8))) short s8v;   // 8 bf16 (4 VGPRs)
typedef __attribute__((ext_vector_type(4))) float f4v;   // 4 fp32
#define MFMA16(a, b, c) __builtin_amdgcn_mfma_f32_16x16x32_bf16(a, b, c, 0, 0, 0)

// ---------- helpers ----------
__device__ __forceinline__ float waveSum(float v) {
#pragma unroll
  for (int m = 32; m > 0; m >>= 1) v += __shfl_xor(v, m);
  return v;
}
__device__ __forceinline__ float b2f(unsigned short u) {
  union { unsigned x; float f; } v; v.x = (unsigned)u << 16; return v.f;
}
__device__ __forceinline__ unsigned short f2bu(float f) {
  bf16 h = __float2bfloat16(f); return *reinterpret_cast<unsigned short*>(&h);
}
__device__ __forceinline__ float ldf(const float* p) { return *p; }
__device__ __forceinline__ float ldf(const bf16* p)  { return __bfloat162float(*p); }
__device__ __forceinline__ void  stf(float* p, float v) { *p = v; }
__device__ __forceinline__ void  stf(bf16*  p, float v) { *p = __float2bfloat16(v); }

// ---------- LayerNorm over last dim D (one row per block) ----------
template<int D, typename InT, typename OutT>
__global__ __launch_bounds__(D) void ln_kernel(const InT* __restrict__ in, OutT* __restrict__ out) {
  constexpr int NW = D / 64;
  __shared__ float sb[NW];
  size_t row = blockIdx.x;
  int t = threadIdx.x;
  float v = ldf(in + row * D + t);
  float s = waveSum(v);
  if ((t & 63) == 0) sb[t >> 6] = s;
  __syncthreads();
  float tot = 0.f;
#pragma unroll
  for (int i = 0; i < NW; i++) tot += sb[i];
  float mean = tot * (1.0f / D);
  float d = v - mean;
  __syncthreads();
  float s2 = waveSum(d * d);
  if ((t & 63) == 0) sb[t >> 6] = s2;
  __syncthreads();
  float tot2 = 0.f;
#pragma unroll
  for (int i = 0; i < NW; i++) tot2 += sb[i];
  float rstd = rsqrtf(tot2 * (1.0f / D) + 1e-5f);
  stf(out + row * D + t, d * rstd);
}

// ---------- LayerNorm D=128, one row per WAVE ----------
template<typename InT, typename OutT>
__global__ __launch_bounds__(256) void ln128w_kernel(const InT* __restrict__ in,
                                                     OutT* __restrict__ out) {
  size_t row = (size_t)blockIdx.x * 4 + (threadIdx.x >> 6);
  int l = threadIdx.x & 63;
  const InT* p = in + row * 128 + l * 2;
  float v0 = ldf(p), v1 = ldf(p + 1);
  float mean = waveSum(v0 + v1) * (1.f / 128.f);
  float d0 = v0 - mean, d1 = v1 - mean;
  float rstd = rsqrtf(waveSum(d0 * d0 + d1 * d1) * (1.f / 128.f) + 1e-5f);
  OutT* q = out + row * 128 + l * 2;
  stf(q, d0 * rstd);
  stf(q + 1, d1 * rstd);
}

// ---------- broadcast init ----------
__global__ void bcast_kernel(const float* __restrict__ s, float* __restrict__ d,
                             unsigned mask, size_t total) {
  size_t i = (size_t)blockIdx.x * blockDim.x + threadIdx.x;
  if (i < total) d[i] = s[i & mask];
}

// ---------- weight transpose+convert: out[n][k] = bf16(in[k][n]) ----------
__global__ __launch_bounds__(256) void twcvt_kernel(const float* __restrict__ in,
                                                    bf16* __restrict__ out, int K, int N,
                                                    int inZ, int outZ) {
  const float* inp = in + (size_t)blockIdx.z * inZ;
  bf16* outp = out + (size_t)blockIdx.z * outZ;
  __shared__ float tile[32][33];
  int tx = threadIdx.x & 31, ty = threadIdx.x >> 5;
  int k0 = blockIdx.y * 32, n0 = blockIdx.x * 32;
#pragma unroll
  for (int it = 0; it < 4; it++)
    tile[ty + it * 8][tx] = inp[(size_t)(k0 + ty + it * 8) * N + n0 + tx];
  __syncthreads();
#pragma unroll
  for (int it = 0; it < 4; it++)
    outp[(size_t)(n0 + ty + it * 8) * K + k0 + tx] = __float2bfloat16(tile[tx][ty + it * 8]);
}

// ---------- MFMA tile staging with XOR swizzle ----------
template<int ROWS>
__device__ __forceinline__ void stageTile(const bf16* __restrict__ g, int srcLd,
                                          char* lds, int t) {
  constexpr int IT = ROWS * 16 / 256;
#pragma unroll
  for (int it = 0; it < IT; it++) {
    int u = t + it * 256;
    int row = u >> 4, c16 = u & 15;
    uint4 val = *(const uint4*)(g + (size_t)row * srcLd + c16 * 8);
    *(uint4*)(lds + row * 256 + ((c16 ^ (row & 7)) << 4)) = val;
  }
}
__device__ __forceinline__ s8v readFrag(const char* lds, int row, int c16) {
  return *(const s8v*)(lds + row * 256 + ((c16 ^ (row & 7)) << 4));
}

// ---------- node MFMA GEMM: 128 rows x 128 cols per block ----------
// EPI 0: f32 store [row][N]; EPI 1: relu->bf16 [row][N];
// EPI 2: bf16 scatter to [seg][b][h][i][32] (qkv head-split)
template<int KTOT, int EPI>
__global__ __launch_bounds__(256) void ngemm128_kernel(
    const bf16* __restrict__ A, const bf16* __restrict__ Wt, void* __restrict__ outv,
    int N, int rowShift) {
  __shared__ char Ash[32768];
  __shared__ char Wsh[32768];
  int t = threadIdx.x, l = t & 63, w = t >> 6;
  size_t r0 = (size_t)blockIdx.x * 128;
  int c0 = blockIdx.y * 128;
  int rb = w * 32;
  f4v acc[2][8];
#pragma unroll
  for (int rf = 0; rf < 2; rf++)
#pragma unroll
    for (int cf = 0; cf < 8; cf++) acc[rf][cf] = (f4v){0.f, 0.f, 0.f, 0.f};
#pragma unroll
  for (int kb = 0; kb < KTOT; kb += 128) {
    if (kb) __syncthreads();
    stageTile<128>(A + r0 * KTOT + kb, KTOT, Ash, t);
    stageTile<128>(Wt + (size_t)c0 * KTOT + kb, KTOT, Wsh, t);
    __syncthreads();
#pragma unroll
    for (int kc = 0; kc < 4; kc++) {
      int c16 = kc * 4 + (l >> 4);
      s8v af[2];
#pragma unroll
      for (int rf = 0; rf < 2; rf++) af[rf] = readFrag(Ash, rb + rf * 16 + (l & 15), c16);
#pragma unroll
      for (int cf = 0; cf < 8; cf++) {
        s8v b0 = readFrag(Wsh, cf * 16 + (l & 15), c16);
#pragma unroll
        for (int rf = 0; rf < 2; rf++) acc[rf][cf] = MFMA16(af[rf], b0, acc[rf][cf]);
      }
    }
  }
#pragma unroll
  for (int rf = 0; rf < 2; rf++)
#pragma unroll
    for (int cf = 0; cf < 8; cf++)
#pragma unroll
      for (int i = 0; i < 4; i++) {
        size_t row = r0 + rb + rf * 16 + ((l >> 4) << 2) + i;
        int col = c0 + cf * 16 + (l & 15);
        float v = acc[rf][cf][i];
        if (EPI == 0) {
          ((float*)outv)[row * N + col] = v;
        } else if (EPI == 1) {
          ((bf16*)outv)[row * N + col] = __float2bfloat16(fmaxf(v, 0.f));
        } else {
          int seg = col >> 8, h = (col >> 5) & 7, d = col & 31;
          int b = (int)(row >> rowShift);
          int ii = (int)(row & ((1 << rowShift) - 1));
          ((bf16*)outv)[(((size_t)seg * 8 + b) * 8 + h) * ((size_t)(1 << rowShift) * 32)
                        + (size_t)ii * 32 + d] = __float2bfloat16(v);
        }
      }
}

// ---------- MFMA fused attention: one block per (b*8+h, 64-row q-tile) ----------
// q layout [b][h][128][32]; k/v layouts [b][h][NKV][32] via kvStride elems per bh.
// o written to [b*128+i][h*32+d] bf16 (ld 256).
template<int NKV, int HASBIAS>
__global__ __launch_bounds__(256) void attn_mfma_kernel(
    const bf16* __restrict__ qb, const bf16* __restrict__ kb, const bf16* __restrict__ vb,
    int kvStride, const float* __restrict__ bias, bf16* __restrict__ o) {
  constexpr int CF = NKV / 16, KC = NKV / 32;
  constexpr int QB = 64 * 80, KB = NKV * 80, VB = 32 * NKV * 2, PB = 64 * NKV * 2;
  __shared__ char lds[QB + KB + VB + PB];
  char* Qs = lds; char* Ks = lds + QB; char* Vt = Ks + KB; char* Ps = Vt + VB;
  int t = threadIdx.x, l = t & 63, w = t >> 6;
  int bh = blockIdx.x, row0 = blockIdx.y * 64;
  const bf16* Qp = qb + (size_t)bh * 4096 + (size_t)row0 * 32;
  const bf16* Kp = kb + (size_t)bh * kvStride;
  const bf16* Vp = vb + (size_t)bh * kvStride;
  // stage Q (64 rows x 32, row stride 80B: 2-way bank alias = free)
  {
    int row = t >> 2, c = t & 3;
    *(uint4*)(Qs + row * 80 + c * 16) = *(const uint4*)(Qp + row * 32 + c * 8);
  }
  // stage K (NKV rows x 32)
  for (int u = t; u < NKV * 4; u += 256) {
    int row = u >> 2, c = u & 3;
    *(uint4*)(Ks + row * 80 + c * 16) = *(const uint4*)(Kp + row * 32 + c * 8);
  }
  // stage V transposed -> Vt[d][j], swizzled 16B-chunk rows of NKV*2 bytes
  for (int u = t; u < NKV * 4; u += 256) {
    int j = u >> 2, db = (u & 3) * 8;
    uint4 v = *(const uint4*)(Vp + j * 32 + db);
    const unsigned short* pv = (const unsigned short*)&v;
#pragma unroll
    for (int e = 0; e < 8; e++) {
      int d = db + e;
      *(unsigned short*)(Vt + d * (NKV * 2) + (((j >> 3) ^ (d & 7)) << 4) + (j & 7) * 2) = pv[e];
    }
  }
  __syncthreads();
  int rb = w * 16;
  // S = Q K^T  (one MFMA per 16-col fragment: K-dim = 32)
  f4v acc[CF];
#pragma unroll
  for (int cf = 0; cf < CF; cf++) acc[cf] = (f4v){0.f, 0.f, 0.f, 0.f};
  s8v aq = *(const s8v*)(Qs + (rb + (l & 15)) * 80 + (l >> 4) * 16);
#pragma unroll
  for (int cf = 0; cf < CF; cf++) {
    s8v bk = *(const s8v*)(Ks + (cf * 16 + (l & 15)) * 80 + (l >> 4) * 16);
    acc[cf] = MFMA16(aq, bk, acc[cf]);
  }
  // softmax per row (C-layout: row's 128 cols live in 16 lanes x CF regs)
#pragma unroll
  for (int i = 0; i < 4; i++) {
    int rl = rb + ((l >> 4) << 2) + i;
    float sv[CF];
    float mx = -1e30f;
#pragma unroll
    for (int cf = 0; cf < CF; cf++) {
      float s = acc[cf][i] * INV_SQRT_DH;
      if (HASBIAS)
        s += bias[((size_t)bh * 128 + row0 + rl) * 128 + cf * 16 + (l & 15)];
      sv[cf] = s; mx = fmaxf(mx, s);
    }
#pragma unroll
    for (int m = 1; m < 16; m <<= 1) mx = fmaxf(mx, __shfl_xor(mx, m));
    float sm = 0.f;
#pragma unroll
    for (int cf = 0; cf < CF; cf++) { sv[cf] = __expf(sv[cf] - mx); sm += sv[cf]; }
#pragma unroll
    for (int m = 1; m < 16; m <<= 1) sm += __shfl_xor(sm, m);
    float rs = 1.f / sm;
#pragma unroll
    for (int cf = 0; cf < CF; cf++) {
      int col = cf * 16 + (l & 15);
      int c16 = col >> 3;
      *(unsigned short*)(Ps + rl * (NKV * 2) + ((c16 ^ (rl & 7)) << 4) + (col & 7) * 2) =
          f2bu(sv[cf] * rs);
    }
  }
  __syncthreads();
  // O = P V  (A = P rows, B = V^T rows)
  f4v oacc[2];
  oacc[0] = (f4v){0.f, 0.f, 0.f, 0.f};
  oacc[1] = (f4v){0.f, 0.f, 0.f, 0.f};
#pragma unroll
  for (int kc = 0; kc < KC; kc++) {
    int c16 = kc * 4 + (l >> 4);
    int ar = rb + (l & 15);
    s8v ap = *(const s8v*)(Ps + ar * (NKV * 2) + ((c16 ^ (ar & 7)) << 4));
#pragma unroll
    for (int cf = 0; cf < 2; cf++) {
      int d = cf * 16 + (l & 15);
      s8v bv = *(const s8v*)(Vt + d * (NKV * 2) + ((c16 ^ (d & 7)) << 4));
      oacc[cf] = MFMA16(ap, bv, oacc[cf]);
    }
  }
  int b = bh >> 3, h = bh & 7;
#pragma unroll
  for (int cf = 0; cf < 2; cf++)
#pragma unroll
    for (int i = 0; i < 4; i++) {
      int rl = rb + ((l >> 4) << 2) + i;
      o[((size_t)(b * 128 + row0 + rl)) * 256 + h * 32 + cf * 16 + (l & 15)] =
          __float2bfloat16(oacc[cf][i]);
    }
}

// ---------- node residual+LN: X[64rows x 256] += A@Wt; Xnb = ln(X) fused ----------
template<int KTOT>
__global__ __launch_bounds__(256) void mfma_addx_ln_kernel(
    const bf16* __restrict__ A, const bf16* __restrict__ Wt,
    float* __restrict__ X, bf16* __restrict__ Xnb) {
  __shared__ char Ash[16384];
  __shared__ char Wsh[65536];
  int t = threadIdx.x, l = t & 63, w = t >> 6;
  size_t r0 = (size_t)blockIdx.x * 64;
  int rb = w * 16;
  f4v acc[16];
#pragma unroll
  for (int cf = 0; cf < 16; cf++) acc[cf] = (f4v){0.f, 0.f, 0.f, 0.f};
#pragma unroll
  for (int kb = 0; kb < KTOT; kb += 128) {
    if (kb) __syncthreads();
    stageTile<64>(A + r0 * KTOT + kb, KTOT, Ash, t);
    stageTile<256>(Wt + kb, KTOT, Wsh, t);
    __syncthreads();
#pragma unroll
    for (int kc = 0; kc < 4; kc++) {
      int c16 = kc * 4 + (l >> 4);
      s8v af = readFrag(Ash, rb + (l & 15), c16);
#pragma unroll
      for (int cf = 0; cf < 16; cf++) {
        s8v b0 = readFrag(Wsh, cf * 16 + (l & 15), c16);
        acc[cf] = MFMA16(af, b0, acc[cf]);
      }
    }
  }
#pragma unroll
  for (int cf = 0; cf < 16; cf++)
#pragma unroll
    for (int i = 0; i < 4; i++) {
      size_t row = r0 + rb + ((l >> 4) << 2) + i;
      size_t o = row * 256 + cf * 16 + (l & 15);
      float e = X[o] + acc[cf][i];
      X[o] = e; acc[cf][i] = e;
    }
#pragma unroll
  for (int i = 0; i < 4; i++) {
    float s = 0.f, s2 = 0.f;
#pragma unroll
    for (int cf = 0; cf < 16; cf++) { float x = acc[cf][i]; s += x; s2 += x * x; }
#pragma unroll
    for (int m = 1; m < 16; m <<= 1) { s += __shfl_xor(s, m); s2 += __shfl_xor(s2, m); }
    float mean = s * 0.00390625f;
    float rstd = rsqrtf(s2 * 0.00390625f - mean * mean + 1e-5f);
    size_t row = r0 + rb + ((l >> 4) << 2) + i;
#pragma unroll
    for (int cf = 0; cf < 16; cf++)
      Xnb[row * 256 + cf * 16 + (l & 15)] = __float2bfloat16((acc[cf][i] - mean) * rstd);
  }
}

// ---------- MFMA GEMM edge, 256 rows x 128 cols, two weight mats, K=128 ----------
template<int EPI>
__global__ __launch_bounds__(256, 1) void mfma_nw2_kernel(
    const bf16* __restrict__ A, const bf16* __restrict__ W0t, const bf16* __restrict__ W1t,
    bf16* __restrict__ out) {
  __shared__ char lds[131072];
  char* Ash = lds; char* W0sh = lds + 65536; char* W1sh = lds + 98304;
  int t = threadIdx.x, l = t & 63, w = t >> 6;
  size_t r0 = (size_t)blockIdx.x * 256;
  int rb = w * 64;
  stageTile<256>(A + r0 * 128, 128, Ash, t);
  stageTile<128>(W0t, 128, W0sh, t);
  stageTile<128>(W1t, 128, W1sh, t);
  __syncthreads();
  f4v acc0[4][8], acc1[4][8];
#pragma unroll
  for (int rf = 0; rf < 4; rf++)
#pragma unroll
    for (int cf = 0; cf < 8; cf++) {
      acc0[rf][cf] = (f4v){0.f, 0.f, 0.f, 0.f};
      acc1[rf][cf] = (f4v){0.f, 0.f, 0.f, 0.f};
    }
#pragma unroll
  for (int kc = 0; kc < 4; kc++) {
    int c16 = kc * 4 + (l >> 4);
    s8v af[4];
#pragma unroll
    for (int rf = 0; rf < 4; rf++) af[rf] = readFrag(Ash, rb + rf * 16 + (l & 15), c16);
#pragma unroll
    for (int cf = 0; cf < 8; cf++) {
      s8v b0 = readFrag(W0sh, cf * 16 + (l & 15), c16);
      s8v b1 = readFrag(W1sh, cf * 16 + (l & 15), c16);
#pragma unroll
      for (int rf = 0; rf < 4; rf++) {
        acc0[rf][cf] = MFMA16(af[rf], b0, acc0[rf][cf]);
        acc1[rf][cf] = MFMA16(af[rf], b1, acc1[rf][cf]);
      }
    }
  }
  if (EPI == 1) {
#pragma unroll
    for (int rf = 0; rf < 4; rf++)
#pragma unroll
      for (int cf = 0; cf < 8; cf++)
#pragma unroll
        for (int i = 0; i < 4; i++) {
          size_t row = r0 + rb + rf * 16 + ((l >> 4) << 2) + i;
          int col = cf * 16 + (l & 15);
          out[row * 256 + col]       = __float2bfloat16(fmaxf(acc0[rf][cf][i], 0.f));
          out[row * 256 + 128 + col] = __float2bfloat16(fmaxf(acc1[rf][cf][i], 0.f));
        }
  } else {
    __syncthreads();
    char* tb = lds;
#pragma unroll
    for (int rf = 0; rf < 4; rf++)
#pragma unroll
      for (int cf = 0; cf < 8; cf++) {
        int c = cf * 16 + (l & 15);
        int u0 = rb + rf * 16 + ((l >> 4) << 2);
        uint2 pv;
        pv.x = (unsigned)f2bu(acc1[rf][cf][0] / (1.f + __expf(-acc0[rf][cf][0]))) |
               ((unsigned)f2bu(acc1[rf][cf][1] / (1.f + __expf(-acc0[rf][cf][1]))) << 16);
        pv.y = (unsigned)f2bu(acc1[rf][cf][2] / (1.f + __expf(-acc0[rf][cf][2]))) |
               ((unsigned)f2bu(acc1[rf][cf][3] / (1.f + __expf(-acc0[rf][cf][3]))) << 16);
        *(uint2*)(tb + c * 560 + u0 * 2) = pv;
      }
    __syncthreads();
    int b_ = (int)(r0 >> 14); int ik0 = (int)(r0 & 16383);
    bf16* op = out + (size_t)b_ * 2097152 + ik0;
    int c2 = t >> 1, hf = t & 1;
#pragma unroll
    for (int q = 0; q < 16; q++) {
      int u = hf * 128 + q * 8;
      *(uint4*)(op + (size_t)c2 * 16384 + u) = *(const uint4*)(tb + c2 * 560 + u * 2);
    }
  }
}

// ---------- G = sigmoid(En @ Wt) ----------
__global__ __launch_bounds__(256) void mfma_sig_kernel(
    const bf16* __restrict__ A, const bf16* __restrict__ Wt, bf16* __restrict__ out) {
  __shared__ char lds[65536];
  char* Ash = lds; char* Wsh = lds + 32768;
  int t = threadIdx.x, l = t & 63, w = t >> 6;
  size_t r0 = (size_t)blockIdx.x * 128;
  int rb = w * 32;
  stageTile<128>(A + r0 * 128, 128, Ash, t);
  stageTile<128>(Wt, 128, Wsh, t);
  __syncthreads();
  f4v acc[2][8];
#pragma unroll
  for (int rf = 0; rf < 2; rf++)
#pragma unroll
    for (int cf = 0; cf < 8; cf++) acc[rf][cf] = (f4v){0.f, 0.f, 0.f, 0.f};
#pragma unroll
  for (int kc = 0; kc < 4; kc++) {
    int c16 = kc * 4 + (l >> 4);
    s8v af[2];
#pragma unroll
    for (int rf = 0; rf < 2; rf++) af[rf] = readFrag(Ash, rb + rf * 16 + (l & 15), c16);
#pragma unroll
    for (int cf = 0; cf < 8; cf++) {
      s8v b0 = readFrag(Wsh, cf * 16 + (l & 15), c16);
#pragma unroll
      for (int rf = 0; rf < 2; rf++) acc[rf][cf] = MFMA16(af[rf], b0, acc[rf][cf]);
    }
  }
#pragma unroll
  for (int rf = 0; rf < 2; rf++)
#pragma unroll
    for (int cf = 0; cf < 8; cf++)
#pragma unroll
      for (int i = 0; i < 4; i++) {
        size_t row = r0 + rb + rf * 16 + ((l >> 4) << 2) + i;
        int col = cf * 16 + (l & 15);
        out[row * 128 + col] = __float2bfloat16(1.f / (1.f + __expf(-acc[rf][cf][i])));
      }
}

// ---------- E += G * (Tn@Wt); En = LN(E) fused ----------
__global__ __launch_bounds__(256) void mfma_gmul_add_ln_kernel(
    const bf16* __restrict__ A, const bf16* __restrict__ Wt, const bf16* __restrict__ G,
    float* __restrict__ E, bf16* __restrict__ En) {
  __shared__ char lds[65536];
  char* Ash = lds; char* Wsh = lds + 32768;
  int t = threadIdx.x, l = t & 63, w = t >> 6;
  size_t r0 = (size_t)blockIdx.x * 128;
  int rb = w * 32;
  stageTile<128>(A + r0 * 128, 128, Ash, t);
  stageTile<128>(Wt, 128, Wsh, t);
  __syncthreads();
  f4v acc[2][8];
#pragma unroll
  for (int rf = 0; rf < 2; rf++)
#pragma unroll
    for (int cf = 0; cf < 8; cf++) acc[rf][cf] = (f4v){0.f, 0.f, 0.f, 0.f};
#pragma unroll
  for (int kc = 0; kc < 4; kc++) {
    int c16 = kc * 4 + (l >> 4);
    s8v af[2];
#pragma unroll
    for (int rf = 0; rf < 2; rf++) af[rf] = readFrag(Ash, rb + rf * 16 + (l & 15), c16);
#pragma unroll
    for (int cf = 0; cf < 8; cf++) {
      s8v b0 = readFrag(Wsh, cf * 16 + (l & 15), c16);
#pragma unroll
      for (int rf = 0; rf < 2; rf++) acc[rf][cf] = MFMA16(af[rf], b0, acc[rf][cf]);
    }
  }
  float vv[2][8][4];
#pragma unroll
  for (int rf = 0; rf < 2; rf++)
#pragma unroll
    for (int cf = 0; cf < 8; cf++)
#pragma unroll
      for (int i = 0; i < 4; i++) {
        size_t row = r0 + rb + rf * 16 + ((l >> 4) << 2) + i;
        size_t o = row * 128 + cf * 16 + (l & 15);
        float e = E[o] + __bfloat162float(G[o]) * acc[rf][cf][i];
        E[o] = e; vv[rf][cf][i] = e;
      }
#pragma unroll
  for (int rf = 0; rf < 2; rf++)
#pragma unroll
    for (int i = 0; i < 4; i++) {
      float s = 0.f, s2 = 0.f;
#pragma unroll
      for (int cf = 0; cf < 8; cf++) { float x = vv[rf][cf][i]; s += x; s2 += x * x; }
#pragma unroll
      for (int m = 1; m < 16; m <<= 1) { s += __shfl_xor(s, m); s2 += __shfl_xor(s2, m); }
      float mean = s * 0.0078125f;
      float rstd = rsqrtf(s2 * 0.0078125f - mean * mean + 1e-5f);
      size_t row = r0 + rb + rf * 16 + ((l >> 4) << 2) + i;
#pragma unroll
      for (int cf = 0; cf < 8; cf++)
        En[row * 128 + cf * 16 + (l & 15)] = __float2bfloat16((vv[rf][cf][i] - mean) * rstd);
    }
}

// ---------- E += H @ Wt (K=256); En = LN(E) fused ----------
__global__ __launch_bounds__(256) void mfma_add_ln_kernel(
    const bf16* __restrict__ A, const bf16* __restrict__ Wt,
    float* __restrict__ E, bf16* __restrict__ En) {
  __shared__ char lds[65536];
  char* Ash = lds; char* Wsh = lds + 32768;
  int t = threadIdx.x, l = t & 63, w = t >> 6;
  size_t r0 = (size_t)blockIdx.x * 128;
  int rb = w * 32;
  f4v acc[2][8];
#pragma unroll
  for (int rf = 0; rf < 2; rf++)
#pragma unroll
    for (int cf = 0; cf < 8; cf++) acc[rf][cf] = (f4v){0.f, 0.f, 0.f, 0.f};
#pragma unroll
  for (int kb = 0; kb < 2; kb++) {
    if (kb) __syncthreads();
    stageTile<128>(A + r0 * 256 + kb * 128, 256, Ash, t);
    stageTile<128>(Wt + kb * 128, 256, Wsh, t);
    __syncthreads();
#pragma unroll
    for (int kc = 0; kc < 4; kc++) {
      int c16 = kc * 4 + (l >> 4);
      s8v af[2];
#pragma unroll
      for (int rf = 0; rf < 2; rf++) af[rf] = readFrag(Ash, rb + rf * 16 + (l & 15), c16);
#pragma unroll
      for (int cf = 0; cf < 8; cf++) {
        s8v b0 = readFrag(Wsh, cf * 16 + (l & 15), c16);
#pragma unroll
        for (int rf = 0; rf < 2; rf++) acc[rf][cf] = MFMA16(af[rf], b0, acc[rf][cf]);
      }
    }
  }
  float vv[2][8][4];
#pragma unroll
  for (int rf = 0; rf < 2; rf++)
#pragma unroll
    for (int cf = 0; cf < 8; cf++)
#pragma unroll
      for (int i = 0; i < 4; i++) {
        size_t row = r0 + rb + rf * 16 + ((l >> 4) << 2) + i;
        size_t o = row * 128 + cf * 16 + (l & 15);
        float e = E[o] + acc[rf][cf][i];
        E[o] = e; vv[rf][cf][i] = e;
      }
#pragma unroll
  for (int rf = 0; rf < 2; rf++)
#pragma unroll
    for (int i = 0; i < 4; i++) {
      float s = 0.f, s2 = 0.f;
#pragma unroll
      for (int cf = 0; cf < 8; cf++) { float x = vv[rf][cf][i]; s += x; s2 += x * x; }
#pragma unroll
      for (int m = 1; m < 16; m <<= 1) { s += __shfl_xor(s, m); s2 += __shfl_xor(s2, m); }
      float mean = s * 0.0078125f;
      float rstd = rsqrtf(s2 * 0.0078125f - mean * mean + 1e-5f);
      size_t row = r0 + rb + rf * 16 + ((l >> 4) << 2) + i;
#pragma unroll
      for (int cf = 0; cf < 8; cf++)
        En[row * 128 + cf * 16 + (l & 15)] = __float2bfloat16((vv[rf][cf][i] - mean) * rstd);
    }
}

// ---------- triangle via MFMA: one block per (b,c) ----------
__global__ __launch_bounds__(256, 1) void tri_mfma_kernel(
    const bf16* __restrict__ aT, const bf16* __restrict__ bT, bf16* __restrict__ Tcm) {
  __shared__ char lds[131072];
  char* P1 = lds; char* Q1 = lds + 32768; char* P2 = lds + 65536; char* Q2 = lds + 98304;
  int t = threadIdx.x, l = t & 63, w = t >> 6;
  int bc = blockIdx.x;
  stageTile<128>(aT + (size_t)bc * 16384, 128, P1, t);
  stageTile<128>(bT + (size_t)bc * 16384, 128, Q1, t);
  __syncthreads();
#pragma unroll 8
  for (int it = 0; it < 64; it++) {
    int tile_ = w * 64 + it;
    int k0 = (tile_ & 15) * 8, r0 = (tile_ >> 4) * 8;
    int k = k0 + (l & 7), r = r0 + (l >> 3);
    int ra = r * 256 + ((((k >> 3) ^ (r & 7)) << 4)) + (k & 7) * 2;
    int wa = k * 256 + ((((r >> 3) ^ (k & 7)) << 4)) + (r & 7) * 2;
    *(unsigned short*)(P2 + wa) = *(const unsigned short*)(P1 + ra);
    *(unsigned short*)(Q2 + wa) = *(const unsigned short*)(Q1 + ra);
  }
  __syncthreads();
  int rb = w * 32;
  f4v acc1[2][8], acc2[2][8];
#pragma unroll
  for (int rf = 0; rf < 2; rf++)
#pragma unroll
    for (int cf = 0; cf < 8; cf++) {
      acc1[rf][cf] = (f4v){0.f, 0.f, 0.f, 0.f};
      acc2[rf][cf] = (f4v){0.f, 0.f, 0.f, 0.f};
    }
#pragma unroll
  for (int kc = 0; kc < 4; kc++) {
    int c16 = kc * 4 + (l >> 4);
    s8v a1[2], a2[2];
#pragma unroll
    for (int rf = 0; rf < 2; rf++) {
      a1[rf] = readFrag(P1, rb + rf * 16 + (l & 15), c16);
      a2[rf] = readFrag(P2, rb + rf * 16 + (l & 15), c16);
    }
#pragma unroll
    for (int cf = 0; cf < 8; cf++) {
      s8v b1 = readFrag(Q1, cf * 16 + (l & 15), c16);
      s8v b2 = readFrag(Q2, cf * 16 + (l & 15), c16);
#pragma unroll
      for (int rf = 0; rf < 2; rf++) {
        acc1[rf][cf] = MFMA16(a1[rf], b1, acc1[rf][cf]);
        acc2[rf][cf] = MFMA16(a2[rf], b2, acc2[rf][cf]);
      }
    }
  }
  __syncthreads();
  char* tb = lds;
#pragma unroll
  for (int rf = 0; rf < 2; rf++)
#pragma unroll
    for (int cf = 0; cf < 8; cf++) {
      int j = cf * 16 + (l & 15);
      int i0 = rb + rf * 16 + ((l >> 4) << 2);
      uint2 pv;
      pv.x = (unsigned)f2bu(0.5f * (acc1[rf][cf][0] + acc2[rf][cf][0])) |
             ((unsigned)f2bu(0.5f * (acc1[rf][cf][1] + acc2[rf][cf][1])) << 16);
      pv.y = (unsigned)f2bu(0.5f * (acc1[rf][cf][2] + acc2[rf][cf][2])) |
             ((unsigned)f2bu(0.5f * (acc1[rf][cf][3] + acc2[rf][cf][3])) << 16);
      *(uint2*)(tb + j * 560 + i0 * 2) = pv;
    }
  __syncthreads();
  bf16* op = Tcm + (size_t)bc * 16384;
#pragma unroll
  for (int q = 0; q < 8; q++) {
    int ci = q * 256 + t;
    *(uint4*)(op + ci * 8) = *(const uint4*)(tb + (ci >> 4) * 560 + (ci & 15) * 16);
  }
}

// ---------- permute + LN: Tcm[b][c][j][i] -> Tn[(b,i,j)][c] with LN over c ----------
__global__ __launch_bounds__(256) void permln_kernel(const bf16* __restrict__ Tcm,
                                                     bf16* __restrict__ Tn) {
  __shared__ float tile[128][77];
  __shared__ float ps[4][64], ps2[4][64], mst[64], rst[64];
  int b = blockIdx.z, j = blockIdx.y, i0 = blockIdx.x * 64;
  int t = threadIdx.x;
  const bf16* src = Tcm + (size_t)b * 2097152 + j * 128 + i0;
#pragma unroll
  for (int q = 0; q < 4; q++) {
    int ci = q * 256 + t; int c = ci >> 3, ch = ci & 7;
    uint4 v = *(const uint4*)(src + (size_t)c * 16384 + ch * 8);
    const unsigned short* u = (const unsigned short*)&v;
#pragma unroll
    for (int e = 0; e < 8; e++) tile[c][ch * 8 + e] = b2f(u[e]);
  }
  __syncthreads();
  {
    int i_ = t & 63, part = t >> 6;
    float s = 0.f, s2 = 0.f;
    for (int c = part * 32; c < part * 32 + 32; c++) { float x = tile[c][i_]; s += x; s2 += x * x; }
    ps[part][i_] = s; ps2[part][i_] = s2;
  }
  __syncthreads();
  if (t < 64) {
    float s = ps[0][t] + ps[1][t] + ps[2][t] + ps[3][t];
    float q2 = ps2[0][t] + ps2[1][t] + ps2[2][t] + ps2[3][t];
    float mean = s * 0.0078125f;
    float var = q2 * 0.0078125f - mean * mean;
    mst[t] = mean; rst[t] = rsqrtf(var + 1e-5f);
  }
  __syncthreads();
  {
    int i2 = t & 63, c0 = (t >> 6) * 32;
    float mean = mst[i2], rstd = rst[i2];
    bf16* dst = Tn + ((size_t)b * 16384 + (size_t)(i0 + i2) * 128 + j) * 128 + c0;
#pragma unroll
    for (int qq = 0; qq < 4; qq++) {
      unsigned short pk[8];
#pragma unroll
      for (int e = 0; e < 8; e++)
        pk[e] = f2bu((tile[c0 + qq * 8 + e][i2] - mean) * rstd);
      *(uint4*)(dst + qq * 8) = *(uint4*)pk;
    }
  }
}

// ---------- E += outer(xi,xj) [packed xixj ld=256]; En = LN(E) fused ----------
__global__ __launch_bounds__(256) void outer_ln_kernel(float* __restrict__ E,
    const float* __restrict__ xixj, bf16* __restrict__ En) {
  __shared__ float sb[8];
  size_t r = (size_t)blockIdx.x * 2 + (threadIdx.x >> 7);
  int t = threadIdx.x & 127;
  int b = (int)(r >> 14), i = (int)((r >> 7) & 127), j = (int)(r & 127);
  size_t o = r * 128 + t;
  float e = E[o] + xixj[(size_t)(b * 128 + i) * 256 + t]
                 + xixj[(size_t)(b * 128 + j) * 256 + 128 + t];
  E[o] = e;
  int wg = threadIdx.x >> 6, rh = threadIdx.x >> 7;
  float s = waveSum(e);
  if ((threadIdx.x & 63) == 0) sb[wg] = s;
  __syncthreads();
  float mean = (sb[rh * 2] + sb[rh * 2 + 1]) * (1.f / 128.f);
  float d = e - mean;
  float s2 = waveSum(d * d);
  if ((threadIdx.x & 63) == 0) sb[4 + wg] = s2;
  __syncthreads();
  float rstd = rsqrtf((sb[4 + rh * 2] + sb[4 + rh * 2 + 1]) * (1.f / 128.f) + 1e-5f);
  En[o] = __float2bfloat16(d * rstd);
}

// ---------- 8-col head: out[r,h] = sum_k A[r,k]*W[k,h]; BIAS scatter / A-dot ----------
template<int K, int BIAS, int WITHA>
__global__ __launch_bounds__(256) void head8_kernel(const bf16* __restrict__ A,
    const float* __restrict__ W, float* __restrict__ out,
    const float* __restrict__ aW, float* __restrict__ outA) {
  __shared__ __align__(16) bf16 As[32 * K];
  __shared__ float Ws[K * 8];
  __shared__ float aWs[128];
  size_t r0 = (size_t)blockIdx.x * 32;
  int t = threadIdx.x;
  constexpr int NCH = 32 * K / 8;
#pragma unroll
  for (int it = 0; it < NCH / 256; it++)
    ((uint4*)As)[t + it * 256] = ((const uint4*)(A + r0 * K))[t + it * 256];
  for (int u = t; u < K * 8; u += 256) Ws[u] = W[u];
  if (WITHA) { if (t < 128) aWs[t] = aW[t]; }
  __syncthreads();
  int rr = t >> 3, h = t & 7;
  float acc = 0.f;
#pragma unroll 4
  for (int k = 0; k < K; k++) acc += __bfloat162float(As[rr * K + k]) * Ws[k * 8 + h];
  size_t r = r0 + rr;
  if (BIAS) {
    size_t b = r >> 14, ij = r & 16383;
    out[((b * 8 + h) << 14) + ij] = acc;
  } else {
    out[r * 8 + h] = acc;
  }
  if (WITHA) {
    if (t < 32) {
      float a2 = 0.f;
#pragma unroll 4
      for (int k = 0; k < K; k++) a2 += __bfloat162float(As[t * K + k]) * aWs[k];
      outA[r0 + t] = a2;
    }
  }
}

// ---------- generic narrow head ----------
template<int K, int N>
__global__ __launch_bounds__(256) void headN_kernel(const bf16* __restrict__ A,
    const float* __restrict__ W, float* __restrict__ out) {
  constexpr int R = 256 / N;
  __shared__ __align__(16) bf16 As[R * K];
  __shared__ float Ws[K * N];
  size_t r0 = (size_t)blockIdx.x * R;
  int t = threadIdx.x;
  constexpr int NCH = R * K / 8;
#pragma unroll
  for (int it = 0; it < NCH / 256; it++)
    ((uint4*)As)[t + it * 256] = ((const uint4*)(A + r0 * K))[t + it * 256];
  for (int u = t; u < K * N; u += 256) Ws[u] = W[u];
  __syncthreads();
  int rr = t / N, h = t % N;
  float acc = 0.f;
#pragma unroll 4
  for (int k = 0; k < K; k++) acc += __bfloat162float(As[rr * K + k]) * Ws[k * N + h];
  out[(r0 + rr) * N + h] = acc;
}

// ---------- row dot ----------
template<int D, typename InT>
__global__ __launch_bounds__(D) void rowdot_kernel(const InT* __restrict__ A,
    const float* __restrict__ w, float* __restrict__ out) {
  __shared__ float sb[D / 64];
  size_t r = blockIdx.x; int t = threadIdx.x;
  float v = ldf(A + r * D + t) * w[t];
  v = waveSum(v);
  if ((t & 63) == 0) sb[t >> 6] = v;
  __syncthreads();
  if (t == 0) { float s = 0.f; for (int i = 0; i < D / 64; i++) s += sb[i]; out[r] = s; }
}

extern "C" void kernel_launch(void* const* d_in, const int* in_sizes, int n_in,
                              void* d_out, int out_size, void* d_ws, size_t ws_size,
                              hipStream_t stream) {
  const float* graph = (const float*)d_in[0];
  const float* Xq  = (const float*)d_in[1];
  const float* Eq  = (const float*)d_in[2];
  const float* Wq  = (const float*)d_in[3];
  const float* Wk  = (const float*)d_in[4];
  const float* Wv  = (const float*)d_in[5];
  const float* Wo  = (const float*)d_in[6];
  const float* Sq  = (const float*)d_in[7];
  const float* Sk  = (const float*)d_in[8];
  const float* Sv  = (const float*)d_in[9];
  const float* So  = (const float*)d_in[10];
  const float* Wb  = (const float*)d_in[11];
  const float* Wn1 = (const float*)d_in[12];
  const float* Wn2 = (const float*)d_in[13];
  const float* Woi = (const float*)d_in[14];
  const float* Woj = (const float*)d_in[15];
  const float* Wa  = (const float*)d_in[16];
  const float* Wga = (const float*)d_in[17];
  const float* Wb2 = (const float*)d_in[18];
  const float* Wgb = (const float*)d_in[19];
  const float* Wp  = (const float*)d_in[20];
  const float* Wgp = (const float*)d_in[21];
  const float* We1 = (const float*)d_in[22];
  const float* We2 = (const float*)d_in[23];
  const float* hW  = (const float*)d_in[24];
  const float* neW1 = (const float*)d_in[25];
  const float* neW2 = (const float*)d_in[26];
  const float* nlW  = (const float*)d_in[27];
  const float* nfW1 = (const float*)d_in[28];
  const float* nfW2 = (const float*)d_in[29];
  const float* aW   = (const float*)d_in[30];
  const float* elW  = (const float*)d_in[31];
  const float* efW1 = (const float*)d_in[32];
  const float* efW2 = (const float*)d_in[33];

  char* wsb = (char*)d_ws;
  size_t off = 0;
  auto alloc = [&](size_t bytes) -> char* {
    char* p = wsb + off; off += (bytes + 255) & ~(size_t)255; return p;
  };
  float* X    = (float*)alloc((size_t)262144 * 4);
  bf16*  Xnb  = (bf16*)alloc((size_t)262144 * 2);
  bf16*  srcb = (bf16*)alloc((size_t)131072 * 2);
  bf16*  qb2  = (bf16*)alloc((size_t)262144 * 2);   // cross q  [b][h][128][32]
  bf16*  kvb2 = (bf16*)alloc((size_t)262144 * 2);   // cross kv [k/v][b][h][64][32]
  bf16*  sqkvb = (bf16*)alloc((size_t)786432 * 2);  // self qkv [q/k/v][b][h][128][32]
  bf16*  obB  = (bf16*)alloc((size_t)262144 * 2);
  bf16*  H1   = (bf16*)alloc((size_t)524288 * 2);
  float* xixj = (float*)alloc((size_t)262144 * 4);
  float* bias = (float*)alloc((size_t)1048576 * 4);
  float* E   = (float*)alloc((size_t)16777216 * 4);
  bf16* En   = (bf16*)alloc((size_t)16777216 * 2);
  bf16* aT1  = (bf16*)alloc((size_t)16777216 * 2);   // [b][c][i][k]
  bf16* bT1  = (bf16*)alloc((size_t)16777216 * 2);   // [b][c][j][k]
  bf16* Tcm  = (bf16*)alloc((size_t)16777216 * 2);   // [b][c][j][i]
  bf16* G    = (bf16*)alloc((size_t)16777216 * 2);   // sigmoid(En@Wgp)
  bf16* Tn   = aT1;      // alias: aT1 dead after tri
  bf16* H    = aT1;      // alias: spans aT1+bT1 (contiguous)
  // transposed bf16 edge weights
  bf16* WgaT = (bf16*)alloc((size_t)65536 * 2);
  bf16* WaT  = (bf16*)alloc((size_t)65536 * 2);
  bf16* WgbT = (bf16*)alloc((size_t)65536 * 2);
  bf16* Wb2T = (bf16*)alloc((size_t)65536 * 2);
  bf16* WgpT = (bf16*)alloc((size_t)65536 * 2);
  bf16* WpT  = (bf16*)alloc((size_t)65536 * 2);
  bf16* We1T = (bf16*)alloc((size_t)131072 * 2);
  bf16* We2T = (bf16*)alloc((size_t)131072 * 2);
  bf16* efW1T = (bf16*)alloc((size_t)32768 * 2);
  // transposed bf16 node weights
  bf16* WqT   = (bf16*)alloc((size_t)262144 * 2);
  bf16* WkvT  = (bf16*)alloc((size_t)524288 * 2);
  bf16* SqkvT = (bf16*)alloc((size_t)786432 * 2);
  bf16* WoT   = (bf16*)alloc((size_t)262144 * 2);
  bf16* SoT   = (bf16*)alloc((size_t)262144 * 2);
  bf16* Wn1T  = (bf16*)alloc((size_t)524288 * 2);
  bf16* Wn2T  = (bf16*)alloc((size_t)524288 * 2);
  bf16* WoijT = (bf16*)alloc((size_t)262144 * 2);
  bf16* neW1T = (bf16*)alloc((size_t)131072 * 2);
  bf16* neW2T = (bf16*)alloc((size_t)131072 * 2);
  bf16* nfW1T = (bf16*)alloc((size_t)131072 * 2);

  float* out = (float*)d_out;
  float* out_ne = out;               // 262144
  float* out_h  = out + 262144;      // 1024
  float* out_nl = out + 263168;      // 32768
  float* out_nf = out + 295936;      // 16384
  float* out_A  = out + 312320;      // 131072
  float* out_el = out + 443392;      // 1048576
  float* out_ef = out + 1491968;     // 1048576

  // ---- weight prep (edge) ----
  twcvt_kernel<<<dim3(4, 4, 4), 256, 0, stream>>>(Wga, WgaT, 128, 128, 16384, 16384);
  twcvt_kernel<<<dim3(4, 4, 4), 256, 0, stream>>>(Wa,  WaT,  128, 128, 16384, 16384);
  twcvt_kernel<<<dim3(4, 4, 4), 256, 0, stream>>>(Wgb, WgbT, 128, 128, 16384, 16384);
  twcvt_kernel<<<dim3(4, 4, 4), 256, 0, stream>>>(Wb2, Wb2T, 128, 128, 16384, 16384);
  twcvt_kernel<<<dim3(4, 4, 4), 256, 0, stream>>>(Wgp, WgpT, 128, 128, 16384, 16384);
  twcvt_kernel<<<dim3(4, 4, 4), 256, 0, stream>>>(Wp,  WpT,  128, 128, 16384, 16384);
  twcvt_kernel<<<dim3(8, 4, 4), 256, 0, stream>>>(We1, We1T, 128, 256, 32768, 32768);
  twcvt_kernel<<<dim3(4, 8, 4), 256, 0, stream>>>(We2, We2T, 256, 128, 32768, 32768);
  twcvt_kernel<<<dim3(8, 4, 1), 256, 0, stream>>>(efW1, efW1T, 128, 256, 32768, 32768);
  // ---- weight prep (node) ----
  twcvt_kernel<<<dim3(8, 8, 4), 256, 0, stream>>>(Wq, WqT, 256, 256, 65536, 65536);
  twcvt_kernel<<<dim3(8, 8, 4), 256, 0, stream>>>(Wk, WkvT, 256, 256, 65536, 131072);
  twcvt_kernel<<<dim3(8, 8, 4), 256, 0, stream>>>(Wv, WkvT + 65536, 256, 256, 65536, 131072);
  twcvt_kernel<<<dim3(8, 8, 4), 256, 0, stream>>>(Sq, SqkvT, 256, 256, 65536, 196608);
  twcvt_kernel<<<dim3(8, 8, 4), 256, 0, stream>>>(Sk, SqkvT + 65536, 256, 256, 65536, 196608);
  twcvt_kernel<<<dim3(8, 8, 4), 256, 0, stream>>>(Sv, SqkvT + 131072, 256, 256, 65536, 196608);
  twcvt_kernel<<<dim3(8, 8, 4), 256, 0, stream>>>(Wo, WoT, 256, 256, 65536, 65536);
  twcvt_kernel<<<dim3(8, 8, 4), 256, 0, stream>>>(So, SoT, 256, 256, 65536, 65536);
  twcvt_kernel<<<dim3(16, 8, 4), 256, 0, stream>>>(Wn1, Wn1T, 256, 512, 131072, 131072);
  twcvt_kernel<<<dim3(8, 16, 4), 256, 0, stream>>>(Wn2, Wn2T, 512, 256, 131072, 131072);
  twcvt_kernel<<<dim3(4, 8, 4), 256, 0, stream>>>(Woi, WoijT, 256, 128, 32768, 65536);
  twcvt_kernel<<<dim3(4, 8, 4), 256, 0, stream>>>(Woj, WoijT + 32768, 256, 128, 32768, 65536);
  twcvt_kernel<<<dim3(16, 8, 1), 256, 0, stream>>>(neW1, neW1T, 256, 512, 131072, 131072);
  twcvt_kernel<<<dim3(8, 16, 1), 256, 0, stream>>>(neW2, neW2T, 512, 256, 131072, 131072);
  twcvt_kernel<<<dim3(16, 8, 1), 256, 0, stream>>>(nfW1, nfW1T, 256, 512, 131072, 131072);

  // ---- init ----
  bcast_kernel<<<1024, 256, 0, stream>>>(Xq, X, 32767u, (size_t)262144);
  bcast_kernel<<<65536, 256, 0, stream>>>(Eq, E, 2097151u, (size_t)16777216);
  ln_kernel<256, float, bf16><<<1024, 256, 0, stream>>>(X, Xnb);
  ln_kernel<256, float, bf16><<<512, 256, 0, stream>>>(graph, srcb);
  ln128w_kernel<float, bf16><<<32768, 256, 0, stream>>>(E, En);

  for (int l = 0; l < 4; l++) {
    const bf16* WqT_l   = WqT   + l * 65536;
    const bf16* WkvT_l  = WkvT  + l * 131072;
    const bf16* SqkvT_l = SqkvT + l * 196608;
    const bf16* WoT_l   = WoT   + l * 65536;
    const bf16* SoT_l   = SoT   + l * 65536;
    const bf16* Wn1T_l  = Wn1T  + l * 131072;
    const bf16* Wn2T_l  = Wn2T  + l * 131072;
    const bf16* WoijT_l = WoijT + l * 65536;
    const float* Wb_l = Wb + l * 1024;
    const bf16* WgaT_l = WgaT + l * 16384; const bf16* WaT_l  = WaT  + l * 16384;
    const bf16* WgbT_l = WgbT + l * 16384; const bf16* Wb2T_l = Wb2T + l * 16384;
    const bf16* WgpT_l = WgpT + l * 16384; const bf16* WpT_l  = WpT  + l * 16384;
    const bf16* We1T_l = We1T + l * 32768; const bf16* We2T_l = We2T + l * 32768;

    // (a) cross attention (MFMA)
    ngemm128_kernel<256, 2><<<dim3(8, 2), 256, 0, stream>>>(Xnb, WqT_l, qb2, 256, 7);
    ngemm128_kernel<256, 2><<<dim3(4, 4), 256, 0, stream>>>(srcb, WkvT_l, kvb2, 512, 6);
    attn_mfma_kernel<64, 0><<<dim3(64, 2), 256, 0, stream>>>(
        qb2, kvb2, kvb2 + 131072, 2048, nullptr, obB);
    mfma_addx_ln_kernel<256><<<16, 256, 0, stream>>>(obB, WoT_l, X, Xnb);

    // (b) pair-biased self attention (MFMA)
    head8_kernel<128, 1, 0><<<4096, 256, 0, stream>>>(En, Wb_l, bias, nullptr, nullptr);
    ngemm128_kernel<256, 2><<<dim3(8, 6), 256, 0, stream>>>(Xnb, SqkvT_l, sqkvb, 768, 7);
    attn_mfma_kernel<128, 1><<<dim3(64, 2), 256, 0, stream>>>(
        sqkvb, sqkvb + 262144, sqkvb + 524288, 4096, bias, obB);
    mfma_addx_ln_kernel<256><<<16, 256, 0, stream>>>(obB, SoT_l, X, Xnb);

    // (c) node MLP
    ngemm128_kernel<256, 1><<<dim3(8, 4), 256, 0, stream>>>(Xnb, Wn1T_l, H1, 512, 0);
    mfma_addx_ln_kernel<512><<<16, 256, 0, stream>>>(H1, Wn2T_l, X, Xnb);

    // (d) outer sum into E + fused En = ln(E)
    ngemm128_kernel<256, 0><<<dim3(8, 2), 256, 0, stream>>>(Xnb, WoijT_l, xixj, 256, 0);
    outer_ln_kernel<<<65536, 256, 0, stream>>>(E, xixj, En);

    // (e) triangle multiplicative update (all-MFMA)
    mfma_nw2_kernel<2><<<512, 256, 0, stream>>>(En, WgaT_l, WaT_l, aT1);
    mfma_nw2_kernel<2><<<512, 256, 0, stream>>>(En, WgbT_l, Wb2T_l, bT1);
    mfma_sig_kernel<<<1024, 256, 0, stream>>>(En, WgpT_l, G);
    tri_mfma_kernel<<<1024, 256, 0, stream>>>(aT1, bT1, Tcm);
    permln_kernel<<<dim3(2, 128, 8), 256, 0, stream>>>(Tcm, Tn);
    mfma_gmul_add_ln_kernel<<<1024, 256, 0, stream>>>(Tn, WpT_l, G, E, En);

    // (f) edge MLP
    mfma_nw2_kernel<1><<<512, 256, 0, stream>>>(En, We1T_l, We1T_l + 16384, H);
    mfma_add_ln_kernel<<<1024, 256, 0, stream>>>(H, We2T_l, E, En);
  }

  // node heads (Xnb = ln(final X) from last addx_ln)
  ngemm128_kernel<256, 1><<<dim3(8, 4), 256, 0, stream>>>(Xnb, neW1T, H1, 512, 0);
  ngemm128_kernel<512, 0><<<dim3(8, 2), 256, 0, stream>>>(H1, neW2T, out_ne, 256, 0);
  rowdot_kernel<256, bf16><<<1024, 256, 0, stream>>>(Xnb, hW, out_h);
  headN_kernel<256, 32><<<128, 256, 0, stream>>>(Xnb, nlW, out_nl);
  ngemm128_kernel<256, 1><<<dim3(8, 4), 256, 0, stream>>>(Xnb, nfW1T, H1, 512, 0);
  headN_kernel<512, 16><<<64, 256, 0, stream>>>(H1, nfW2, out_nf);

  // edge heads (En = ln(final E) from last mfma_add_ln)
  head8_kernel<128, 0, 1><<<4096, 256, 0, stream>>>(En, elW, out_el, aW, out_A);
  mfma_nw2_kernel<1><<<512, 256, 0, stream>>>(En, efW1T, efW1T + 16384, H);
  head8_kernel<256, 0, 0><<<4096, 256, 0, stream>>>(H, efW2, out_ef, nullptr, nullptr);
}

// Round 7
// 1824.942 us; speedup vs baseline: 5.3588x; 1.1133x over previous
//
#include <hip/hip_runtime.h>
#include <hip/hip_bf16.h>

using bf16 = __hip_bfloat16;

constexpr int Bc = 8, Kc = 64, Mc = 128, Dnc = 256, Dec = 128, Hnc = 512, Hec = 256, Hc = 8;
constexpr float INV_SQRT_DH = 0.17677669529663687f;   // 1/sqrt(32)

typedef __attribute__((ext_vector_type(8))) short s8v;   // 8 bf16 (4 VGPRs)
typedef __attribute__((ext_vector_type(4))) float f4v;   // 4 fp32
#define MFMA16(a, b, c) __builtin_amdgcn_mfma_f32_16x16x32_bf16(a, b, c, 0, 0, 0)

// ---------- helpers ----------
__device__ __forceinline__ float waveSum(float v) {
#pragma unroll
  for (int m = 32; m > 0; m >>= 1) v += __shfl_xor(v, m);
  return v;
}
__device__ __forceinline__ float b2f(unsigned short u) {
  union { unsigned x; float f; } v; v.x = (unsigned)u << 16; return v.f;
}
__device__ __forceinline__ unsigned short f2bu(float f) {
  bf16 h = __float2bfloat16(f); return *reinterpret_cast<unsigned short*>(&h);
}
__device__ __forceinline__ float ldf(const float* p) { return *p; }
__device__ __forceinline__ float ldf(const bf16* p)  { return __bfloat162float(*p); }
__device__ __forceinline__ void  stf(float* p, float v) { *p = v; }
__device__ __forceinline__ void  stf(bf16*  p, float v) { *p = __float2bfloat16(v); }

// ---------- LayerNorm over last dim D (one row per block) ----------
template<int D, typename InT, typename OutT>
__global__ __launch_bounds__(D) void ln_kernel(const InT* __restrict__ in, OutT* __restrict__ out) {
  constexpr int NW = D / 64;
  __shared__ float sb[NW];
  size_t row = blockIdx.x;
  int t = threadIdx.x;
  float v = ldf(in + row * D + t);
  float s = waveSum(v);
  if ((t & 63) == 0) sb[t >> 6] = s;
  __syncthreads();
  float tot = 0.f;
#pragma unroll
  for (int i = 0; i < NW; i++) tot += sb[i];
  float mean = tot * (1.0f / D);
  float d = v - mean;
  __syncthreads();
  float s2 = waveSum(d * d);
  if ((t & 63) == 0) sb[t >> 6] = s2;
  __syncthreads();
  float tot2 = 0.f;
#pragma unroll
  for (int i = 0; i < NW; i++) tot2 += sb[i];
  float rstd = rsqrtf(tot2 * (1.0f / D) + 1e-5f);
  stf(out + row * D + t, d * rstd);
}

// ---------- LayerNorm D=128, one row per WAVE ----------
template<typename InT, typename OutT>
__global__ __launch_bounds__(256) void ln128w_kernel(const InT* __restrict__ in,
                                                     OutT* __restrict__ out) {
  size_t row = (size_t)blockIdx.x * 4 + (threadIdx.x >> 6);
  int l = threadIdx.x & 63;
  const InT* p = in + row * 128 + l * 2;
  float v0 = ldf(p), v1 = ldf(p + 1);
  float mean = waveSum(v0 + v1) * (1.f / 128.f);
  float d0 = v0 - mean, d1 = v1 - mean;
  float rstd = rsqrtf(waveSum(d0 * d0 + d1 * d1) * (1.f / 128.f) + 1e-5f);
  OutT* q = out + row * 128 + l * 2;
  stf(q, d0 * rstd);
  stf(q + 1, d1 * rstd);
}

// ---------- broadcast init ----------
__global__ void bcast_kernel(const float* __restrict__ s, float* __restrict__ d,
                             unsigned mask, size_t total) {
  size_t i = (size_t)blockIdx.x * blockDim.x + threadIdx.x;
  if (i < total) d[i] = s[i & mask];
}

// ---------- weight transpose+convert: out[n][k] = bf16(in[k][n]) ----------
__global__ __launch_bounds__(256) void twcvt_kernel(const float* __restrict__ in,
                                                    bf16* __restrict__ out, int K, int N,
                                                    int inZ, int outZ) {
  const float* inp = in + (size_t)blockIdx.z * inZ;
  bf16* outp = out + (size_t)blockIdx.z * outZ;
  __shared__ float tile[32][33];
  int tx = threadIdx.x & 31, ty = threadIdx.x >> 5;
  int k0 = blockIdx.y * 32, n0 = blockIdx.x * 32;
#pragma unroll
  for (int it = 0; it < 4; it++)
    tile[ty + it * 8][tx] = inp[(size_t)(k0 + ty + it * 8) * N + n0 + tx];
  __syncthreads();
#pragma unroll
  for (int it = 0; it < 4; it++)
    outp[(size_t)(n0 + ty + it * 8) * K + k0 + tx] = __float2bfloat16(tile[tx][ty + it * 8]);
}

// ---------- MFMA tile staging with XOR swizzle ----------
template<int ROWS>
__device__ __forceinline__ void stageTile(const bf16* __restrict__ g, int srcLd,
                                          char* lds, int t) {
  constexpr int IT = ROWS * 16 / 256;
#pragma unroll
  for (int it = 0; it < IT; it++) {
    int u = t + it * 256;
    int row = u >> 4, c16 = u & 15;
    uint4 val = *(const uint4*)(g + (size_t)row * srcLd + c16 * 8);
    *(uint4*)(lds + row * 256 + ((c16 ^ (row & 7)) << 4)) = val;
  }
}
__device__ __forceinline__ s8v readFrag(const char* lds, int row, int c16) {
  return *(const s8v*)(lds + row * 256 + ((c16 ^ (row & 7)) << 4));
}

// ---------- node MFMA GEMM: 128 rows x 128 cols per block ----------
template<int KTOT, int EPI>
__global__ __launch_bounds__(256) void ngemm128_kernel(
    const bf16* __restrict__ A, const bf16* __restrict__ Wt, void* __restrict__ outv,
    int N, int rowShift) {
  __shared__ char Ash[32768];
  __shared__ char Wsh[32768];
  int t = threadIdx.x, l = t & 63, w = t >> 6;
  size_t r0 = (size_t)blockIdx.x * 128;
  int c0 = blockIdx.y * 128;
  int rb = w * 32;
  f4v acc[2][8];
#pragma unroll
  for (int rf = 0; rf < 2; rf++)
#pragma unroll
    for (int cf = 0; cf < 8; cf++) acc[rf][cf] = (f4v){0.f, 0.f, 0.f, 0.f};
#pragma unroll
  for (int kb = 0; kb < KTOT; kb += 128) {
    if (kb) __syncthreads();
    stageTile<128>(A + r0 * KTOT + kb, KTOT, Ash, t);
    stageTile<128>(Wt + (size_t)c0 * KTOT + kb, KTOT, Wsh, t);
    __syncthreads();
#pragma unroll
    for (int kc = 0; kc < 4; kc++) {
      int c16 = kc * 4 + (l >> 4);
      s8v af[2];
#pragma unroll
      for (int rf = 0; rf < 2; rf++) af[rf] = readFrag(Ash, rb + rf * 16 + (l & 15), c16);
#pragma unroll
      for (int cf = 0; cf < 8; cf++) {
        s8v b0 = readFrag(Wsh, cf * 16 + (l & 15), c16);
#pragma unroll
        for (int rf = 0; rf < 2; rf++) acc[rf][cf] = MFMA16(af[rf], b0, acc[rf][cf]);
      }
    }
  }
#pragma unroll
  for (int rf = 0; rf < 2; rf++)
#pragma unroll
    for (int cf = 0; cf < 8; cf++)
#pragma unroll
      for (int i = 0; i < 4; i++) {
        size_t row = r0 + rb + rf * 16 + ((l >> 4) << 2) + i;
        int col = c0 + cf * 16 + (l & 15);
        float v = acc[rf][cf][i];
        if (EPI == 0) {
          ((float*)outv)[row * N + col] = v;
        } else if (EPI == 1) {
          ((bf16*)outv)[row * N + col] = __float2bfloat16(fmaxf(v, 0.f));
        } else {
          int seg = col >> 8, h = (col >> 5) & 7, d = col & 31;
          int b = (int)(row >> rowShift);
          int ii = (int)(row & ((1 << rowShift) - 1));
          ((bf16*)outv)[(((size_t)seg * 8 + b) * 8 + h) * ((size_t)(1 << rowShift) * 32)
                        + (size_t)ii * 32 + d] = __float2bfloat16(v);
        }
      }
}

// ---------- MFMA fused attention ----------
template<int NKV, int HASBIAS>
__global__ __launch_bounds__(256) void attn_mfma_kernel(
    const bf16* __restrict__ qb, const bf16* __restrict__ kb, const bf16* __restrict__ vb,
    int kvStride, const float* __restrict__ bias, bf16* __restrict__ o) {
  constexpr int CF = NKV / 16, KC = NKV / 32;
  constexpr int QB = 64 * 80, KB = NKV * 80, VB = 32 * NKV * 2, PB = 64 * NKV * 2;
  __shared__ char lds[QB + KB + VB + PB];
  char* Qs = lds; char* Ks = lds + QB; char* Vt = Ks + KB; char* Ps = Vt + VB;
  int t = threadIdx.x, l = t & 63, w = t >> 6;
  int bh = blockIdx.x, row0 = blockIdx.y * 64;
  const bf16* Qp = qb + (size_t)bh * 4096 + (size_t)row0 * 32;
  const bf16* Kp = kb + (size_t)bh * kvStride;
  const bf16* Vp = vb + (size_t)bh * kvStride;
  {
    int row = t >> 2, c = t & 3;
    *(uint4*)(Qs + row * 80 + c * 16) = *(const uint4*)(Qp + row * 32 + c * 8);
  }
  for (int u = t; u < NKV * 4; u += 256) {
    int row = u >> 2, c = u & 3;
    *(uint4*)(Ks + row * 80 + c * 16) = *(const uint4*)(Kp + row * 32 + c * 8);
  }
  for (int u = t; u < NKV * 4; u += 256) {
    int j = u >> 2, db = (u & 3) * 8;
    uint4 v = *(const uint4*)(Vp + j * 32 + db);
    const unsigned short* pv = (const unsigned short*)&v;
#pragma unroll
    for (int e = 0; e < 8; e++) {
      int d = db + e;
      *(unsigned short*)(Vt + d * (NKV * 2) + (((j >> 3) ^ (d & 7)) << 4) + (j & 7) * 2) = pv[e];
    }
  }
  __syncthreads();
  int rb = w * 16;
  f4v acc[CF];
#pragma unroll
  for (int cf = 0; cf < CF; cf++) acc[cf] = (f4v){0.f, 0.f, 0.f, 0.f};
  s8v aq = *(const s8v*)(Qs + (rb + (l & 15)) * 80 + (l >> 4) * 16);
#pragma unroll
  for (int cf = 0; cf < CF; cf++) {
    s8v bk = *(const s8v*)(Ks + (cf * 16 + (l & 15)) * 80 + (l >> 4) * 16);
    acc[cf] = MFMA16(aq, bk, acc[cf]);
  }
#pragma unroll
  for (int i = 0; i < 4; i++) {
    int rl = rb + ((l >> 4) << 2) + i;
    float sv[CF];
    float mx = -1e30f;
#pragma unroll
    for (int cf = 0; cf < CF; cf++) {
      float s = acc[cf][i] * INV_SQRT_DH;
      if (HASBIAS)
        s += bias[((size_t)bh * 128 + row0 + rl) * 128 + cf * 16 + (l & 15)];
      sv[cf] = s; mx = fmaxf(mx, s);
    }
#pragma unroll
    for (int m = 1; m < 16; m <<= 1) mx = fmaxf(mx, __shfl_xor(mx, m));
    float sm = 0.f;
#pragma unroll
    for (int cf = 0; cf < CF; cf++) { sv[cf] = __expf(sv[cf] - mx); sm += sv[cf]; }
#pragma unroll
    for (int m = 1; m < 16; m <<= 1) sm += __shfl_xor(sm, m);
    float rs = 1.f / sm;
#pragma unroll
    for (int cf = 0; cf < CF; cf++) {
      int col = cf * 16 + (l & 15);
      int c16 = col >> 3;
      *(unsigned short*)(Ps + rl * (NKV * 2) + ((c16 ^ (rl & 7)) << 4) + (col & 7) * 2) =
          f2bu(sv[cf] * rs);
    }
  }
  __syncthreads();
  f4v oacc[2];
  oacc[0] = (f4v){0.f, 0.f, 0.f, 0.f};
  oacc[1] = (f4v){0.f, 0.f, 0.f, 0.f};
#pragma unroll
  for (int kc = 0; kc < KC; kc++) {
    int c16 = kc * 4 + (l >> 4);
    int ar = rb + (l & 15);
    s8v ap = *(const s8v*)(Ps + ar * (NKV * 2) + ((c16 ^ (ar & 7)) << 4));
#pragma unroll
    for (int cf = 0; cf < 2; cf++) {
      int d = cf * 16 + (l & 15);
      s8v bv = *(const s8v*)(Vt + d * (NKV * 2) + ((c16 ^ (d & 7)) << 4));
      oacc[cf] = MFMA16(ap, bv, oacc[cf]);
    }
  }
  int b = bh >> 3, h = bh & 7;
#pragma unroll
  for (int cf = 0; cf < 2; cf++)
#pragma unroll
    for (int i = 0; i < 4; i++) {
      int rl = rb + ((l >> 4) << 2) + i;
      o[((size_t)(b * 128 + row0 + rl)) * 256 + h * 32 + cf * 16 + (l & 15)] =
          __float2bfloat16(oacc[cf][i]);
    }
}

// ---------- node residual+LN: X[64rows x 256] += A@Wt; Xnb = ln(X) fused ----------
template<int KTOT>
__global__ __launch_bounds__(256) void mfma_addx_ln_kernel(
    const bf16* __restrict__ A, const bf16* __restrict__ Wt,
    float* __restrict__ X, bf16* __restrict__ Xnb) {
  __shared__ char Ash[16384];
  __shared__ char Wsh[65536];
  int t = threadIdx.x, l = t & 63, w = t >> 6;
  size_t r0 = (size_t)blockIdx.x * 64;
  int rb = w * 16;
  f4v acc[16];
#pragma unroll
  for (int cf = 0; cf < 16; cf++) acc[cf] = (f4v){0.f, 0.f, 0.f, 0.f};
#pragma unroll
  for (int kb = 0; kb < KTOT; kb += 128) {
    if (kb) __syncthreads();
    stageTile<64>(A + r0 * KTOT + kb, KTOT, Ash, t);
    stageTile<256>(Wt + kb, KTOT, Wsh, t);
    __syncthreads();
#pragma unroll
    for (int kc = 0; kc < 4; kc++) {
      int c16 = kc * 4 + (l >> 4);
      s8v af = readFrag(Ash, rb + (l & 15), c16);
#pragma unroll
      for (int cf = 0; cf < 16; cf++) {
        s8v b0 = readFrag(Wsh, cf * 16 + (l & 15), c16);
        acc[cf] = MFMA16(af, b0, acc[cf]);
      }
    }
  }
#pragma unroll
  for (int cf = 0; cf < 16; cf++)
#pragma unroll
    for (int i = 0; i < 4; i++) {
      size_t row = r0 + rb + ((l >> 4) << 2) + i;
      size_t o = row * 256 + cf * 16 + (l & 15);
      float e = X[o] + acc[cf][i];
      X[o] = e; acc[cf][i] = e;
    }
#pragma unroll
  for (int i = 0; i < 4; i++) {
    float s = 0.f, s2 = 0.f;
#pragma unroll
    for (int cf = 0; cf < 16; cf++) { float x = acc[cf][i]; s += x; s2 += x * x; }
#pragma unroll
    for (int m = 1; m < 16; m <<= 1) { s += __shfl_xor(s, m); s2 += __shfl_xor(s2, m); }
    float mean = s * 0.00390625f;
    float rstd = rsqrtf(s2 * 0.00390625f - mean * mean + 1e-5f);
    size_t row = r0 + rb + ((l >> 4) << 2) + i;
#pragma unroll
    for (int cf = 0; cf < 16; cf++)
      Xnb[row * 256 + cf * 16 + (l & 15)] = __float2bfloat16((acc[cf][i] - mean) * rstd);
  }
}

// ---------- MFMA GEMM edge, 256 rows x 128 cols, two weight mats, K=128 ----------
// EPI 1: relu|relu -> bf16 [row][256]; EPI 2: gated sigmoid, TRANSPOSED out [b][c][ik]
template<int EPI>
__global__ __launch_bounds__(256, 1) void mfma_nw2_kernel(
    const bf16* __restrict__ A, const bf16* __restrict__ W0t, const bf16* __restrict__ W1t,
    bf16* __restrict__ out) {
  __shared__ char lds[131072];
  char* Ash = lds; char* W0sh = lds + 65536; char* W1sh = lds + 98304;
  int t = threadIdx.x, l = t & 63, w = t >> 6;
  size_t r0 = (size_t)blockIdx.x * 256;
  int rb = w * 64;
  stageTile<256>(A + r0 * 128, 128, Ash, t);
  stageTile<128>(W0t, 128, W0sh, t);
  stageTile<128>(W1t, 128, W1sh, t);
  __syncthreads();
  f4v acc0[4][8], acc1[4][8];
#pragma unroll
  for (int rf = 0; rf < 4; rf++)
#pragma unroll
    for (int cf = 0; cf < 8; cf++) {
      acc0[rf][cf] = (f4v){0.f, 0.f, 0.f, 0.f};
      acc1[rf][cf] = (f4v){0.f, 0.f, 0.f, 0.f};
    }
#pragma unroll
  for (int kc = 0; kc < 4; kc++) {
    int c16 = kc * 4 + (l >> 4);
    s8v af[4];
#pragma unroll
    for (int rf = 0; rf < 4; rf++) af[rf] = readFrag(Ash, rb + rf * 16 + (l & 15), c16);
#pragma unroll
    for (int cf = 0; cf < 8; cf++) {
      s8v b0 = readFrag(W0sh, cf * 16 + (l & 15), c16);
      s8v b1 = readFrag(W1sh, cf * 16 + (l & 15), c16);
#pragma unroll
      for (int rf = 0; rf < 4; rf++) {
        acc0[rf][cf] = MFMA16(af[rf], b0, acc0[rf][cf]);
        acc1[rf][cf] = MFMA16(af[rf], b1, acc1[rf][cf]);
      }
    }
  }
  if (EPI == 1) {
#pragma unroll
    for (int rf = 0; rf < 4; rf++)
#pragma unroll
      for (int cf = 0; cf < 8; cf++)
#pragma unroll
        for (int i = 0; i < 4; i++) {
          size_t row = r0 + rb + rf * 16 + ((l >> 4) << 2) + i;
          int col = cf * 16 + (l & 15);
          out[row * 256 + col]       = __float2bfloat16(fmaxf(acc0[rf][cf][i], 0.f));
          out[row * 256 + 128 + col] = __float2bfloat16(fmaxf(acc1[rf][cf][i], 0.f));
        }
  } else {
    __syncthreads();
    char* tb = lds;   // 128 c-rows x 560B (512B payload), overlaps dead Ash/W0sh
#pragma unroll
    for (int rf = 0; rf < 4; rf++)
#pragma unroll
      for (int cf = 0; cf < 8; cf++) {
        int c = cf * 16 + (l & 15);
        int u0 = rb + rf * 16 + ((l >> 4) << 2);
        uint2 pv;
        pv.x = (unsigned)f2bu(acc1[rf][cf][0] / (1.f + __expf(-acc0[rf][cf][0]))) |
               ((unsigned)f2bu(acc1[rf][cf][1] / (1.f + __expf(-acc0[rf][cf][1]))) << 16);
        pv.y = (unsigned)f2bu(acc1[rf][cf][2] / (1.f + __expf(-acc0[rf][cf][2]))) |
               ((unsigned)f2bu(acc1[rf][cf][3] / (1.f + __expf(-acc0[rf][cf][3]))) << 16);
        *(uint2*)(tb + c * 560 + u0 * 2) = pv;
      }
    __syncthreads();
    int b_ = (int)(r0 >> 14); int ik0 = (int)(r0 & 16383);
    bf16* op = out + (size_t)b_ * 2097152 + ik0;
    // coalesced: 32 lanes cover one c's 256-elem span (512B contiguous)
#pragma unroll
    for (int q = 0; q < 16; q++) {
      int idx = q * 256 + t;
      int c = idx >> 5, li = idx & 31;
      *(uint4*)(op + (size_t)c * 16384 + li * 8) = *(const uint4*)(tb + c * 560 + li * 16);
    }
  }
}

// ---------- fused: E += sigmoid(En@Wgp) * (Tn@Wp); En = LN(E) ----------
__global__ __launch_bounds__(256, 1) void mfma_gmulsig_add_ln_kernel(
    const bf16* __restrict__ Tn, const bf16* __restrict__ Enin,
    const bf16* __restrict__ WpT, const bf16* __restrict__ WgpT,
    float* __restrict__ E, bf16* __restrict__ En) {
  __shared__ char lds[131072];
  char* Tsh = lds; char* Esh = lds + 32768; char* Wpsh = lds + 65536; char* Wgsh = lds + 98304;
  int t = threadIdx.x, l = t & 63, w = t >> 6;
  size_t r0 = (size_t)blockIdx.x * 128;
  int rb = w * 32;
  stageTile<128>(Tn + r0 * 128, 128, Tsh, t);
  stageTile<128>(Enin + r0 * 128, 128, Esh, t);
  stageTile<128>(WpT, 128, Wpsh, t);
  stageTile<128>(WgpT, 128, Wgsh, t);
  __syncthreads();
  f4v accp[2][8], accg[2][8];
#pragma unroll
  for (int rf = 0; rf < 2; rf++)
#pragma unroll
    for (int cf = 0; cf < 8; cf++) {
      accp[rf][cf] = (f4v){0.f, 0.f, 0.f, 0.f};
      accg[rf][cf] = (f4v){0.f, 0.f, 0.f, 0.f};
    }
#pragma unroll
  for (int kc = 0; kc < 4; kc++) {
    int c16 = kc * 4 + (l >> 4);
    s8v at[2], ae[2];
#pragma unroll
    for (int rf = 0; rf < 2; rf++) {
      at[rf] = readFrag(Tsh, rb + rf * 16 + (l & 15), c16);
      ae[rf] = readFrag(Esh, rb + rf * 16 + (l & 15), c16);
    }
#pragma unroll
    for (int cf = 0; cf < 8; cf++) {
      s8v bp = readFrag(Wpsh, cf * 16 + (l & 15), c16);
      s8v bg = readFrag(Wgsh, cf * 16 + (l & 15), c16);
#pragma unroll
      for (int rf = 0; rf < 2; rf++) {
        accp[rf][cf] = MFMA16(at[rf], bp, accp[rf][cf]);
        accg[rf][cf] = MFMA16(ae[rf], bg, accg[rf][cf]);
      }
    }
  }
#pragma unroll
  for (int rf = 0; rf < 2; rf++)
#pragma unroll
    for (int cf = 0; cf < 8; cf++)
#pragma unroll
      for (int i = 0; i < 4; i++) {
        size_t row = r0 + rb + rf * 16 + ((l >> 4) << 2) + i;
        size_t o = row * 128 + cf * 16 + (l & 15);
        float g = 1.f / (1.f + __expf(-accg[rf][cf][i]));
        float e = E[o] + g * accp[rf][cf][i];
        E[o] = e; accp[rf][cf][i] = e;
      }
#pragma unroll
  for (int rf = 0; rf < 2; rf++)
#pragma unroll
    for (int i = 0; i < 4; i++) {
      float s = 0.f, s2 = 0.f;
#pragma unroll
      for (int cf = 0; cf < 8; cf++) { float x = accp[rf][cf][i]; s += x; s2 += x * x; }
#pragma unroll
      for (int m = 1; m < 16; m <<= 1) { s += __shfl_xor(s, m); s2 += __shfl_xor(s2, m); }
      float mean = s * 0.0078125f;
      float rstd = rsqrtf(s2 * 0.0078125f - mean * mean + 1e-5f);
      size_t row = r0 + rb + rf * 16 + ((l >> 4) << 2) + i;
#pragma unroll
      for (int cf = 0; cf < 8; cf++)
        En[row * 128 + cf * 16 + (l & 15)] = __float2bfloat16((accp[rf][cf][i] - mean) * rstd);
    }
}

// ---------- fused edge MLP: E += relu(En@We1)@We2 (H in LDS); En = LN(E) ----------
__global__ __launch_bounds__(256, 1) void mfma_mlp_ln_kernel(
    const bf16* __restrict__ Enin, const bf16* __restrict__ W1t, const bf16* __restrict__ W2t,
    float* __restrict__ E, bf16* __restrict__ En) {
  __shared__ char lds[131072];
  char* Ash = lds;            // 32KB: A = En rows (K=128); later W2 chunk0
  char* W1sh = lds + 32768;   // 32KB: W1 half; later W2 chunk1
  char* Hs0 = lds + 65536;    // 32KB: H cols 0-127
  char* Hs1 = lds + 98304;    // 32KB: H cols 128-255
  int t = threadIdx.x, l = t & 63, w = t >> 6;
  size_t r0 = (size_t)blockIdx.x * 128;
  int rb = w * 32;
  stageTile<128>(Enin + r0 * 128, 128, Ash, t);
  stageTile<128>(W1t, 128, W1sh, t);
  __syncthreads();
#pragma unroll
  for (int half = 0; half < 2; half++) {
    if (half) {
      __syncthreads();                          // all waves done reading W1sh half0
      stageTile<128>(W1t + 16384, 128, W1sh, t);
      __syncthreads();
    }
    f4v acc[2][8];
#pragma unroll
    for (int rf = 0; rf < 2; rf++)
#pragma unroll
      for (int cf = 0; cf < 8; cf++) acc[rf][cf] = (f4v){0.f, 0.f, 0.f, 0.f};
#pragma unroll
    for (int kc = 0; kc < 4; kc++) {
      int c16 = kc * 4 + (l >> 4);
      s8v af[2];
#pragma unroll
      for (int rf = 0; rf < 2; rf++) af[rf] = readFrag(Ash, rb + rf * 16 + (l & 15), c16);
#pragma unroll
      for (int cf = 0; cf < 8; cf++) {
        s8v b0 = readFrag(W1sh, cf * 16 + (l & 15), c16);
#pragma unroll
        for (int rf = 0; rf < 2; rf++) acc[rf][cf] = MFMA16(af[rf], b0, acc[rf][cf]);
      }
    }
    char* Hsh = half ? Hs1 : Hs0;
#pragma unroll
    for (int rf = 0; rf < 2; rf++)
#pragma unroll
      for (int cf = 0; cf < 8; cf++)
#pragma unroll
        for (int i = 0; i < 4; i++) {
          int row = rb + rf * 16 + ((l >> 4) << 2) + i;
          int col = cf * 16 + (l & 15);
          *(unsigned short*)(Hsh + row * 256 + (((col >> 3) ^ (row & 7)) << 4) + (col & 7) * 2)
              = f2bu(fmaxf(acc[rf][cf][i], 0.f));
        }
  }
  __syncthreads();                              // Ash/W1sh dead; Hs complete
  stageTile<128>(W2t, 256, Ash, t);             // W2 chunk0 (k 0-127)
  stageTile<128>(W2t + 128, 256, W1sh, t);      // W2 chunk1 (k 128-255)
  __syncthreads();
  f4v acc2[2][8];
#pragma unroll
  for (int rf = 0; rf < 2; rf++)
#pragma unroll
    for (int cf = 0; cf < 8; cf++) acc2[rf][cf] = (f4v){0.f, 0.f, 0.f, 0.f};
#pragma unroll
  for (int kb = 0; kb < 2; kb++) {
    const char* Hb = kb ? Hs1 : Hs0;
    const char* Wb2 = kb ? W1sh : Ash;
#pragma unroll
    for (int kc = 0; kc < 4; kc++) {
      int c16 = kc * 4 + (l >> 4);
      s8v af[2];
#pragma unroll
      for (int rf = 0; rf < 2; rf++) af[rf] = readFrag(Hb, rb + rf * 16 + (l & 15), c16);
#pragma unroll
      for (int cf = 0; cf < 8; cf++) {
        s8v b0 = readFrag(Wb2, cf * 16 + (l & 15), c16);
#pragma unroll
        for (int rf = 0; rf < 2; rf++) acc2[rf][cf] = MFMA16(af[rf], b0, acc2[rf][cf]);
      }
    }
  }
#pragma unroll
  for (int rf = 0; rf < 2; rf++)
#pragma unroll
    for (int cf = 0; cf < 8; cf++)
#pragma unroll
      for (int i = 0; i < 4; i++) {
        size_t row = r0 + rb + rf * 16 + ((l >> 4) << 2) + i;
        size_t o = row * 128 + cf * 16 + (l & 15);
        float e = E[o] + acc2[rf][cf][i];
        E[o] = e; acc2[rf][cf][i] = e;
      }
#pragma unroll
  for (int rf = 0; rf < 2; rf++)
#pragma unroll
    for (int i = 0; i < 4; i++) {
      float s = 0.f, s2 = 0.f;
#pragma unroll
      for (int cf = 0; cf < 8; cf++) { float x = acc2[rf][cf][i]; s += x; s2 += x * x; }
#pragma unroll
      for (int m = 1; m < 16; m <<= 1) { s += __shfl_xor(s, m); s2 += __shfl_xor(s2, m); }
      float mean = s * 0.0078125f;
      float rstd = rsqrtf(s2 * 0.0078125f - mean * mean + 1e-5f);
      size_t row = r0 + rb + rf * 16 + ((l >> 4) << 2) + i;
#pragma unroll
      for (int cf = 0; cf < 8; cf++)
        En[row * 128 + cf * 16 + (l & 15)] = __float2bfloat16((acc2[rf][cf][i] - mean) * rstd);
    }
}

// ---------- triangle via MFMA: one block per (b,c) ----------
__global__ __launch_bounds__(256, 1) void tri_mfma_kernel(
    const bf16* __restrict__ aT, const bf16* __restrict__ bT, bf16* __restrict__ Tcm) {
  __shared__ char lds[131072];
  char* P1 = lds; char* Q1 = lds + 32768; char* P2 = lds + 65536; char* Q2 = lds + 98304;
  int t = threadIdx.x, l = t & 63, w = t >> 6;
  int bc = blockIdx.x;
  stageTile<128>(aT + (size_t)bc * 16384, 128, P1, t);
  stageTile<128>(bT + (size_t)bc * 16384, 128, Q1, t);
  __syncthreads();
#pragma unroll 8
  for (int it = 0; it < 64; it++) {
    int tile_ = w * 64 + it;
    int k0 = (tile_ & 15) * 8, r0 = (tile_ >> 4) * 8;
    int k = k0 + (l & 7), r = r0 + (l >> 3);
    int ra = r * 256 + ((((k >> 3) ^ (r & 7)) << 4)) + (k & 7) * 2;
    int wa = k * 256 + ((((r >> 3) ^ (k & 7)) << 4)) + (r & 7) * 2;
    *(unsigned short*)(P2 + wa) = *(const unsigned short*)(P1 + ra);
    *(unsigned short*)(Q2 + wa) = *(const unsigned short*)(Q1 + ra);
  }
  __syncthreads();
  int rb = w * 32;
  f4v acc1[2][8], acc2[2][8];
#pragma unroll
  for (int rf = 0; rf < 2; rf++)
#pragma unroll
    for (int cf = 0; cf < 8; cf++) {
      acc1[rf][cf] = (f4v){0.f, 0.f, 0.f, 0.f};
      acc2[rf][cf] = (f4v){0.f, 0.f, 0.f, 0.f};
    }
#pragma unroll
  for (int kc = 0; kc < 4; kc++) {
    int c16 = kc * 4 + (l >> 4);
    s8v a1[2], a2[2];
#pragma unroll
    for (int rf = 0; rf < 2; rf++) {
      a1[rf] = readFrag(P1, rb + rf * 16 + (l & 15), c16);
      a2[rf] = readFrag(P2, rb + rf * 16 + (l & 15), c16);
    }
#pragma unroll
    for (int cf = 0; cf < 8; cf++) {
      s8v b1 = readFrag(Q1, cf * 16 + (l & 15), c16);
      s8v b2 = readFrag(Q2, cf * 16 + (l & 15), c16);
#pragma unroll
      for (int rf = 0; rf < 2; rf++) {
        acc1[rf][cf] = MFMA16(a1[rf], b1, acc1[rf][cf]);
        acc2[rf][cf] = MFMA16(a2[rf], b2, acc2[rf][cf]);
      }
    }
  }
  __syncthreads();
  char* tb = lds;
#pragma unroll
  for (int rf = 0; rf < 2; rf++)
#pragma unroll
    for (int cf = 0; cf < 8; cf++) {
      int j = cf * 16 + (l & 15);
      int i0 = rb + rf * 16 + ((l >> 4) << 2);
      uint2 pv;
      pv.x = (unsigned)f2bu(0.5f * (acc1[rf][cf][0] + acc2[rf][cf][0])) |
             ((unsigned)f2bu(0.5f * (acc1[rf][cf][1] + acc2[rf][cf][1])) << 16);
      pv.y = (unsigned)f2bu(0.5f * (acc1[rf][cf][2] + acc2[rf][cf][2])) |
             ((unsigned)f2bu(0.5f * (acc1[rf][cf][3] + acc2[rf][cf][3])) << 16);
      *(uint2*)(tb + j * 560 + i0 * 2) = pv;
    }
  __syncthreads();
  bf16* op = Tcm + (size_t)bc * 16384;
#pragma unroll
  for (int q = 0; q < 8; q++) {
    int ci = q * 256 + t;
    *(uint4*)(op + ci * 8) = *(const uint4*)(tb + (ci >> 4) * 560 + (ci & 15) * 16);
  }
}

// ---------- permute + LN: Tcm[b][c][j][i] -> Tn[(b,i,j)][c] with LN over c ----------
__global__ __launch_bounds__(256) void permln_kernel(const bf16* __restrict__ Tcm,
                                                     bf16* __restrict__ Tn) {
  __shared__ float tile[128][77];
  __shared__ float ps[4][64], ps2[4][64], mst[64], rst[64];
  int b = blockIdx.z, j = blockIdx.y, i0 = blockIdx.x * 64;
  int t = threadIdx.x;
  const bf16* src = Tcm + (size_t)b * 2097152 + j * 128 + i0;
#pragma unroll
  for (int q = 0; q < 4; q++) {
    int ci = q * 256 + t; int c = ci >> 3, ch = ci & 7;
    uint4 v = *(const uint4*)(src + (size_t)c * 16384 + ch * 8);
    const unsigned short* u = (const unsigned short*)&v;
#pragma unroll
    for (int e = 0; e < 8; e++) tile[c][ch * 8 + e] = b2f(u[e]);
  }
  __syncthreads();
  {
    int i_ = t & 63, part = t >> 6;
    float s = 0.f, s2 = 0.f;
    for (int c = part * 32; c < part * 32 + 32; c++) { float x = tile[c][i_]; s += x; s2 += x * x; }
    ps[part][i_] = s; ps2[part][i_] = s2;
  }
  __syncthreads();
  if (t < 64) {
    float s = ps[0][t] + ps[1][t] + ps[2][t] + ps[3][t];
    float q2 = ps2[0][t] + ps2[1][t] + ps2[2][t] + ps2[3][t];
    float mean = s * 0.0078125f;
    float var = q2 * 0.0078125f - mean * mean;
    mst[t] = mean; rst[t] = rsqrtf(var + 1e-5f);
  }
  __syncthreads();
  {
    int i2 = t & 63, c0 = (t >> 6) * 32;
    float mean = mst[i2], rstd = rst[i2];
    bf16* dst = Tn + ((size_t)b * 16384 + (size_t)(i0 + i2) * 128 + j) * 128 + c0;
#pragma unroll
    for (int qq = 0; qq < 4; qq++) {
      unsigned short pk[8];
#pragma unroll
      for (int e = 0; e < 8; e++)
        pk[e] = f2bu((tile[c0 + qq * 8 + e][i2] - mean) * rstd);
      *(uint4*)(dst + qq * 8) = *(uint4*)pk;
    }
  }
}

// ---------- E += outer(xi,xj); En = LN(E); one row per wave, float2/lane ----------
__global__ __launch_bounds__(256) void outer_ln_kernel(float* __restrict__ E,
    const float* __restrict__ xixj, bf16* __restrict__ En) {
  size_t r = (size_t)blockIdx.x * 4 + (threadIdx.x >> 6);
  int l = threadIdx.x & 63;
  int b = (int)(r >> 14), i = (int)((r >> 7) & 127), j = (int)(r & 127);
  size_t o = r * 128 + l * 2;
  float2 e2 = *(const float2*)(E + o);
  float2 xi2 = *(const float2*)(xixj + (size_t)(b * 128 + i) * 256 + l * 2);
  float2 xj2 = *(const float2*)(xixj + (size_t)(b * 128 + j) * 256 + 128 + l * 2);
  float e0 = e2.x + xi2.x + xj2.x;
  float e1 = e2.y + xi2.y + xj2.y;
  float2 eo; eo.x = e0; eo.y = e1;
  *(float2*)(E + o) = eo;
  float mean = waveSum(e0 + e1) * (1.f / 128.f);
  float d0 = e0 - mean, d1 = e1 - mean;
  float rstd = rsqrtf(waveSum(d0 * d0 + d1 * d1) * (1.f / 128.f) + 1e-5f);
  unsigned pk = (unsigned)f2bu(d0 * rstd) | ((unsigned)f2bu(d1 * rstd) << 16);
  *(unsigned*)(En + o) = pk;
}

// ---------- 8-col head: out[r,h] = sum_k A[r,k]*W[k,h]; BIAS scatter / A-dot ----------
template<int K, int BIAS, int WITHA>
__global__ __launch_bounds__(256) void head8_kernel(const bf16* __restrict__ A,
    const float* __restrict__ W, float* __restrict__ out,
    const float* __restrict__ aW, float* __restrict__ outA) {
  __shared__ __align__(16) bf16 As[32 * K];
  __shared__ float Ws[K * 8];
  __shared__ float aWs[128];
  __shared__ float bsh[8][33];
  size_t r0 = (size_t)blockIdx.x * 32;
  int t = threadIdx.x;
  constexpr int NCH = 32 * K / 8;
#pragma unroll
  for (int it = 0; it < NCH / 256; it++)
    ((uint4*)As)[t + it * 256] = ((const uint4*)(A + r0 * K))[t + it * 256];
  for (int u = t; u < K * 8; u += 256) Ws[u] = W[u];
  if (WITHA) { if (t < 128) aWs[t] = aW[t]; }
  __syncthreads();
  int rr = t >> 3, h = t & 7;
  float acc = 0.f;
#pragma unroll 4
  for (int k = 0; k < K; k++) acc += __bfloat162float(As[rr * K + k]) * Ws[k * 8 + h];
  if (BIAS) {
    bsh[h][rr] = acc;
    __syncthreads();
    int b = (int)(r0 >> 14), ij0 = (int)(r0 & 16383);
    out[(((size_t)b * 8 + (t >> 5)) << 14) + ij0 + (t & 31)] = bsh[t >> 5][t & 31];
  } else {
    out[(r0 + rr) * 8 + h] = acc;
  }
  if (WITHA) {
    if (t < 32) {
      float a2 = 0.f;
#pragma unroll 4
      for (int k = 0; k < K; k++) a2 += __bfloat162float(As[t * K + k]) * aWs[k];
      outA[r0 + t] = a2;
    }
  }
}

// ---------- generic narrow head ----------
template<int K, int N>
__global__ __launch_bounds__(256) void headN_kernel(const bf16* __restrict__ A,
    const float* __restrict__ W, float* __restrict__ out) {
  constexpr int R = 256 / N;
  __shared__ __align__(16) bf16 As[R * K];
  __shared__ float Ws[K * N];
  size_t r0 = (size_t)blockIdx.x * R;
  int t = threadIdx.x;
  constexpr int NCH = R * K / 8;
#pragma unroll
  for (int it = 0; it < NCH / 256; it++)
    ((uint4*)As)[t + it * 256] = ((const uint4*)(A + r0 * K))[t + it * 256];
  for (int u = t; u < K * N; u += 256) Ws[u] = W[u];
  __syncthreads();
  int rr = t / N, h = t % N;
  float acc = 0.f;
#pragma unroll 4
  for (int k = 0; k < K; k++) acc += __bfloat162float(As[rr * K + k]) * Ws[k * N + h];
  out[(r0 + rr) * N + h] = acc;
}

// ---------- row dot ----------
template<int D, typename InT>
__global__ __launch_bounds__(D) void rowdot_kernel(const InT* __restrict__ A,
    const float* __restrict__ w, float* __restrict__ out) {
  __shared__ float sb[D / 64];
  size_t r = blockIdx.x; int t = threadIdx.x;
  float v = ldf(A + r * D + t) * w[t];
  v = waveSum(v);
  if ((t & 63) == 0) sb[t >> 6] = v;
  __syncthreads();
  if (t == 0) { float s = 0.f; for (int i = 0; i < D / 64; i++) s += sb[i]; out[r] = s; }
}

extern "C" void kernel_launch(void* const* d_in, const int* in_sizes, int n_in,
                              void* d_out, int out_size, void* d_ws, size_t ws_size,
                              hipStream_t stream) {
  const float* graph = (const float*)d_in[0];
  const float* Xq  = (const float*)d_in[1];
  const float* Eq  = (const float*)d_in[2];
  const float* Wq  = (const float*)d_in[3];
  const float* Wk  = (const float*)d_in[4];
  const float* Wv  = (const float*)d_in[5];
  const float* Wo  = (const float*)d_in[6];
  const float* Sq  = (const float*)d_in[7];
  const float* Sk  = (const float*)d_in[8];
  const float* Sv  = (const float*)d_in[9];
  const float* So  = (const float*)d_in[10];
  const float* Wb  = (const float*)d_in[11];
  const float* Wn1 = (const float*)d_in[12];
  const float* Wn2 = (const float*)d_in[13];
  const float* Woi = (const float*)d_in[14];
  const float* Woj = (const float*)d_in[15];
  const float* Wa  = (const float*)d_in[16];
  const float* Wga = (const float*)d_in[17];
  const float* Wb2 = (const float*)d_in[18];
  const float* Wgb = (const float*)d_in[19];
  const float* Wp  = (const float*)d_in[20];
  const float* Wgp = (const float*)d_in[21];
  const float* We1 = (const float*)d_in[22];
  const float* We2 = (const float*)d_in[23];
  const float* hW  = (const float*)d_in[24];
  const float* neW1 = (const float*)d_in[25];
  const float* neW2 = (const float*)d_in[26];
  const float* nlW  = (const float*)d_in[27];
  const float* nfW1 = (const float*)d_in[28];
  const float* nfW2 = (const float*)d_in[29];
  const float* aW   = (const float*)d_in[30];
  const float* elW  = (const float*)d_in[31];
  const float* efW1 = (const float*)d_in[32];
  const float* efW2 = (const float*)d_in[33];

  char* wsb = (char*)d_ws;
  size_t off = 0;
  auto alloc = [&](size_t bytes) -> char* {
    char* p = wsb + off; off += (bytes + 255) & ~(size_t)255; return p;
  };
  float* X    = (float*)alloc((size_t)262144 * 4);
  bf16*  Xnb  = (bf16*)alloc((size_t)262144 * 2);
  bf16*  srcb = (bf16*)alloc((size_t)131072 * 2);
  bf16*  qb2  = (bf16*)alloc((size_t)262144 * 2);
  bf16*  kvb2 = (bf16*)alloc((size_t)262144 * 2);
  bf16*  sqkvb = (bf16*)alloc((size_t)786432 * 2);
  bf16*  obB  = (bf16*)alloc((size_t)262144 * 2);
  bf16*  H1   = (bf16*)alloc((size_t)524288 * 2);
  float* xixj = (float*)alloc((size_t)262144 * 4);
  float* bias = (float*)alloc((size_t)1048576 * 4);
  float* E   = (float*)alloc((size_t)16777216 * 4);
  bf16* En   = (bf16*)alloc((size_t)16777216 * 2);
  bf16* aT1  = (bf16*)alloc((size_t)16777216 * 2);   // [b][c][i][k]
  bf16* bT1  = (bf16*)alloc((size_t)16777216 * 2);   // [b][c][j][k]
  bf16* Tcm  = (bf16*)alloc((size_t)16777216 * 2);   // [b][c][j][i]
  bf16* Tn   = aT1;      // alias: aT1 dead after tri
  bf16* H    = aT1;      // alias: spans aT1+bT1 (final heads only)
  // transposed bf16 edge weights
  bf16* WgaT = (bf16*)alloc((size_t)65536 * 2);
  bf16* WaT  = (bf16*)alloc((size_t)65536 * 2);
  bf16* WgbT = (bf16*)alloc((size_t)65536 * 2);
  bf16* Wb2T = (bf16*)alloc((size_t)65536 * 2);
  bf16* WgpT = (bf16*)alloc((size_t)65536 * 2);
  bf16* WpT  = (bf16*)alloc((size_t)65536 * 2);
  bf16* We1T = (bf16*)alloc((size_t)131072 * 2);
  bf16* We2T = (bf16*)alloc((size_t)131072 * 2);
  bf16* efW1T = (bf16*)alloc((size_t)32768 * 2);
  // transposed bf16 node weights
  bf16* WqT   = (bf16*)alloc((size_t)262144 * 2);
  bf16* WkvT  = (bf16*)alloc((size_t)524288 * 2);
  bf16* SqkvT = (bf16*)alloc((size_t)786432 * 2);
  bf16* WoT   = (bf16*)alloc((size_t)262144 * 2);
  bf16* SoT   = (bf16*)alloc((size_t)262144 * 2);
  bf16* Wn1T  = (bf16*)alloc((size_t)524288 * 2);
  bf16* Wn2T  = (bf16*)alloc((size_t)524288 * 2);
  bf16* WoijT = (bf16*)alloc((size_t)262144 * 2);
  bf16* neW1T = (bf16*)alloc((size_t)131072 * 2);
  bf16* neW2T = (bf16*)alloc((size_t)131072 * 2);
  bf16* nfW1T = (bf16*)alloc((size_t)131072 * 2);

  float* out = (float*)d_out;
  float* out_ne = out;               // 262144
  float* out_h  = out + 262144;      // 1024
  float* out_nl = out + 263168;      // 32768
  float* out_nf = out + 295936;      // 16384
  float* out_A  = out + 312320;      // 131072
  float* out_el = out + 443392;      // 1048576
  float* out_ef = out + 1491968;     // 1048576

  // ---- weight prep (edge) ----
  twcvt_kernel<<<dim3(4, 4, 4), 256, 0, stream>>>(Wga, WgaT, 128, 128, 16384, 16384);
  twcvt_kernel<<<dim3(4, 4, 4), 256, 0, stream>>>(Wa,  WaT,  128, 128, 16384, 16384);
  twcvt_kernel<<<dim3(4, 4, 4), 256, 0, stream>>>(Wgb, WgbT, 128, 128, 16384, 16384);
  twcvt_kernel<<<dim3(4, 4, 4), 256, 0, stream>>>(Wb2, Wb2T, 128, 128, 16384, 16384);
  twcvt_kernel<<<dim3(4, 4, 4), 256, 0, stream>>>(Wgp, WgpT, 128, 128, 16384, 16384);
  twcvt_kernel<<<dim3(4, 4, 4), 256, 0, stream>>>(Wp,  WpT,  128, 128, 16384, 16384);
  twcvt_kernel<<<dim3(8, 4, 4), 256, 0, stream>>>(We1, We1T, 128, 256, 32768, 32768);
  twcvt_kernel<<<dim3(4, 8, 4), 256, 0, stream>>>(We2, We2T, 256, 128, 32768, 32768);
  twcvt_kernel<<<dim3(8, 4, 1), 256, 0, stream>>>(efW1, efW1T, 128, 256, 32768, 32768);
  // ---- weight prep (node) ----
  twcvt_kernel<<<dim3(8, 8, 4), 256, 0, stream>>>(Wq, WqT, 256, 256, 65536, 65536);
  twcvt_kernel<<<dim3(8, 8, 4), 256, 0, stream>>>(Wk, WkvT, 256, 256, 65536, 131072);
  twcvt_kernel<<<dim3(8, 8, 4), 256, 0, stream>>>(Wv, WkvT + 65536, 256, 256, 65536, 131072);
  twcvt_kernel<<<dim3(8, 8, 4), 256, 0, stream>>>(Sq, SqkvT, 256, 256, 65536, 196608);
  twcvt_kernel<<<dim3(8, 8, 4), 256, 0, stream>>>(Sk, SqkvT + 65536, 256, 256, 65536, 196608);
  twcvt_kernel<<<dim3(8, 8, 4), 256, 0, stream>>>(Sv, SqkvT + 131072, 256, 256, 65536, 196608);
  twcvt_kernel<<<dim3(8, 8, 4), 256, 0, stream>>>(Wo, WoT, 256, 256, 65536, 65536);
  twcvt_kernel<<<dim3(8, 8, 4), 256, 0, stream>>>(So, SoT, 256, 256, 65536, 65536);
  twcvt_kernel<<<dim3(16, 8, 4), 256, 0, stream>>>(Wn1, Wn1T, 256, 512, 131072, 131072);
  twcvt_kernel<<<dim3(8, 16, 4), 256, 0, stream>>>(Wn2, Wn2T, 512, 256, 131072, 131072);
  twcvt_kernel<<<dim3(4, 8, 4), 256, 0, stream>>>(Woi, WoijT, 256, 128, 32768, 65536);
  twcvt_kernel<<<dim3(4, 8, 4), 256, 0, stream>>>(Woj, WoijT + 32768, 256, 128, 32768, 65536);
  twcvt_kernel<<<dim3(16, 8, 1), 256, 0, stream>>>(neW1, neW1T, 256, 512, 131072, 131072);
  twcvt_kernel<<<dim3(8, 16, 1), 256, 0, stream>>>(neW2, neW2T, 512, 256, 131072, 131072);
  twcvt_kernel<<<dim3(16, 8, 1), 256, 0, stream>>>(nfW1, nfW1T, 256, 512, 131072, 131072);

  // ---- init ----
  bcast_kernel<<<1024, 256, 0, stream>>>(Xq, X, 32767u, (size_t)262144);
  bcast_kernel<<<65536, 256, 0, stream>>>(Eq, E, 2097151u, (size_t)16777216);
  ln_kernel<256, float, bf16><<<1024, 256, 0, stream>>>(X, Xnb);
  ln_kernel<256, float, bf16><<<512, 256, 0, stream>>>(graph, srcb);
  ln128w_kernel<float, bf16><<<32768, 256, 0, stream>>>(E, En);

  for (int l = 0; l < 4; l++) {
    const bf16* WqT_l   = WqT   + l * 65536;
    const bf16* WkvT_l  = WkvT  + l * 131072;
    const bf16* SqkvT_l = SqkvT + l * 196608;
    const bf16* WoT_l   = WoT   + l * 65536;
    const bf16* SoT_l   = SoT   + l * 65536;
    const bf16* Wn1T_l  = Wn1T  + l * 131072;
    const bf16* Wn2T_l  = Wn2T  + l * 131072;
    const bf16* WoijT_l = WoijT + l * 65536;
    const float* Wb_l = Wb + l * 1024;
    const bf16* WgaT_l = WgaT + l * 16384; const bf16* WaT_l  = WaT  + l * 16384;
    const bf16* WgbT_l = WgbT + l * 16384; const bf16* Wb2T_l = Wb2T + l * 16384;
    const bf16* WgpT_l = WgpT + l * 16384; const bf16* WpT_l  = WpT  + l * 16384;
    const bf16* We1T_l = We1T + l * 32768; const bf16* We2T_l = We2T + l * 32768;

    // (a) cross attention (MFMA)
    ngemm128_kernel<256, 2><<<dim3(8, 2), 256, 0, stream>>>(Xnb, WqT_l, qb2, 256, 7);
    ngemm128_kernel<256, 2><<<dim3(4, 4), 256, 0, stream>>>(srcb, WkvT_l, kvb2, 512, 6);
    attn_mfma_kernel<64, 0><<<dim3(64, 2), 256, 0, stream>>>(
        qb2, kvb2, kvb2 + 131072, 2048, nullptr, obB);
    mfma_addx_ln_kernel<256><<<16, 256, 0, stream>>>(obB, WoT_l, X, Xnb);

    // (b) pair-biased self attention (MFMA)
    head8_kernel<128, 1, 0><<<4096, 256, 0, stream>>>(En, Wb_l, bias, nullptr, nullptr);
    ngemm128_kernel<256, 2><<<dim3(8, 6), 256, 0, stream>>>(Xnb, SqkvT_l, sqkvb, 768, 7);
    attn_mfma_kernel<128, 1><<<dim3(64, 2), 256, 0, stream>>>(
        sqkvb, sqkvb + 262144, sqkvb + 524288, 4096, bias, obB);
    mfma_addx_ln_kernel<256><<<16, 256, 0, stream>>>(obB, SoT_l, X, Xnb);

    // (c) node MLP
    ngemm128_kernel<256, 1><<<dim3(8, 4), 256, 0, stream>>>(Xnb, Wn1T_l, H1, 512, 0);
    mfma_addx_ln_kernel<512><<<16, 256, 0, stream>>>(H1, Wn2T_l, X, Xnb);

    // (d) outer sum into E + fused En = ln(E)
    ngemm128_kernel<256, 0><<<dim3(8, 2), 256, 0, stream>>>(Xnb, WoijT_l, xixj, 256, 0);
    outer_ln_kernel<<<32768, 256, 0, stream>>>(E, xixj, En);

    // (e) triangle multiplicative update (all-MFMA, sigmoid-gate fused)
    mfma_nw2_kernel<2><<<512, 256, 0, stream>>>(En, WgaT_l, WaT_l, aT1);
    mfma_nw2_kernel<2><<<512, 256, 0, stream>>>(En, WgbT_l, Wb2T_l, bT1);
    tri_mfma_kernel<<<1024, 256, 0, stream>>>(aT1, bT1, Tcm);
    permln_kernel<<<dim3(2, 128, 8), 256, 0, stream>>>(Tcm, Tn);
    mfma_gmulsig_add_ln_kernel<<<1024, 256, 0, stream>>>(Tn, En, WpT_l, WgpT_l, E, En);

    // (f) fused edge MLP (hidden stays in LDS)
    mfma_mlp_ln_kernel<<<1024, 256, 0, stream>>>(En, We1T_l, We2T_l, E, En);
  }

  // node heads (Xnb = ln(final X) from last addx_ln)
  ngemm128_kernel<256, 1><<<dim3(8, 4), 256, 0, stream>>>(Xnb, neW1T, H1, 512, 0);
  ngemm128_kernel<512, 0><<<dim3(8, 2), 256, 0, stream>>>(H1, neW2T, out_ne, 256, 0);
  rowdot_kernel<256, bf16><<<1024, 256, 0, stream>>>(Xnb, hW, out_h);
  headN_kernel<256, 32><<<128, 256, 0, stream>>>(Xnb, nlW, out_nl);
  ngemm128_kernel<256, 1><<<dim3(8, 4), 256, 0, stream>>>(Xnb, nfW1T, H1, 512, 0);
  headN_kernel<512, 16><<<64, 256, 0, stream>>>(H1, nfW2, out_nf);

  // edge heads (En = ln(final E) from last mfma_mlp_ln)
  head8_kernel<128, 0, 1><<<4096, 256, 0, stream>>>(En, elW, out_el, aW, out_A);
  mfma_nw2_kernel<1><<<512, 256, 0, stream>>>(En, efW1T, efW1T + 16384, H);
  head8_kernel<256, 0, 0><<<4096, 256, 0, stream>>>(H, efW2, out_ef, nullptr, nullptr);
}